// Round 6
// baseline (667.145 us; speedup 1.0000x reference)
//
#include <hip/hip_runtime.h>
#include <math.h>

#define PDIM 8
#define BSZ 256
#define CEEG 22
#define TLEN 1000
#define KW 12
#define C2 96
#define TOUT 989
#define TSTR 992          // padded h2 row stride (16B-aligned float4 stores)
#define NSWEEP 7
#define NROUND (NSWEEP*31)

// ---- workspace layout (in floats) ----
#define OFF_H1   ((size_t)0)
#define SZ_H1    ((size_t)BSZ*CEEG*TLEN)
#define OFF_H2   (OFF_H1 + SZ_H1)
#define SZ_H2    ((size_t)BSZ*C2*TSTR)
#define OFF_S    (OFF_H2 + SZ_H2)
#define SZ_S     ((size_t)BSZ*3*1024)
#define OFF_QQT  (OFF_S + SZ_S)
#define SZ_QQT   ((size_t)BSZ*3*256)
#define OFF_KKT  (OFF_QQT + SZ_QQT)
#define OFF_VP   (OFF_KKT + SZ_QQT)
#define SZ_VP    ((size_t)BSZ*256)
#define OFF_P1   (OFF_VP + SZ_VP)
#define SZ_P1    ((size_t)BSZ*44)
#define OFF_P2   (OFF_P1 + SZ_P1)
#define SZ_P2    ((size_t)BSZ*8*192)
#define OFF_BN1  (OFF_P2 + SZ_P2)
#define OFF_BN2  (OFF_BN1 + (size_t)64)

// ================= K1: conv1 (22ch spatial filter) + BN1 partial stats ==========
__global__ __launch_bounds__(256) void k1_conv1(const float* __restrict__ x,
        const float* __restrict__ w1, float* __restrict__ h1,
        float* __restrict__ part1) {
    __shared__ float sw[CEEG*CEEG];       // [o][c]
    __shared__ float red[4][44];
    int b = blockIdx.x;
    int tid = threadIdx.x;
    for (int i = tid; i < CEEG*CEEG; i += 256) sw[i] = w1[i];
    __syncthreads();
    float sum[CEEG], sumsq[CEEG];
    #pragma unroll
    for (int o = 0; o < CEEG; ++o) { sum[o] = 0.f; sumsq[o] = 0.f; }
    const float* xb = x + (size_t)b*CEEG*TLEN;
    float* hb = h1 + (size_t)b*CEEG*TLEN;
    for (int it = 0; it < 4; ++it) {
        int t = it*256 + tid;
        if (t < TLEN) {
            float acc[CEEG];
            #pragma unroll
            for (int o = 0; o < CEEG; ++o) acc[o] = 0.f;
            #pragma unroll 2
            for (int c = 0; c < CEEG; ++c) {
                float xv = xb[c*TLEN + t];
                #pragma unroll
                for (int o = 0; o < CEEG; ++o) acc[o] = fmaf(xv, sw[o*CEEG + c], acc[o]);
            }
            #pragma unroll
            for (int o = 0; o < CEEG; ++o) {
                hb[o*TLEN + t] = acc[o];
                sum[o]  += acc[o];
                sumsq[o] += acc[o]*acc[o];
            }
        }
    }
    int lane = tid & 63, wv = tid >> 6;
    #pragma unroll
    for (int o = 0; o < CEEG; ++o) {
        float s = sum[o], s2 = sumsq[o];
        for (int off = 32; off > 0; off >>= 1) {
            s  += __shfl_down(s,  off, 64);
            s2 += __shfl_down(s2, off, 64);
        }
        if (lane == 0) { red[wv][o] = s; red[wv][CEEG + o] = s2; }
    }
    __syncthreads();
    if (tid < 44) {
        part1[(size_t)b*44 + tid] = red[0][tid] + red[1][tid] + red[2][tid] + red[3][tid];
    }
}

// ================= K2: finalize BN1 params (1 block / channel) ==========
__global__ __launch_bounds__(64) void k2_bn1(const float* __restrict__ part1,
        const float* __restrict__ g, const float* __restrict__ bta, float* __restrict__ p1) {
    int c = blockIdx.x, t = threadIdx.x;
    float s = 0.f, s2 = 0.f;
    for (int blk = t; blk < BSZ; blk += 64) {
        s  += part1[(size_t)blk*44 + c];
        s2 += part1[(size_t)blk*44 + CEEG + c];
    }
    for (int off = 32; off > 0; off >>= 1) {
        s  += __shfl_down(s,  off, 64);
        s2 += __shfl_down(s2, off, 64);
    }
    if (t == 0) {
        double N = (double)BSZ * (double)TLEN;
        double mu = (double)s / N, var = (double)s2 / N - mu*mu;
        double scale = (double)g[c] / sqrt(var + 1e-5);
        p1[c] = (float)scale;
        p1[CEEG + c] = (float)((double)bta[c] - mu*scale);
    }
}

// ================= K3: conv2 (96x22x12) [R4 version]: 3o x 16t / thread ====
__global__ __launch_bounds__(256) void k3_conv2(const float* __restrict__ h1,
        const float* __restrict__ w2, const float* __restrict__ p1,
        float* __restrict__ h2, float* __restrict__ part2) {
    __shared__ float sin_[CEEG][160];       // staged input (BN1+ELU), 16B-aligned rows
    __shared__ float swt[2][C2*14];         // double-buffered weights [o][14]
    __shared__ float rStat[C2][20];         // per-(o, tgroup) partial sums
    int b = blockIdx.x;
    int tile = blockIdx.y;                  // 0..7
    int t0 = tile * 128;
    int tid = threadIdx.x;
    int og = tid & 31;                      // o base = 3*og
    int tg = tid >> 5;                      // t base = 16*tg
    int ob = 3*og;
    const float* hb = h1 + (size_t)b*CEEG*TLEN;

    // stage input window [t0, t0+139] with BN1+ELU; zero beyond TLEN
    for (int i = tid; i < CEEG*140; i += 256) {
        int c = i / 140, tt = i - c*140;
        float v = 0.f;
        int t = t0 + tt;
        if (t < TLEN) {
            float z = fmaf(hb[c*TLEN + t], p1[c], p1[CEEG + c]);
            v = z > 0.f ? z : expm1f(z);
        }
        sin_[c][tt] = v;
    }
    // stage weights for c=0 into buf 0
    for (int i = tid; i < C2*KW; i += 256) {
        int o = i / KW, k = i - o*KW;
        swt[0][o*14 + k] = w2[o*264 + k];   // c=0
    }
    __syncthreads();

    float acc[3][16];
    #pragma unroll
    for (int j = 0; j < 3; ++j)
        #pragma unroll
        for (int i = 0; i < 16; ++i) acc[j][i] = 0.f;

    for (int c = 0; c < CEEG; ++c) {
        int buf = c & 1;
        // prefetch weights for c+1 into other buffer
        if (c + 1 < CEEG) {
            int cn = c + 1;
            for (int i = tid; i < C2*KW; i += 256) {
                int o = i / KW, k = i - o*KW;
                swt[buf ^ 1][o*14 + k] = w2[o*264 + cn*12 + k];
            }
        }
        // load this thread's weights (float2, 2-way bank alias = free)
        float aw[3][12];
        #pragma unroll
        for (int j = 0; j < 3; ++j) {
            const float2* wr = (const float2*)&swt[buf][(ob + j)*14];
            #pragma unroll
            for (int h = 0; h < 6; ++h) {
                float2 wv2 = wr[h];
                aw[j][2*h] = wv2.x; aw[j][2*h + 1] = wv2.y;
            }
        }
        // load input window (float4 broadcast: 2 distinct addrs per wave)
        float bw[28];
        const float4* br = (const float4*)&sin_[c][tg*16];
        #pragma unroll
        for (int h = 0; h < 7; ++h) {
            float4 bv = br[h];
            bw[4*h] = bv.x; bw[4*h+1] = bv.y; bw[4*h+2] = bv.z; bw[4*h+3] = bv.w;
        }
        #pragma unroll
        for (int k = 0; k < KW; ++k) {
            #pragma unroll
            for (int j = 0; j < 3; ++j) {
                float a = aw[j][k];
                #pragma unroll
                for (int i = 0; i < 16; ++i)
                    acc[j][i] = fmaf(a, bw[i + k], acc[j][i]);
            }
        }
        __syncthreads();
    }

    // stores + BN2 partial stats
    float* h2b = h2 + (size_t)b*C2*TSTR;
    int tbase = t0 + tg*16;
    #pragma unroll
    for (int j = 0; j < 3; ++j) {
        int o = ob + j;
        float s = 0.f, s2 = 0.f;
        if (tbase + 15 < TOUT) {
            float* dst = &h2b[(size_t)o*TSTR + tbase];
            #pragma unroll
            for (int h = 0; h < 4; ++h) {
                *(float4*)&dst[4*h] = make_float4(acc[j][4*h], acc[j][4*h+1], acc[j][4*h+2], acc[j][4*h+3]);
                #pragma unroll
                for (int u = 0; u < 4; ++u) {
                    float v = acc[j][4*h + u];
                    s += v; s2 += v*v;
                }
            }
        } else {
            #pragma unroll
            for (int i = 0; i < 16; ++i) {
                int t = tbase + i;
                if (t < TOUT) {
                    float v = acc[j][i];
                    h2b[(size_t)o*TSTR + t] = v;
                    s += v; s2 += v*v;
                }
            }
        }
        rStat[o][2*tg]     = s;
        rStat[o][2*tg + 1] = s2;
    }
    __syncthreads();
    if (tid < C2) {
        float s = 0.f, s2 = 0.f;
        #pragma unroll
        for (int g2 = 0; g2 < 8; ++g2) { s += rStat[tid][2*g2]; s2 += rStat[tid][2*g2+1]; }
        float* pb = part2 + ((size_t)b*8 + tile)*192;
        pb[tid] = s; pb[96 + tid] = s2;
    }
}

// ================= K4: finalize BN2 params (1 block / channel) ==========
__global__ __launch_bounds__(256) void k4_bn2(const float* __restrict__ part2,
        const float* __restrict__ g, const float* __restrict__ bta, float* __restrict__ p2) {
    __shared__ float rs[4], rs2[4];
    int q = blockIdx.x, t = threadIdx.x;
    float s = 0.f, s2 = 0.f;
    for (int blk = t; blk < BSZ*8; blk += 256) {
        s  += part2[(size_t)blk*192 + q];
        s2 += part2[(size_t)blk*192 + 96 + q];
    }
    for (int off = 32; off > 0; off >>= 1) {
        s  += __shfl_down(s,  off, 64);
        s2 += __shfl_down(s2, off, 64);
    }
    int lane = t & 63, wv = t >> 6;
    if (lane == 0) { rs[wv] = s; rs2[wv] = s2; }
    __syncthreads();
    if (t == 0) {
        double S  = (double)rs[0]  + rs[1]  + rs[2]  + rs[3];
        double S2 = (double)rs2[0] + rs2[1] + rs2[2] + rs2[3];
        double N = (double)BSZ * (double)TOUT;
        double mu = S / N, var = S2 / N - mu*mu;
        double scale = (double)g[q] / sqrt(var + 1e-5);
        p2[q] = (float)scale;
        p2[C2 + q] = (float)((double)bta[q] - mu*scale);
    }
}

// ================= K5: BN2+ELU fused Gram matrices S[b][m] = X X^T ==========
__global__ __launch_bounds__(256) void k5_gram(const float* __restrict__ h2,
        const float* __restrict__ p2, float* __restrict__ S) {
    __shared__ float sx[32][68];
    int bm = blockIdx.x;
    int b = bm / 3, m = bm % 3;
    int tid = threadIdx.x;
    int r0 = (tid >> 4) * 2;
    int c0 = (tid & 15) * 2;
    float a00 = 0.f, a01 = 0.f, a10 = 0.f, a11 = 0.f;
    const float* hb = h2 + ((size_t)b*C2 + m*32)*TSTR;
    int row = tid >> 3;
    int ts  = (tid & 7) * 8;
    float sc = p2[m*32 + row], sh = p2[C2 + m*32 + row];
    for (int t0 = 0; t0 < TOUT; t0 += 64) {
        __syncthreads();
        #pragma unroll
        for (int j = 0; j < 8; ++j) {
            int t = t0 + ts + j;
            float v = 0.f;
            if (t < TOUT) {
                float z = fmaf(hb[(size_t)row*TSTR + t], sc, sh);
                v = z > 0.f ? z : expm1f(z);
            }
            sx[row][ts + j] = v;
        }
        __syncthreads();
        #pragma unroll
        for (int tt = 0; tt < 64; tt += 4) {
            float4 va0 = *(const float4*)&sx[r0][tt];
            float4 va1 = *(const float4*)&sx[r0+1][tt];
            float4 vb0 = *(const float4*)&sx[c0][tt];
            float4 vb1 = *(const float4*)&sx[c0+1][tt];
            a00 = fmaf(va0.x, vb0.x, fmaf(va0.y, vb0.y, fmaf(va0.z, vb0.z, fmaf(va0.w, vb0.w, a00))));
            a01 = fmaf(va0.x, vb1.x, fmaf(va0.y, vb1.y, fmaf(va0.z, vb1.z, fmaf(va0.w, vb1.w, a01))));
            a10 = fmaf(va1.x, vb0.x, fmaf(va1.y, vb0.y, fmaf(va1.z, vb0.z, fmaf(va1.w, vb0.w, a10))));
            a11 = fmaf(va1.x, vb1.x, fmaf(va1.y, vb1.y, fmaf(va1.z, vb1.z, fmaf(va1.w, vb1.w, a11))));
        }
    }
    float* Sb = S + (size_t)bm*1024;
    Sb[r0*32 + c0]       = a00;
    Sb[r0*32 + c0 + 1]   = a01;
    Sb[(r0+1)*32 + c0]   = a10;
    Sb[(r0+1)*32 + c0+1] = a11;
}

// ================= K6 v4: ping-pong Jacobi, ONE barrier/round, redundant cs ======
__device__ __forceinline__ void pair_of(int r, int k, int& p, int& q) {
    if (k == 0) { p = r; q = 31; }
    else {
        int a = (r + k) % 31;
        int b2 = (r - k + 31) % 31;
        p = min(a, b2); q = max(a, b2);
    }
}

__device__ __forceinline__ void rot_of(float app, float aqq, float apq, float& c, float& s) {
    c = 1.f; s = 0.f;
    if (apq != 0.f) {
        float tau = (aqq - app) / (2.f * apq);
        float tt = (tau >= 0.f ? 1.f : -1.f) / (fabsf(tau) + sqrtf(1.f + tau*tau));
        c = 1.f / sqrtf(1.f + tt*tt);
        s = tt * c;
        if (!(c == c) || !(s == s)) { c = 1.f; s = 0.f; }
    }
}

__global__ __launch_bounds__(256) void k6_eig(const float* __restrict__ S,
        const float* __restrict__ wq, const float* __restrict__ wk, const float* __restrict__ wv,
        float* __restrict__ QQt, float* __restrict__ KKt, float* __restrict__ Vp) {
    __shared__ float A[2][32][33];
    __shared__ float Vt[2][32][34];         // V transposed: Vt[col][row], even stride
    __shared__ float sW[3][512];
    __shared__ unsigned int ptab[31*16];
    __shared__ float Up[32][9];
    __shared__ float Aw[16][9];
    __shared__ float G[8][9];
    __shared__ float Lm[8][9];
    __shared__ float Mm[16][9];
    __shared__ float lam[32];
    int bm = blockIdx.x, b = bm / 3, m = bm % 3;
    int tid = threadIdx.x;
    const float* Sb = S + (size_t)bm*1024;
    for (int i = tid; i < 1024; i += 256) {
        int r_ = i >> 5, c_ = i & 31;
        A[0][r_][c_] = Sb[i];
        Vt[0][r_][c_] = (r_ == c_) ? 1.f : 0.f;
    }
    for (int i = tid; i < 512; i += 256) {
        sW[0][i] = wq[i]; sW[1][i] = wk[i]; sW[2][i] = wv[i];
    }
    for (int i = tid; i < 31*16; i += 256) {
        int r_ = i >> 4, k_ = i & 15;
        int p, q; pair_of(r_, k_, p, q);
        ptab[i] = (unsigned)p | ((unsigned)q << 16);
    }
    __syncthreads();

    int kk_ = tid >> 4, ll_ = tid & 15;
    int i0 = kk_ * 2;
    for (int rc = 0; rc < NROUND; ++rc) {
        int r = rc % 31;
        int cur = rc & 1, nxt = cur ^ 1;
        unsigned pqk = ptab[(r << 4) + kk_];
        unsigned pql = ptab[(r << 4) + ll_];
        int p = pqk & 0xffff, q = pqk >> 16;
        int rr = pql & 0xffff, ss = pql >> 16;
        // redundant rotation compute from OLD buffer (no cs broadcast barrier)
        float ck, sk, cl, sl;
        rot_of(A[cur][p][p], A[cur][q][q], A[cur][p][q], ck, sk);
        rot_of(A[cur][rr][rr], A[cur][ss][ss], A[cur][rr][ss], cl, sl);
        // A cell update: read old, write new
        float apr = A[cur][p][rr], aps = A[cur][p][ss];
        float aqr = A[cur][q][rr], aqs = A[cur][q][ss];
        float tpr = ck*apr - sk*aqr;
        float tqr = sk*apr + ck*aqr;
        float tps = ck*aps - sk*aqs;
        float tqs = sk*aps + ck*aqs;
        A[nxt][p][rr] = cl*tpr - sl*tps;
        A[nxt][p][ss] = sl*tpr + cl*tps;
        A[nxt][q][rr] = cl*tqr - sl*tqs;
        A[nxt][q][ss] = sl*tqr + cl*tqs;
        // V update (transposed layout): cols rr,ss of V = rows of Vt
        float2 vr = *(const float2*)&Vt[cur][rr][i0];
        float2 vs = *(const float2*)&Vt[cur][ss][i0];
        float2 nvr, nvs;
        nvr.x = cl*vr.x - sl*vs.x;
        nvr.y = cl*vr.y - sl*vs.y;
        nvs.x = sl*vr.x + cl*vs.x;
        nvs.y = sl*vr.y + cl*vs.y;
        *(float2*)&Vt[nxt][rr][i0] = nvr;
        *(float2*)&Vt[nxt][ss][i0] = nvs;
        __syncthreads();
    }
    const int fin = NROUND & 1;

    // top-8 eigenvalue selection (descending) -> Up (Up[row][rank] = Vt[col][row])
    if (tid < 32) lam[tid] = A[fin][tid][tid];
    __syncthreads();
    if (tid < 32) {
        float lj = lam[tid];
        int rank = 0;
        #pragma unroll
        for (int i = 0; i < 32; ++i) {
            float li = lam[i];
            rank += (li > lj) || (li == lj && i < tid);
        }
        if (rank < PDIM) {
            #pragma unroll
            for (int i = 0; i < 32; ++i) Up[i][rank] = Vt[fin][tid][i];
        }
    }
    __syncthreads();

    // projections: P = A (A^T A)^{-1} A^T for A = W * Up  (== qr(A).Q @ Q^T)
    for (int widx = 0; widx < 3; ++widx) {
        if (widx == 2 && m != 2) break;   // V-projection only needed for m==2
        const float* W = sW[widx];
        if (tid < 128) {
            int o = tid >> 3, pp = tid & 7;
            float s = 0.f;
            #pragma unroll
            for (int i = 0; i < 32; ++i) s = fmaf(W[o*32 + i], Up[i][pp], s);
            Aw[o][pp] = s;
        }
        __syncthreads();
        if (tid < 64) {
            int xx = tid >> 3, yy = tid & 7;
            float s = 0.f;
            #pragma unroll
            for (int o = 0; o < 16; ++o) s = fmaf(Aw[o][xx], Aw[o][yy], s);
            G[xx][yy] = s;
        }
        __syncthreads();
        if (tid == 0) {
            float Lr[8][8];
            #pragma unroll
            for (int jj = 0; jj < 8; ++jj) {
                float d = G[jj][jj];
                #pragma unroll
                for (int kk = 0; kk < 8; ++kk) if (kk < jj) d -= Lr[jj][kk]*Lr[jj][kk];
                d = sqrtf(fmaxf(d, 1e-30f));
                float inv = 1.f / d;
                Lr[jj][jj] = d;
                Lm[jj][jj] = inv;     // store INVERSE of diagonal
                #pragma unroll
                for (int ii = 0; ii < 8; ++ii) if (ii > jj) {
                    float v = G[ii][jj];
                    #pragma unroll
                    for (int kk = 0; kk < 8; ++kk) if (kk < jj) v -= Lr[ii][kk]*Lr[jj][kk];
                    v *= inv;
                    Lr[ii][jj] = v;
                    Lm[ii][jj] = v;
                }
            }
        }
        __syncthreads();
        if (tid < 16) {
            int o = tid;
            float a[8], mv[8];
            #pragma unroll
            for (int pp = 0; pp < 8; ++pp) a[pp] = Aw[o][pp];
            #pragma unroll
            for (int jj = 0; jj < 8; ++jj) {
                float v = a[jj];
                #pragma unroll
                for (int kk = 0; kk < 8; ++kk) if (kk < jj) v -= Lm[jj][kk]*mv[kk];
                mv[jj] = v * Lm[jj][jj];
            }
            #pragma unroll
            for (int pp = 0; pp < 8; ++pp) Mm[o][pp] = mv[pp];
        }
        __syncthreads();
        {
            int d = tid >> 4, e = tid & 15;
            float s = 0.f;
            #pragma unroll
            for (int pp = 0; pp < 8; ++pp) s = fmaf(Mm[d][pp], Mm[e][pp], s);
            float* dst = (widx == 0) ? (QQt + (size_t)bm*256)
                       : (widx == 1) ? (KKt + (size_t)bm*256)
                       : (Vp + (size_t)b*256);
            dst[d*16 + e] = s;
        }
        __syncthreads();
    }
}

// ================= K7: attention scores + softmax(i=2) + output linear ==========
__global__ __launch_bounds__(64) void k7_out(const float* __restrict__ QQt,
        const float* __restrict__ KKt, const float* __restrict__ Vp,
        const float* __restrict__ lw, const float* __restrict__ lb,
        float* __restrict__ out) {
    __shared__ float sQ[3][256], sK[3][256], sVp[256], ssc[9], wj[3];
    int b = blockIdx.x, tid = threadIdx.x;
    for (int i = tid; i < 768; i += 64) {
        sQ[i >> 8][i & 255] = QQt[(size_t)b*768 + i];
        sK[i >> 8][i & 255] = KKt[(size_t)b*768 + i];
    }
    for (int i = tid; i < 256; i += 64) sVp[i] = Vp[(size_t)b*256 + i];
    __syncthreads();
    for (int pair = 0; pair < 9; ++pair) {
        int i = pair / 3, j = pair % 3;
        const float* Qj = sQ[j];
        const float* Ki = sK[i];
        float accp = 0.f;
        #pragma unroll
        for (int it = 0; it < 4; ++it) {
            int e = tid + 64*it;
            int d = e >> 4, ee = e & 15;
            float y = 0.f;
            #pragma unroll
            for (int f = 0; f < 16; ++f) {
                float dv = Qj[d*16 + f] - Ki[d*16 + f];
                float ev = Qj[ee*16 + f] - Ki[ee*16 + f];
                y = fmaf(dv, ev, y);
            }
            accp += y*y;
        }
        for (int off = 32; off > 0; off >>= 1) accp += __shfl_down(accp, off, 64);
        if (tid == 0) {
            float E = sqrtf(accp);
            ssc[pair] = 1.f / (1.f + log1pf(E));
        }
        __syncthreads();
    }
    if (tid < 3) {
        int j = tid;
        float e0 = expf(ssc[0*3 + j]), e1 = expf(ssc[1*3 + j]), e2 = expf(ssc[2*3 + j]);
        wj[j] = e2 / (e0 + e1 + e2);
    }
    __syncthreads();
    int o = tid >> 4, g = tid & 15;
    float part = 0.f;
    #pragma unroll
    for (int t = 0; t < 16; ++t) {
        int de = g*16 + t;
        float vv = sVp[de];
        float l0 = lw[o*768 + de];
        float l1 = lw[o*768 + 256 + de];
        float l2 = lw[o*768 + 512 + de];
        part = fmaf(vv, fmaf(wj[0], l0, fmaf(wj[1], l1, wj[2]*l2)), part);
    }
    for (int off = 8; off > 0; off >>= 1) part += __shfl_down(part, off, 16);
    if (g == 0) out[b*4 + o] = part + lb[o];
}

// ================= launch ==========
extern "C" void kernel_launch(void* const* d_in, const int* in_sizes, int n_in,
                              void* d_out, int out_size, void* d_ws, size_t ws_size,
                              hipStream_t stream) {
    const float* x  = (const float*)d_in[0];
    const float* w1 = (const float*)d_in[1];
    // d_in[2] conv1_b: cancels exactly in batch-norm (mean subtraction) -> unused
    const float* g1 = (const float*)d_in[3];
    const float* b1 = (const float*)d_in[4];
    const float* w2 = (const float*)d_in[5];
    // d_in[6] conv2_b: cancels exactly in batch-norm -> unused
    const float* g2 = (const float*)d_in[7];
    const float* b2 = (const float*)d_in[8];
    const float* wq = (const float*)d_in[9];
    const float* wk = (const float*)d_in[10];
    const float* wv = (const float*)d_in[11];
    const float* lw = (const float*)d_in[12];
    const float* lb = (const float*)d_in[13];

    float* ws   = (float*)d_ws;
    float* h1   = ws + OFF_H1;
    float* h2   = ws + OFF_H2;
    float* Sm   = ws + OFF_S;
    float* qqt  = ws + OFF_QQT;
    float* kkt  = ws + OFF_KKT;
    float* vpm  = ws + OFF_VP;
    float* p1a  = ws + OFF_P1;
    float* p2a  = ws + OFF_P2;
    float* bn1p = ws + OFF_BN1;
    float* bn2p = ws + OFF_BN2;

    k1_conv1<<<BSZ, 256, 0, stream>>>(x, w1, h1, p1a);
    k2_bn1<<<CEEG, 64, 0, stream>>>(p1a, g1, b1, bn1p);
    dim3 g3(BSZ, 8);
    k3_conv2<<<g3, 256, 0, stream>>>(h1, w2, bn1p, h2, p2a);
    k4_bn2<<<C2, 256, 0, stream>>>(p2a, g2, b2, bn2p);
    k5_gram<<<BSZ*3, 256, 0, stream>>>(h2, bn2p, Sm);
    k6_eig<<<BSZ*3, 256, 0, stream>>>(Sm, wq, wk, wv, qqt, kkt, vpm);
    k7_out<<<BSZ, 64, 0, stream>>>(qqt, kkt, vpm, lw, lb, (float*)d_out);
}

// Round 7
// 587.725 us; speedup vs baseline: 1.1351x; 1.1351x over previous
//
#include <hip/hip_runtime.h>
#include <math.h>

#define PDIM 8
#define BSZ 256
#define CEEG 22
#define TLEN 1000
#define KW 12
#define C2 96
#define TOUT 989
#define TSTR 992          // padded h2 row stride (16B-aligned float4 stores)
#define NSWEEP 7
#define NROUND (NSWEEP*31)

// ---- workspace layout (in floats) ----
#define OFF_H1   ((size_t)0)
#define SZ_H1    ((size_t)BSZ*CEEG*TLEN)
#define OFF_H2   (OFF_H1 + SZ_H1)
#define SZ_H2    ((size_t)BSZ*C2*TSTR)
#define OFF_S    (OFF_H2 + SZ_H2)
#define SZ_S     ((size_t)BSZ*3*1024)
#define OFF_QQT  (OFF_S + SZ_S)
#define SZ_QQT   ((size_t)BSZ*3*256)
#define OFF_KKT  (OFF_QQT + SZ_QQT)
#define OFF_VP   (OFF_KKT + SZ_QQT)
#define SZ_VP    ((size_t)BSZ*256)
#define OFF_P1   (OFF_VP + SZ_VP)
#define SZ_P1    ((size_t)BSZ*44)
#define OFF_P2   (OFF_P1 + SZ_P1)
#define SZ_P2    ((size_t)BSZ*8*192)
#define OFF_BN1  (OFF_P2 + SZ_P2)
#define OFF_BN2  (OFF_BN1 + (size_t)64)

// ================= K1: conv1 (22ch spatial filter) + BN1 partial stats ==========
__global__ __launch_bounds__(256) void k1_conv1(const float* __restrict__ x,
        const float* __restrict__ w1, float* __restrict__ h1,
        float* __restrict__ part1) {
    __shared__ float sw[CEEG*CEEG];       // [o][c]
    __shared__ float red[4][44];
    int b = blockIdx.x;
    int tid = threadIdx.x;
    for (int i = tid; i < CEEG*CEEG; i += 256) sw[i] = w1[i];
    __syncthreads();
    float sum[CEEG], sumsq[CEEG];
    #pragma unroll
    for (int o = 0; o < CEEG; ++o) { sum[o] = 0.f; sumsq[o] = 0.f; }
    const float* xb = x + (size_t)b*CEEG*TLEN;
    float* hb = h1 + (size_t)b*CEEG*TLEN;
    for (int it = 0; it < 4; ++it) {
        int t = it*256 + tid;
        if (t < TLEN) {
            float acc[CEEG];
            #pragma unroll
            for (int o = 0; o < CEEG; ++o) acc[o] = 0.f;
            #pragma unroll 2
            for (int c = 0; c < CEEG; ++c) {
                float xv = xb[c*TLEN + t];
                #pragma unroll
                for (int o = 0; o < CEEG; ++o) acc[o] = fmaf(xv, sw[o*CEEG + c], acc[o]);
            }
            #pragma unroll
            for (int o = 0; o < CEEG; ++o) {
                hb[o*TLEN + t] = acc[o];
                sum[o]  += acc[o];
                sumsq[o] += acc[o]*acc[o];
            }
        }
    }
    int lane = tid & 63, wv = tid >> 6;
    #pragma unroll
    for (int o = 0; o < CEEG; ++o) {
        float s = sum[o], s2 = sumsq[o];
        for (int off = 32; off > 0; off >>= 1) {
            s  += __shfl_down(s,  off, 64);
            s2 += __shfl_down(s2, off, 64);
        }
        if (lane == 0) { red[wv][o] = s; red[wv][CEEG + o] = s2; }
    }
    __syncthreads();
    if (tid < 44) {
        part1[(size_t)b*44 + tid] = red[0][tid] + red[1][tid] + red[2][tid] + red[3][tid];
    }
}

// ================= K2: finalize BN1 params (1 block / channel) ==========
__global__ __launch_bounds__(64) void k2_bn1(const float* __restrict__ part1,
        const float* __restrict__ g, const float* __restrict__ bta, float* __restrict__ p1) {
    int c = blockIdx.x, t = threadIdx.x;
    float s = 0.f, s2 = 0.f;
    for (int blk = t; blk < BSZ; blk += 64) {
        s  += part1[(size_t)blk*44 + c];
        s2 += part1[(size_t)blk*44 + CEEG + c];
    }
    for (int off = 32; off > 0; off >>= 1) {
        s  += __shfl_down(s,  off, 64);
        s2 += __shfl_down(s2, off, 64);
    }
    if (t == 0) {
        double N = (double)BSZ * (double)TLEN;
        double mu = (double)s / N, var = (double)s2 / N - mu*mu;
        double scale = (double)g[c] / sqrt(var + 1e-5);
        p1[c] = (float)scale;
        p1[CEEG + c] = (float)((double)bta[c] - mu*scale);
    }
}

// ================= K3: conv2 (96x22x12) [R4 version]: 3o x 16t / thread ====
__global__ __launch_bounds__(256) void k3_conv2(const float* __restrict__ h1,
        const float* __restrict__ w2, const float* __restrict__ p1,
        float* __restrict__ h2, float* __restrict__ part2) {
    __shared__ float sin_[CEEG][160];       // staged input (BN1+ELU), 16B-aligned rows
    __shared__ float swt[2][C2*14];         // double-buffered weights [o][14]
    __shared__ float rStat[C2][20];         // per-(o, tgroup) partial sums
    int b = blockIdx.x;
    int tile = blockIdx.y;                  // 0..7
    int t0 = tile * 128;
    int tid = threadIdx.x;
    int og = tid & 31;                      // o base = 3*og
    int tg = tid >> 5;                      // t base = 16*tg
    int ob = 3*og;
    const float* hb = h1 + (size_t)b*CEEG*TLEN;

    // stage input window [t0, t0+139] with BN1+ELU; zero beyond TLEN
    for (int i = tid; i < CEEG*140; i += 256) {
        int c = i / 140, tt = i - c*140;
        float v = 0.f;
        int t = t0 + tt;
        if (t < TLEN) {
            float z = fmaf(hb[c*TLEN + t], p1[c], p1[CEEG + c]);
            v = z > 0.f ? z : expm1f(z);
        }
        sin_[c][tt] = v;
    }
    // stage weights for c=0 into buf 0
    for (int i = tid; i < C2*KW; i += 256) {
        int o = i / KW, k = i - o*KW;
        swt[0][o*14 + k] = w2[o*264 + k];   // c=0
    }
    __syncthreads();

    float acc[3][16];
    #pragma unroll
    for (int j = 0; j < 3; ++j)
        #pragma unroll
        for (int i = 0; i < 16; ++i) acc[j][i] = 0.f;

    for (int c = 0; c < CEEG; ++c) {
        int buf = c & 1;
        // prefetch weights for c+1 into other buffer
        if (c + 1 < CEEG) {
            int cn = c + 1;
            for (int i = tid; i < C2*KW; i += 256) {
                int o = i / KW, k = i - o*KW;
                swt[buf ^ 1][o*14 + k] = w2[o*264 + cn*12 + k];
            }
        }
        // load this thread's weights (float2, 2-way bank alias = free)
        float aw[3][12];
        #pragma unroll
        for (int j = 0; j < 3; ++j) {
            const float2* wr = (const float2*)&swt[buf][(ob + j)*14];
            #pragma unroll
            for (int h = 0; h < 6; ++h) {
                float2 wv2 = wr[h];
                aw[j][2*h] = wv2.x; aw[j][2*h + 1] = wv2.y;
            }
        }
        // load input window (float4 broadcast: 2 distinct addrs per wave)
        float bw[28];
        const float4* br = (const float4*)&sin_[c][tg*16];
        #pragma unroll
        for (int h = 0; h < 7; ++h) {
            float4 bv = br[h];
            bw[4*h] = bv.x; bw[4*h+1] = bv.y; bw[4*h+2] = bv.z; bw[4*h+3] = bv.w;
        }
        #pragma unroll
        for (int k = 0; k < KW; ++k) {
            #pragma unroll
            for (int j = 0; j < 3; ++j) {
                float a = aw[j][k];
                #pragma unroll
                for (int i = 0; i < 16; ++i)
                    acc[j][i] = fmaf(a, bw[i + k], acc[j][i]);
            }
        }
        __syncthreads();
    }

    // stores + BN2 partial stats
    float* h2b = h2 + (size_t)b*C2*TSTR;
    int tbase = t0 + tg*16;
    #pragma unroll
    for (int j = 0; j < 3; ++j) {
        int o = ob + j;
        float s = 0.f, s2 = 0.f;
        if (tbase + 15 < TOUT) {
            float* dst = &h2b[(size_t)o*TSTR + tbase];
            #pragma unroll
            for (int h = 0; h < 4; ++h) {
                *(float4*)&dst[4*h] = make_float4(acc[j][4*h], acc[j][4*h+1], acc[j][4*h+2], acc[j][4*h+3]);
                #pragma unroll
                for (int u = 0; u < 4; ++u) {
                    float v = acc[j][4*h + u];
                    s += v; s2 += v*v;
                }
            }
        } else {
            #pragma unroll
            for (int i = 0; i < 16; ++i) {
                int t = tbase + i;
                if (t < TOUT) {
                    float v = acc[j][i];
                    h2b[(size_t)o*TSTR + t] = v;
                    s += v; s2 += v*v;
                }
            }
        }
        rStat[o][2*tg]     = s;
        rStat[o][2*tg + 1] = s2;
    }
    __syncthreads();
    if (tid < C2) {
        float s = 0.f, s2 = 0.f;
        #pragma unroll
        for (int g2 = 0; g2 < 8; ++g2) { s += rStat[tid][2*g2]; s2 += rStat[tid][2*g2+1]; }
        float* pb = part2 + ((size_t)b*8 + tile)*192;
        pb[tid] = s; pb[96 + tid] = s2;
    }
}

// ================= K4: finalize BN2 params (1 block / channel) ==========
__global__ __launch_bounds__(256) void k4_bn2(const float* __restrict__ part2,
        const float* __restrict__ g, const float* __restrict__ bta, float* __restrict__ p2) {
    __shared__ float rs[4], rs2[4];
    int q = blockIdx.x, t = threadIdx.x;
    float s = 0.f, s2 = 0.f;
    for (int blk = t; blk < BSZ*8; blk += 256) {
        s  += part2[(size_t)blk*192 + q];
        s2 += part2[(size_t)blk*192 + 96 + q];
    }
    for (int off = 32; off > 0; off >>= 1) {
        s  += __shfl_down(s,  off, 64);
        s2 += __shfl_down(s2, off, 64);
    }
    int lane = t & 63, wv = t >> 6;
    if (lane == 0) { rs[wv] = s; rs2[wv] = s2; }
    __syncthreads();
    if (t == 0) {
        double S  = (double)rs[0]  + rs[1]  + rs[2]  + rs[3];
        double S2 = (double)rs2[0] + rs2[1] + rs2[2] + rs2[3];
        double N = (double)BSZ * (double)TOUT;
        double mu = S / N, var = S2 / N - mu*mu;
        double scale = (double)g[q] / sqrt(var + 1e-5);
        p2[q] = (float)scale;
        p2[C2 + q] = (float)((double)bta[q] - mu*scale);
    }
}

// ================= K5: BN2+ELU fused Gram matrices S[b][m] = X X^T ==========
__global__ __launch_bounds__(256) void k5_gram(const float* __restrict__ h2,
        const float* __restrict__ p2, float* __restrict__ S) {
    __shared__ float sx[32][68];
    int bm = blockIdx.x;
    int b = bm / 3, m = bm % 3;
    int tid = threadIdx.x;
    int r0 = (tid >> 4) * 2;
    int c0 = (tid & 15) * 2;
    float a00 = 0.f, a01 = 0.f, a10 = 0.f, a11 = 0.f;
    const float* hb = h2 + ((size_t)b*C2 + m*32)*TSTR;
    int row = tid >> 3;
    int ts  = (tid & 7) * 8;
    float sc = p2[m*32 + row], sh = p2[C2 + m*32 + row];
    for (int t0 = 0; t0 < TOUT; t0 += 64) {
        __syncthreads();
        #pragma unroll
        for (int j = 0; j < 8; ++j) {
            int t = t0 + ts + j;
            float v = 0.f;
            if (t < TOUT) {
                float z = fmaf(hb[(size_t)row*TSTR + t], sc, sh);
                v = z > 0.f ? z : expm1f(z);
            }
            sx[row][ts + j] = v;
        }
        __syncthreads();
        #pragma unroll
        for (int tt = 0; tt < 64; tt += 4) {
            float4 va0 = *(const float4*)&sx[r0][tt];
            float4 va1 = *(const float4*)&sx[r0+1][tt];
            float4 vb0 = *(const float4*)&sx[c0][tt];
            float4 vb1 = *(const float4*)&sx[c0+1][tt];
            a00 = fmaf(va0.x, vb0.x, fmaf(va0.y, vb0.y, fmaf(va0.z, vb0.z, fmaf(va0.w, vb0.w, a00))));
            a01 = fmaf(va0.x, vb1.x, fmaf(va0.y, vb1.y, fmaf(va0.z, vb1.z, fmaf(va0.w, vb1.w, a01))));
            a10 = fmaf(va1.x, vb0.x, fmaf(va1.y, vb0.y, fmaf(va1.z, vb0.z, fmaf(va1.w, vb0.w, a10))));
            a11 = fmaf(va1.x, vb1.x, fmaf(va1.y, vb1.y, fmaf(va1.z, vb1.z, fmaf(va1.w, vb1.w, a11))));
        }
    }
    float* Sb = S + (size_t)bm*1024;
    Sb[r0*32 + c0]       = a00;
    Sb[r0*32 + c0 + 1]   = a01;
    Sb[(r0+1)*32 + c0]   = a10;
    Sb[(r0+1)*32 + c0+1] = a11;
}

// ====== K6 v5: A ping-pong, wave-local cs via shfl, ONE barrier/round ======
__device__ __forceinline__ void pair_of(int r, int k, int& p, int& q) {
    if (k == 0) { p = r; q = 31; }
    else {
        int a = (r + k) % 31;
        int b2 = (r - k + 31) % 31;
        p = min(a, b2); q = max(a, b2);
    }
}

__device__ __forceinline__ void rot_of(float app, float aqq, float apq, float& c, float& s) {
    c = 1.f; s = 0.f;
    if (apq != 0.f) {
        float tau = (aqq - app) / (2.f * apq);
        float tt = (tau >= 0.f ? 1.f : -1.f) / (fabsf(tau) + sqrtf(1.f + tau*tau));
        c = 1.f / sqrtf(1.f + tt*tt);
        s = tt * c;
        if (!(c == c) || !(s == s)) { c = 1.f; s = 0.f; }
    }
}

__global__ __launch_bounds__(256) void k6_eig(const float* __restrict__ S,
        const float* __restrict__ wq, const float* __restrict__ wk, const float* __restrict__ wv,
        float* __restrict__ QQt, float* __restrict__ KKt, float* __restrict__ Vp) {
    __shared__ float A[2][32][33];          // ping-pong A (breaks rot/update race)
    __shared__ float Vt[32][34];            // V transposed, in-place (exclusive cells)
    __shared__ float sW[3][512];
    __shared__ unsigned int ptab[31*16];
    __shared__ float Up[32][9];
    __shared__ float Aw[16][9];
    __shared__ float G[8][9];
    __shared__ float Lm[8][9];
    __shared__ float Mm[16][9];
    __shared__ float lam[32];
    int bm = blockIdx.x, b = bm / 3, m = bm % 3;
    int tid = threadIdx.x;
    const float* Sb = S + (size_t)bm*1024;
    for (int i = tid; i < 1024; i += 256) {
        int r_ = i >> 5, c_ = i & 31;
        A[0][r_][c_] = Sb[i];
        Vt[r_][c_] = (r_ == c_) ? 1.f : 0.f;
    }
    for (int i = tid; i < 512; i += 256) {
        sW[0][i] = wq[i]; sW[1][i] = wk[i]; sW[2][i] = wv[i];
    }
    for (int i = tid; i < 31*16; i += 256) {
        int r_ = i >> 4, k_ = i & 15;
        int p, q; pair_of(r_, k_, p, q);
        ptab[i] = (unsigned)p | ((unsigned)q << 16);
    }
    __syncthreads();

    int kk_ = tid >> 4, ll_ = tid & 15;
    int lane = tid & 63;
    int i0 = kk_ * 2;
    for (int rc = 0; rc < NROUND; ++rc) {
        int r = rc % 31;
        int cur = rc & 1, nxt = cur ^ 1;
        // lanes 0..15 of EVERY wave compute all 16 rotations from A[cur]
        float cw = 1.f, sw_ = 0.f;
        if (lane < 16) {
            unsigned pq = ptab[(r << 4) + lane];
            int p_ = pq & 0xffff, q_ = pq >> 16;
            rot_of(A[cur][p_][p_], A[cur][q_][q_], A[cur][p_][q_], cw, sw_);
        }
        unsigned pqk = ptab[(r << 4) + kk_];
        unsigned pql = ptab[(r << 4) + ll_];
        int p = pqk & 0xffff, q = pqk >> 16;
        int rr = pql & 0xffff, ss = pql >> 16;
        float ck = __shfl(cw, kk_, 64), sk = __shfl(sw_, kk_, 64);
        float cl = __shfl(cw, ll_, 64), sl = __shfl(sw_, ll_, 64);
        // A cell update: read A[cur], write A[nxt] (all cells rewritten)
        float apr = A[cur][p][rr], aps = A[cur][p][ss];
        float aqr = A[cur][q][rr], aqs = A[cur][q][ss];
        float tpr = ck*apr - sk*aqr;
        float tqr = sk*apr + ck*aqr;
        float tps = ck*aps - sk*aqs;
        float tqs = sk*aps + ck*aqs;
        A[nxt][p][rr] = cl*tpr - sl*tps;
        A[nxt][p][ss] = sl*tpr + cl*tps;
        A[nxt][q][rr] = cl*tqr - sl*tqs;
        A[nxt][q][ss] = sl*tqr + cl*tqs;
        // V update (transposed, in-place; cells exclusive to this thread)
        float2 vr = *(const float2*)&Vt[rr][i0];
        float2 vs = *(const float2*)&Vt[ss][i0];
        float2 nvr, nvs;
        nvr.x = cl*vr.x - sl*vs.x;
        nvr.y = cl*vr.y - sl*vs.y;
        nvs.x = sl*vr.x + cl*vs.x;
        nvs.y = sl*vr.y + cl*vs.y;
        *(float2*)&Vt[rr][i0] = nvr;
        *(float2*)&Vt[ss][i0] = nvs;
        __syncthreads();
    }
    const int fin = NROUND & 1;

    // top-8 eigenvalue selection (descending) -> Up (Up[row][rank] = Vt[col][row])
    if (tid < 32) lam[tid] = A[fin][tid][tid];
    __syncthreads();
    if (tid < 32) {
        float lj = lam[tid];
        int rank = 0;
        #pragma unroll
        for (int i = 0; i < 32; ++i) {
            float li = lam[i];
            rank += (li > lj) || (li == lj && i < tid);
        }
        if (rank < PDIM) {
            #pragma unroll
            for (int i = 0; i < 32; ++i) Up[i][rank] = Vt[tid][i];
        }
    }
    __syncthreads();

    // projections: P = A (A^T A)^{-1} A^T for A = W * Up  (== qr(A).Q @ Q^T)
    for (int widx = 0; widx < 3; ++widx) {
        if (widx == 2 && m != 2) break;   // V-projection only needed for m==2
        const float* W = sW[widx];
        if (tid < 128) {
            int o = tid >> 3, pp = tid & 7;
            float s = 0.f;
            #pragma unroll
            for (int i = 0; i < 32; ++i) s = fmaf(W[o*32 + i], Up[i][pp], s);
            Aw[o][pp] = s;
        }
        __syncthreads();
        if (tid < 64) {
            int xx = tid >> 3, yy = tid & 7;
            float s = 0.f;
            #pragma unroll
            for (int o = 0; o < 16; ++o) s = fmaf(Aw[o][xx], Aw[o][yy], s);
            G[xx][yy] = s;
        }
        __syncthreads();
        if (tid == 0) {
            float Lr[8][8];
            #pragma unroll
            for (int jj = 0; jj < 8; ++jj) {
                float d = G[jj][jj];
                #pragma unroll
                for (int kk = 0; kk < 8; ++kk) if (kk < jj) d -= Lr[jj][kk]*Lr[jj][kk];
                d = sqrtf(fmaxf(d, 1e-30f));
                float inv = 1.f / d;
                Lr[jj][jj] = d;
                Lm[jj][jj] = inv;     // store INVERSE of diagonal
                #pragma unroll
                for (int ii = 0; ii < 8; ++ii) if (ii > jj) {
                    float v = G[ii][jj];
                    #pragma unroll
                    for (int kk = 0; kk < 8; ++kk) if (kk < jj) v -= Lr[ii][kk]*Lr[jj][kk];
                    v *= inv;
                    Lr[ii][jj] = v;
                    Lm[ii][jj] = v;
                }
            }
        }
        __syncthreads();
        if (tid < 16) {
            int o = tid;
            float a[8], mv[8];
            #pragma unroll
            for (int pp = 0; pp < 8; ++pp) a[pp] = Aw[o][pp];
            #pragma unroll
            for (int jj = 0; jj < 8; ++jj) {
                float v = a[jj];
                #pragma unroll
                for (int kk = 0; kk < 8; ++kk) if (kk < jj) v -= Lm[jj][kk]*mv[kk];
                mv[jj] = v * Lm[jj][jj];
            }
            #pragma unroll
            for (int pp = 0; pp < 8; ++pp) Mm[o][pp] = mv[pp];
        }
        __syncthreads();
        {
            int d = tid >> 4, e = tid & 15;
            float s = 0.f;
            #pragma unroll
            for (int pp = 0; pp < 8; ++pp) s = fmaf(Mm[d][pp], Mm[e][pp], s);
            float* dst = (widx == 0) ? (QQt + (size_t)bm*256)
                       : (widx == 1) ? (KKt + (size_t)bm*256)
                       : (Vp + (size_t)b*256);
            dst[d*16 + e] = s;
        }
        __syncthreads();
    }
}

// ================= K7: attention scores + softmax(i=2) + output linear ==========
__global__ __launch_bounds__(64) void k7_out(const float* __restrict__ QQt,
        const float* __restrict__ KKt, const float* __restrict__ Vp,
        const float* __restrict__ lw, const float* __restrict__ lb,
        float* __restrict__ out) {
    __shared__ float sQ[3][256], sK[3][256], sVp[256], ssc[9], wj[3];
    int b = blockIdx.x, tid = threadIdx.x;
    for (int i = tid; i < 768; i += 64) {
        sQ[i >> 8][i & 255] = QQt[(size_t)b*768 + i];
        sK[i >> 8][i & 255] = KKt[(size_t)b*768 + i];
    }
    for (int i = tid; i < 256; i += 64) sVp[i] = Vp[(size_t)b*256 + i];
    __syncthreads();
    for (int pair = 0; pair < 9; ++pair) {
        int i = pair / 3, j = pair % 3;
        const float* Qj = sQ[j];
        const float* Ki = sK[i];
        float accp = 0.f;
        #pragma unroll
        for (int it = 0; it < 4; ++it) {
            int e = tid + 64*it;
            int d = e >> 4, ee = e & 15;
            float y = 0.f;
            #pragma unroll
            for (int f = 0; f < 16; ++f) {
                float dv = Qj[d*16 + f] - Ki[d*16 + f];
                float ev = Qj[ee*16 + f] - Ki[ee*16 + f];
                y = fmaf(dv, ev, y);
            }
            accp += y*y;
        }
        for (int off = 32; off > 0; off >>= 1) accp += __shfl_down(accp, off, 64);
        if (tid == 0) {
            float E = sqrtf(accp);
            ssc[pair] = 1.f / (1.f + log1pf(E));
        }
        __syncthreads();
    }
    if (tid < 3) {
        int j = tid;
        float e0 = expf(ssc[0*3 + j]), e1 = expf(ssc[1*3 + j]), e2 = expf(ssc[2*3 + j]);
        wj[j] = e2 / (e0 + e1 + e2);
    }
    __syncthreads();
    int o = tid >> 4, g = tid & 15;
    float part = 0.f;
    #pragma unroll
    for (int t = 0; t < 16; ++t) {
        int de = g*16 + t;
        float vv = sVp[de];
        float l0 = lw[o*768 + de];
        float l1 = lw[o*768 + 256 + de];
        float l2 = lw[o*768 + 512 + de];
        part = fmaf(vv, fmaf(wj[0], l0, fmaf(wj[1], l1, wj[2]*l2)), part);
    }
    for (int off = 8; off > 0; off >>= 1) part += __shfl_down(part, off, 16);
    if (g == 0) out[b*4 + o] = part + lb[o];
}

// ================= launch ==========
extern "C" void kernel_launch(void* const* d_in, const int* in_sizes, int n_in,
                              void* d_out, int out_size, void* d_ws, size_t ws_size,
                              hipStream_t stream) {
    const float* x  = (const float*)d_in[0];
    const float* w1 = (const float*)d_in[1];
    // d_in[2] conv1_b: cancels exactly in batch-norm (mean subtraction) -> unused
    const float* g1 = (const float*)d_in[3];
    const float* b1 = (const float*)d_in[4];
    const float* w2 = (const float*)d_in[5];
    // d_in[6] conv2_b: cancels exactly in batch-norm -> unused
    const float* g2 = (const float*)d_in[7];
    const float* b2 = (const float*)d_in[8];
    const float* wq = (const float*)d_in[9];
    const float* wk = (const float*)d_in[10];
    const float* wv = (const float*)d_in[11];
    const float* lw = (const float*)d_in[12];
    const float* lb = (const float*)d_in[13];

    float* ws   = (float*)d_ws;
    float* h1   = ws + OFF_H1;
    float* h2   = ws + OFF_H2;
    float* Sm   = ws + OFF_S;
    float* qqt  = ws + OFF_QQT;
    float* kkt  = ws + OFF_KKT;
    float* vpm  = ws + OFF_VP;
    float* p1a  = ws + OFF_P1;
    float* p2a  = ws + OFF_P2;
    float* bn1p = ws + OFF_BN1;
    float* bn2p = ws + OFF_BN2;

    k1_conv1<<<BSZ, 256, 0, stream>>>(x, w1, h1, p1a);
    k2_bn1<<<CEEG, 64, 0, stream>>>(p1a, g1, b1, bn1p);
    dim3 g3(BSZ, 8);
    k3_conv2<<<g3, 256, 0, stream>>>(h1, w2, bn1p, h2, p2a);
    k4_bn2<<<C2, 256, 0, stream>>>(p2a, g2, b2, bn2p);
    k5_gram<<<BSZ*3, 256, 0, stream>>>(h2, bn2p, Sm);
    k6_eig<<<BSZ*3, 256, 0, stream>>>(Sm, wq, wk, wv, qqt, kkt, vpm);
    k7_out<<<BSZ, 64, 0, stream>>>(qqt, kkt, vpm, lw, lb, (float*)d_out);
}

// Round 8
// 554.659 us; speedup vs baseline: 1.2028x; 1.0596x over previous
//
#include <hip/hip_runtime.h>
#include <math.h>

#define PDIM 8
#define BSZ 256
#define CEEG 22
#define TLEN 1000
#define KW 12
#define C2 96
#define TOUT 989
#define TSTR 992          // padded h2 row stride (16B-aligned float4 stores)
#define NSWEEP 7

// ---- workspace layout (in floats) ----
#define OFF_H1   ((size_t)0)
#define SZ_H1    ((size_t)BSZ*CEEG*TLEN)
#define OFF_H2   (OFF_H1 + SZ_H1)
#define SZ_H2    ((size_t)BSZ*C2*TSTR)
#define OFF_S    (OFF_H2 + SZ_H2)
#define SZ_S     ((size_t)BSZ*3*1024)
#define OFF_QQT  (OFF_S + SZ_S)
#define SZ_QQT   ((size_t)BSZ*3*256)
#define OFF_KKT  (OFF_QQT + SZ_QQT)
#define OFF_VP   (OFF_KKT + SZ_QQT)
#define SZ_VP    ((size_t)BSZ*256)
#define OFF_P1   (OFF_VP + SZ_VP)
#define SZ_P1    ((size_t)BSZ*44)
#define OFF_P2   (OFF_P1 + SZ_P1)
#define SZ_P2    ((size_t)BSZ*8*192)
#define OFF_BN1  (OFF_P2 + SZ_P2)
#define OFF_BN2  (OFF_BN1 + (size_t)64)

// ================= K1: conv1 (22ch spatial filter) + BN1 partial stats ==========
__global__ __launch_bounds__(256) void k1_conv1(const float* __restrict__ x,
        const float* __restrict__ w1, float* __restrict__ h1,
        float* __restrict__ part1) {
    __shared__ float sw[CEEG*CEEG];       // [o][c]
    __shared__ float red[4][44];
    int b = blockIdx.x;
    int tid = threadIdx.x;
    for (int i = tid; i < CEEG*CEEG; i += 256) sw[i] = w1[i];
    __syncthreads();
    float sum[CEEG], sumsq[CEEG];
    #pragma unroll
    for (int o = 0; o < CEEG; ++o) { sum[o] = 0.f; sumsq[o] = 0.f; }
    const float* xb = x + (size_t)b*CEEG*TLEN;
    float* hb = h1 + (size_t)b*CEEG*TLEN;
    for (int it = 0; it < 4; ++it) {
        int t = it*256 + tid;
        if (t < TLEN) {
            float acc[CEEG];
            #pragma unroll
            for (int o = 0; o < CEEG; ++o) acc[o] = 0.f;
            #pragma unroll 2
            for (int c = 0; c < CEEG; ++c) {
                float xv = xb[c*TLEN + t];
                #pragma unroll
                for (int o = 0; o < CEEG; ++o) acc[o] = fmaf(xv, sw[o*CEEG + c], acc[o]);
            }
            #pragma unroll
            for (int o = 0; o < CEEG; ++o) {
                hb[o*TLEN + t] = acc[o];
                sum[o]  += acc[o];
                sumsq[o] += acc[o]*acc[o];
            }
        }
    }
    int lane = tid & 63, wv = tid >> 6;
    #pragma unroll
    for (int o = 0; o < CEEG; ++o) {
        float s = sum[o], s2 = sumsq[o];
        for (int off = 32; off > 0; off >>= 1) {
            s  += __shfl_down(s,  off, 64);
            s2 += __shfl_down(s2, off, 64);
        }
        if (lane == 0) { red[wv][o] = s; red[wv][CEEG + o] = s2; }
    }
    __syncthreads();
    if (tid < 44) {
        part1[(size_t)b*44 + tid] = red[0][tid] + red[1][tid] + red[2][tid] + red[3][tid];
    }
}

// ================= K2: finalize BN1 params (1 block / channel) ==========
__global__ __launch_bounds__(64) void k2_bn1(const float* __restrict__ part1,
        const float* __restrict__ g, const float* __restrict__ bta, float* __restrict__ p1) {
    int c = blockIdx.x, t = threadIdx.x;
    float s = 0.f, s2 = 0.f;
    for (int blk = t; blk < BSZ; blk += 64) {
        s  += part1[(size_t)blk*44 + c];
        s2 += part1[(size_t)blk*44 + CEEG + c];
    }
    for (int off = 32; off > 0; off >>= 1) {
        s  += __shfl_down(s,  off, 64);
        s2 += __shfl_down(s2, off, 64);
    }
    if (t == 0) {
        double N = (double)BSZ * (double)TLEN;
        double mu = (double)s / N, var = (double)s2 / N - mu*mu;
        double scale = (double)g[c] / sqrt(var + 1e-5);
        p1[c] = (float)scale;
        p1[CEEG + c] = (float)((double)bta[c] - mu*scale);
    }
}

// ===== K3 v4: conv2, 3o x 16t / thread, quad-buffered weights, 1 barrier / 2c ====
__global__ __launch_bounds__(256) void k3_conv2(const float* __restrict__ h1,
        const float* __restrict__ w2, const float* __restrict__ p1,
        float* __restrict__ h2, float* __restrict__ part2) {
    __shared__ float sin_[CEEG][160];       // staged input (BN1+ELU), 16B-aligned rows
    __shared__ float swt[4][C2*14];         // quad-buffered weights [o][14]
    __shared__ float rStat[C2][20];         // per-(o, tgroup) partial sums
    int b = blockIdx.x;
    int tile = blockIdx.y;                  // 0..7
    int t0 = tile * 128;
    int tid = threadIdx.x;
    int og = tid & 31;                      // o base = 3*og
    int tg = tid >> 5;                      // t base = 16*tg
    int ob = 3*og;
    const float* hb = h1 + (size_t)b*CEEG*TLEN;

    // stage input window [t0, t0+139] with BN1+ELU; zero beyond TLEN
    for (int i = tid; i < CEEG*140; i += 256) {
        int c = i / 140, tt = i - c*140;
        float v = 0.f;
        int t = t0 + tt;
        if (t < TLEN) {
            float z = fmaf(hb[c*TLEN + t], p1[c], p1[CEEG + c]);
            v = z > 0.f ? z : expm1f(z);
        }
        sin_[c][tt] = v;
    }
    // stage weights for c=0,1 into buffers 0,1 (24 contiguous floats per o)
    for (int i = tid; i < C2*6; i += 256) {
        int o = i / 6, part = i - (i/6)*6;
        float4 wv4 = *(const float4*)&w2[o*264 + part*4];
        int bufsel = part < 3 ? 0 : 1;
        int kbase = (part < 3 ? part : part - 3) * 4;
        float* dst = &swt[bufsel][o*14 + kbase];
        *(float2*)&dst[0] = make_float2(wv4.x, wv4.y);
        *(float2*)&dst[2] = make_float2(wv4.z, wv4.w);
    }
    __syncthreads();

    float acc[3][16];
    #pragma unroll
    for (int j = 0; j < 3; ++j)
        #pragma unroll
        for (int i = 0; i < 16; ++i) acc[j][i] = 0.f;

    for (int cc = 0; cc < CEEG; cc += 2) {
        int base = ((cc >> 1) & 1) * 2;     // buffers {base, base+1} hold c=cc, cc+1
        // prefetch weights for cc+2, cc+3 into the other buffer pair
        if (cc + 2 < CEEG) {
            int cn = cc + 2;
            int pb = base ^ 2;
            for (int i = tid; i < C2*6; i += 256) {
                int o = i / 6, part = i - (i/6)*6;
                float4 wv4 = *(const float4*)&w2[o*264 + cn*12 + part*4];
                int bufsel = part < 3 ? pb : pb + 1;
                int kbase = (part < 3 ? part : part - 3) * 4;
                float* dst = &swt[bufsel][o*14 + kbase];
                *(float2*)&dst[0] = make_float2(wv4.x, wv4.y);
                *(float2*)&dst[2] = make_float2(wv4.z, wv4.w);
            }
        }
        #pragma unroll
        for (int half = 0; half < 2; ++half) {
            int c = cc + half;
            int buf = base + half;
            // this thread's weights (float2, bank-friendly stride 14)
            float aw[3][12];
            #pragma unroll
            for (int j = 0; j < 3; ++j) {
                const float2* wr = (const float2*)&swt[buf][(ob + j)*14];
                #pragma unroll
                for (int h = 0; h < 6; ++h) {
                    float2 wv2 = wr[h];
                    aw[j][2*h] = wv2.x; aw[j][2*h + 1] = wv2.y;
                }
            }
            // input window (float4 broadcast: 2 distinct addrs per wave)
            float bw[28];
            const float4* br = (const float4*)&sin_[c][tg*16];
            #pragma unroll
            for (int h = 0; h < 7; ++h) {
                float4 bv = br[h];
                bw[4*h] = bv.x; bw[4*h+1] = bv.y; bw[4*h+2] = bv.z; bw[4*h+3] = bv.w;
            }
            #pragma unroll
            for (int k = 0; k < KW; ++k) {
                #pragma unroll
                for (int j = 0; j < 3; ++j) {
                    float a = aw[j][k];
                    #pragma unroll
                    for (int i = 0; i < 16; ++i)
                        acc[j][i] = fmaf(a, bw[i + k], acc[j][i]);
                }
            }
        }
        __syncthreads();
    }

    // stores + BN2 partial stats
    float* h2b = h2 + (size_t)b*C2*TSTR;
    int tbase = t0 + tg*16;
    #pragma unroll
    for (int j = 0; j < 3; ++j) {
        int o = ob + j;
        float s = 0.f, s2 = 0.f;
        if (tbase + 15 < TOUT) {
            float* dst = &h2b[(size_t)o*TSTR + tbase];
            #pragma unroll
            for (int h = 0; h < 4; ++h) {
                *(float4*)&dst[4*h] = make_float4(acc[j][4*h], acc[j][4*h+1], acc[j][4*h+2], acc[j][4*h+3]);
                #pragma unroll
                for (int u = 0; u < 4; ++u) {
                    float v = acc[j][4*h + u];
                    s += v; s2 += v*v;
                }
            }
        } else {
            #pragma unroll
            for (int i = 0; i < 16; ++i) {
                int t = tbase + i;
                if (t < TOUT) {
                    float v = acc[j][i];
                    h2b[(size_t)o*TSTR + t] = v;
                    s += v; s2 += v*v;
                }
            }
        }
        rStat[o][2*tg]     = s;
        rStat[o][2*tg + 1] = s2;
    }
    __syncthreads();
    if (tid < C2) {
        float s = 0.f, s2 = 0.f;
        #pragma unroll
        for (int g2 = 0; g2 < 8; ++g2) { s += rStat[tid][2*g2]; s2 += rStat[tid][2*g2+1]; }
        float* pb = part2 + ((size_t)b*8 + tile)*192;
        pb[tid] = s; pb[96 + tid] = s2;
    }
}

// ================= K4: finalize BN2 params (1 block / channel) ==========
__global__ __launch_bounds__(256) void k4_bn2(const float* __restrict__ part2,
        const float* __restrict__ g, const float* __restrict__ bta, float* __restrict__ p2) {
    __shared__ float rs[4], rs2[4];
    int q = blockIdx.x, t = threadIdx.x;
    float s = 0.f, s2 = 0.f;
    for (int blk = t; blk < BSZ*8; blk += 256) {
        s  += part2[(size_t)blk*192 + q];
        s2 += part2[(size_t)blk*192 + 96 + q];
    }
    for (int off = 32; off > 0; off >>= 1) {
        s  += __shfl_down(s,  off, 64);
        s2 += __shfl_down(s2, off, 64);
    }
    int lane = t & 63, wv = t >> 6;
    if (lane == 0) { rs[wv] = s; rs2[wv] = s2; }
    __syncthreads();
    if (t == 0) {
        double S  = (double)rs[0]  + rs[1]  + rs[2]  + rs[3];
        double S2 = (double)rs2[0] + rs2[1] + rs2[2] + rs2[3];
        double N = (double)BSZ * (double)TOUT;
        double mu = S / N, var = S2 / N - mu*mu;
        double scale = (double)g[q] / sqrt(var + 1e-5);
        p2[q] = (float)scale;
        p2[C2 + q] = (float)((double)bta[q] - mu*scale);
    }
}

// ================= K5: BN2+ELU fused Gram matrices S[b][m] = X X^T ==========
__global__ __launch_bounds__(256) void k5_gram(const float* __restrict__ h2,
        const float* __restrict__ p2, float* __restrict__ S) {
    __shared__ float sx[32][68];
    int bm = blockIdx.x;
    int b = bm / 3, m = bm % 3;
    int tid = threadIdx.x;
    int r0 = (tid >> 4) * 2;
    int c0 = (tid & 15) * 2;
    float a00 = 0.f, a01 = 0.f, a10 = 0.f, a11 = 0.f;
    const float* hb = h2 + ((size_t)b*C2 + m*32)*TSTR;
    int row = tid >> 3;
    int ts  = (tid & 7) * 8;
    float sc = p2[m*32 + row], sh = p2[C2 + m*32 + row];
    for (int t0 = 0; t0 < TOUT; t0 += 64) {
        __syncthreads();
        #pragma unroll
        for (int j = 0; j < 8; ++j) {
            int t = t0 + ts + j;
            float v = 0.f;
            if (t < TOUT) {
                float z = fmaf(hb[(size_t)row*TSTR + t], sc, sh);
                v = z > 0.f ? z : expm1f(z);
            }
            sx[row][ts + j] = v;
        }
        __syncthreads();
        #pragma unroll
        for (int tt = 0; tt < 64; tt += 4) {
            float4 va0 = *(const float4*)&sx[r0][tt];
            float4 va1 = *(const float4*)&sx[r0+1][tt];
            float4 vb0 = *(const float4*)&sx[c0][tt];
            float4 vb1 = *(const float4*)&sx[c0+1][tt];
            a00 = fmaf(va0.x, vb0.x, fmaf(va0.y, vb0.y, fmaf(va0.z, vb0.z, fmaf(va0.w, vb0.w, a00))));
            a01 = fmaf(va0.x, vb1.x, fmaf(va0.y, vb1.y, fmaf(va0.z, vb1.z, fmaf(va0.w, vb1.w, a01))));
            a10 = fmaf(va1.x, vb0.x, fmaf(va1.y, vb0.y, fmaf(va1.z, vb0.z, fmaf(va1.w, vb0.w, a10))));
            a11 = fmaf(va1.x, vb1.x, fmaf(va1.y, vb1.y, fmaf(va1.z, vb1.z, fmaf(va1.w, vb1.w, a11))));
        }
    }
    float* Sb = S + (size_t)bm*1024;
    Sb[r0*32 + c0]       = a00;
    Sb[r0*32 + c0 + 1]   = a01;
    Sb[(r0+1)*32 + c0]   = a10;
    Sb[(r0+1)*32 + c0+1] = a11;
}

// ================= K6 v3 (R4-best): 256 thr/matrix, b64 V, f2 cs ======
__device__ __forceinline__ void pair_of(int r, int k, int& p, int& q) {
    if (k == 0) { p = r; q = 31; }
    else {
        int a = (r + k) % 31;
        int b2 = (r - k + 31) % 31;
        p = min(a, b2); q = max(a, b2);
    }
}

__global__ __launch_bounds__(256) void k6_eig(const float* __restrict__ S,
        const float* __restrict__ wq, const float* __restrict__ wk, const float* __restrict__ wv,
        float* __restrict__ QQt, float* __restrict__ KKt, float* __restrict__ Vp) {
    __shared__ float A[32][33];
    __shared__ float Vt[32][34];            // V transposed: Vt[col][row], even stride
    __shared__ float2 cs2[16];
    __shared__ float sW[3][512];
    __shared__ unsigned int ptab[31*16];
    __shared__ float Up[32][9];
    __shared__ float Aw[16][9];
    __shared__ float G[8][9];
    __shared__ float Lm[8][9];
    __shared__ float Mm[16][9];
    __shared__ float lam[32];
    int bm = blockIdx.x, b = bm / 3, m = bm % 3;
    int tid = threadIdx.x;
    const float* Sb = S + (size_t)bm*1024;
    for (int i = tid; i < 1024; i += 256) {
        int r_ = i >> 5, c_ = i & 31;
        A[r_][c_] = Sb[i];
        Vt[r_][c_] = (r_ == c_) ? 1.f : 0.f;
    }
    for (int i = tid; i < 512; i += 256) {
        sW[0][i] = wq[i]; sW[1][i] = wk[i]; sW[2][i] = wv[i];
    }
    for (int i = tid; i < 31*16; i += 256) {
        int r_ = i >> 4, k_ = i & 15;
        int p, q; pair_of(r_, k_, p, q);
        ptab[i] = (unsigned)p | ((unsigned)q << 16);
    }
    __syncthreads();

    int kk_ = tid >> 4, ll_ = tid & 15;
    int i0 = kk_ * 2;
    for (int sweep = 0; sweep < NSWEEP; ++sweep) {
        for (int r = 0; r < 31; ++r) {
            if (tid < 16) {
                unsigned pq = ptab[(r << 4) + tid];
                int p = pq & 0xffff, q = pq >> 16;
                float app = A[p][p], aqq = A[q][q], apq = A[p][q];
                float c = 1.f, s = 0.f;
                if (apq != 0.f) {
                    float tau = (aqq - app) / (2.f * apq);
                    float tt = (tau >= 0.f ? 1.f : -1.f) / (fabsf(tau) + sqrtf(1.f + tau*tau));
                    c = 1.f / sqrtf(1.f + tt*tt);
                    s = tt * c;
                    if (!(c == c) || !(s == s)) { c = 1.f; s = 0.f; }
                }
                cs2[tid] = make_float2(c, s);
            }
            __syncthreads();
            {
                unsigned pqk = ptab[(r << 4) + kk_];
                unsigned pql = ptab[(r << 4) + ll_];
                int p = pqk & 0xffff, q = pqk >> 16;
                int rr = pql & 0xffff, ss = pql >> 16;
                float2 ck2 = cs2[kk_], cl2 = cs2[ll_];
                float ck = ck2.x, sk = ck2.y, cl = cl2.x, sl = cl2.y;
                float apr = A[p][rr], aps = A[p][ss], aqr = A[q][rr], aqs = A[q][ss];
                float tpr = ck*apr - sk*aqr;
                float tqr = sk*apr + ck*aqr;
                float tps = ck*aps - sk*aqs;
                float tqs = sk*aps + ck*aqs;
                A[p][rr] = cl*tpr - sl*tps;
                A[p][ss] = sl*tpr + cl*tps;
                A[q][rr] = cl*tqr - sl*tqs;
                A[q][ss] = sl*tqr + cl*tqs;
                // V update (transposed layout): cols rr,ss of V = rows of Vt
                float2 vr = *(const float2*)&Vt[rr][i0];
                float2 vs = *(const float2*)&Vt[ss][i0];
                float2 nvr, nvs;
                nvr.x = cl*vr.x - sl*vs.x;
                nvr.y = cl*vr.y - sl*vs.y;
                nvs.x = sl*vr.x + cl*vs.x;
                nvs.y = sl*vr.y + cl*vs.y;
                *(float2*)&Vt[rr][i0] = nvr;
                *(float2*)&Vt[ss][i0] = nvs;
            }
            __syncthreads();
        }
    }

    // top-8 eigenvalue selection (descending) -> Up (Up[row][rank] = Vt[col][row])
    if (tid < 32) lam[tid] = A[tid][tid];
    __syncthreads();
    if (tid < 32) {
        float lj = lam[tid];
        int rank = 0;
        #pragma unroll
        for (int i = 0; i < 32; ++i) {
            float li = lam[i];
            rank += (li > lj) || (li == lj && i < tid);
        }
        if (rank < PDIM) {
            #pragma unroll
            for (int i = 0; i < 32; ++i) Up[i][rank] = Vt[tid][i];
        }
    }
    __syncthreads();

    // projections: P = A (A^T A)^{-1} A^T for A = W * Up  (== qr(A).Q @ Q^T)
    for (int widx = 0; widx < 3; ++widx) {
        if (widx == 2 && m != 2) break;   // V-projection only needed for m==2
        const float* W = sW[widx];
        if (tid < 128) {
            int o = tid >> 3, pp = tid & 7;
            float s = 0.f;
            #pragma unroll
            for (int i = 0; i < 32; ++i) s = fmaf(W[o*32 + i], Up[i][pp], s);
            Aw[o][pp] = s;
        }
        __syncthreads();
        if (tid < 64) {
            int xx = tid >> 3, yy = tid & 7;
            float s = 0.f;
            #pragma unroll
            for (int o = 0; o < 16; ++o) s = fmaf(Aw[o][xx], Aw[o][yy], s);
            G[xx][yy] = s;
        }
        __syncthreads();
        if (tid == 0) {
            float Lr[8][8];
            #pragma unroll
            for (int jj = 0; jj < 8; ++jj) {
                float d = G[jj][jj];
                #pragma unroll
                for (int kk = 0; kk < 8; ++kk) if (kk < jj) d -= Lr[jj][kk]*Lr[jj][kk];
                d = sqrtf(fmaxf(d, 1e-30f));
                float inv = 1.f / d;
                Lr[jj][jj] = d;
                Lm[jj][jj] = inv;     // store INVERSE of diagonal
                #pragma unroll
                for (int ii = 0; ii < 8; ++ii) if (ii > jj) {
                    float v = G[ii][jj];
                    #pragma unroll
                    for (int kk = 0; kk < 8; ++kk) if (kk < jj) v -= Lr[ii][kk]*Lr[jj][kk];
                    v *= inv;
                    Lr[ii][jj] = v;
                    Lm[ii][jj] = v;
                }
            }
        }
        __syncthreads();
        if (tid < 16) {
            int o = tid;
            float a[8], mv[8];
            #pragma unroll
            for (int pp = 0; pp < 8; ++pp) a[pp] = Aw[o][pp];
            #pragma unroll
            for (int jj = 0; jj < 8; ++jj) {
                float v = a[jj];
                #pragma unroll
                for (int kk = 0; kk < 8; ++kk) if (kk < jj) v -= Lm[jj][kk]*mv[kk];
                mv[jj] = v * Lm[jj][jj];
            }
            #pragma unroll
            for (int pp = 0; pp < 8; ++pp) Mm[o][pp] = mv[pp];
        }
        __syncthreads();
        {
            int d = tid >> 4, e = tid & 15;
            float s = 0.f;
            #pragma unroll
            for (int pp = 0; pp < 8; ++pp) s = fmaf(Mm[d][pp], Mm[e][pp], s);
            float* dst = (widx == 0) ? (QQt + (size_t)bm*256)
                       : (widx == 1) ? (KKt + (size_t)bm*256)
                       : (Vp + (size_t)b*256);
            dst[d*16 + e] = s;
        }
        __syncthreads();
    }
}

// ================= K7: attention scores + softmax(i=2) + output linear ==========
__global__ __launch_bounds__(64) void k7_out(const float* __restrict__ QQt,
        const float* __restrict__ KKt, const float* __restrict__ Vp,
        const float* __restrict__ lw, const float* __restrict__ lb,
        float* __restrict__ out) {
    __shared__ float sQ[3][256], sK[3][256], sVp[256], ssc[9], wj[3];
    int b = blockIdx.x, tid = threadIdx.x;
    for (int i = tid; i < 768; i += 64) {
        sQ[i >> 8][i & 255] = QQt[(size_t)b*768 + i];
        sK[i >> 8][i & 255] = KKt[(size_t)b*768 + i];
    }
    for (int i = tid; i < 256; i += 64) sVp[i] = Vp[(size_t)b*256 + i];
    __syncthreads();
    for (int pair = 0; pair < 9; ++pair) {
        int i = pair / 3, j = pair % 3;
        const float* Qj = sQ[j];
        const float* Ki = sK[i];
        float accp = 0.f;
        #pragma unroll
        for (int it = 0; it < 4; ++it) {
            int e = tid + 64*it;
            int d = e >> 4, ee = e & 15;
            float y = 0.f;
            #pragma unroll
            for (int f = 0; f < 16; ++f) {
                float dv = Qj[d*16 + f] - Ki[d*16 + f];
                float ev = Qj[ee*16 + f] - Ki[ee*16 + f];
                y = fmaf(dv, ev, y);
            }
            accp += y*y;
        }
        for (int off = 32; off > 0; off >>= 1) accp += __shfl_down(accp, off, 64);
        if (tid == 0) {
            float E = sqrtf(accp);
            ssc[pair] = 1.f / (1.f + log1pf(E));
        }
        __syncthreads();
    }
    if (tid < 3) {
        int j = tid;
        float e0 = expf(ssc[0*3 + j]), e1 = expf(ssc[1*3 + j]), e2 = expf(ssc[2*3 + j]);
        wj[j] = e2 / (e0 + e1 + e2);
    }
    __syncthreads();
    int o = tid >> 4, g = tid & 15;
    float part = 0.f;
    #pragma unroll
    for (int t = 0; t < 16; ++t) {
        int de = g*16 + t;
        float vv = sVp[de];
        float l0 = lw[o*768 + de];
        float l1 = lw[o*768 + 256 + de];
        float l2 = lw[o*768 + 512 + de];
        part = fmaf(vv, fmaf(wj[0], l0, fmaf(wj[1], l1, wj[2]*l2)), part);
    }
    for (int off = 8; off > 0; off >>= 1) part += __shfl_down(part, off, 16);
    if (g == 0) out[b*4 + o] = part + lb[o];
}

// ================= launch ==========
extern "C" void kernel_launch(void* const* d_in, const int* in_sizes, int n_in,
                              void* d_out, int out_size, void* d_ws, size_t ws_size,
                              hipStream_t stream) {
    const float* x  = (const float*)d_in[0];
    const float* w1 = (const float*)d_in[1];
    // d_in[2] conv1_b: cancels exactly in batch-norm (mean subtraction) -> unused
    const float* g1 = (const float*)d_in[3];
    const float* b1 = (const float*)d_in[4];
    const float* w2 = (const float*)d_in[5];
    // d_in[6] conv2_b: cancels exactly in batch-norm -> unused
    const float* g2 = (const float*)d_in[7];
    const float* b2 = (const float*)d_in[8];
    const float* wq = (const float*)d_in[9];
    const float* wk = (const float*)d_in[10];
    const float* wv = (const float*)d_in[11];
    const float* lw = (const float*)d_in[12];
    const float* lb = (const float*)d_in[13];

    float* ws   = (float*)d_ws;
    float* h1   = ws + OFF_H1;
    float* h2   = ws + OFF_H2;
    float* Sm   = ws + OFF_S;
    float* qqt  = ws + OFF_QQT;
    float* kkt  = ws + OFF_KKT;
    float* vpm  = ws + OFF_VP;
    float* p1a  = ws + OFF_P1;
    float* p2a  = ws + OFF_P2;
    float* bn1p = ws + OFF_BN1;
    float* bn2p = ws + OFF_BN2;

    k1_conv1<<<BSZ, 256, 0, stream>>>(x, w1, h1, p1a);
    k2_bn1<<<CEEG, 64, 0, stream>>>(p1a, g1, b1, bn1p);
    dim3 g3(BSZ, 8);
    k3_conv2<<<g3, 256, 0, stream>>>(h1, w2, bn1p, h2, p2a);
    k4_bn2<<<C2, 256, 0, stream>>>(p2a, g2, b2, bn2p);
    k5_gram<<<BSZ*3, 256, 0, stream>>>(h2, bn2p, Sm);
    k6_eig<<<BSZ*3, 256, 0, stream>>>(Sm, wq, wk, wv, qqt, kkt, vpm);
    k7_out<<<BSZ, 64, 0, stream>>>(qqt, kkt, vpm, lw, lb, (float*)d_out);
}

// Round 9
// 532.704 us; speedup vs baseline: 1.2524x; 1.0412x over previous
//
#include <hip/hip_runtime.h>
#include <math.h>

#define PDIM 8
#define BSZ 256
#define CEEG 22
#define TLEN 1000
#define KW 12
#define C2 96
#define TOUT 989
#define TSTR 992          // padded h2 row stride (16B-aligned float4 stores)
#define NSWEEP 7

// ---- workspace layout (in floats) ----
#define OFF_H1   ((size_t)0)
#define SZ_H1    ((size_t)BSZ*CEEG*TLEN)
#define OFF_H2   (OFF_H1 + SZ_H1)
#define SZ_H2    ((size_t)BSZ*C2*TSTR)
#define OFF_S    (OFF_H2 + SZ_H2)
#define SZ_S     ((size_t)BSZ*3*1024)
#define OFF_QQT  (OFF_S + SZ_S)
#define SZ_QQT   ((size_t)BSZ*3*256)
#define OFF_KKT  (OFF_QQT + SZ_QQT)
#define OFF_VP   (OFF_KKT + SZ_QQT)
#define SZ_VP    ((size_t)BSZ*256)
#define OFF_P1   (OFF_VP + SZ_VP)
#define SZ_P1    ((size_t)BSZ*44)
#define OFF_P2   (OFF_P1 + SZ_P1)
#define SZ_P2    ((size_t)BSZ*8*192)
#define OFF_BN1  (OFF_P2 + SZ_P2)
#define OFF_BN2  (OFF_BN1 + (size_t)64)

// ================= K1: conv1 (22ch spatial filter) + BN1 partial stats ==========
__global__ __launch_bounds__(256) void k1_conv1(const float* __restrict__ x,
        const float* __restrict__ w1, float* __restrict__ h1,
        float* __restrict__ part1) {
    __shared__ float sw[CEEG*CEEG];       // [o][c]
    __shared__ float red[4][44];
    int b = blockIdx.x;
    int tid = threadIdx.x;
    for (int i = tid; i < CEEG*CEEG; i += 256) sw[i] = w1[i];
    __syncthreads();
    float sum[CEEG], sumsq[CEEG];
    #pragma unroll
    for (int o = 0; o < CEEG; ++o) { sum[o] = 0.f; sumsq[o] = 0.f; }
    const float* xb = x + (size_t)b*CEEG*TLEN;
    float* hb = h1 + (size_t)b*CEEG*TLEN;
    for (int it = 0; it < 4; ++it) {
        int t = it*256 + tid;
        if (t < TLEN) {
            float acc[CEEG];
            #pragma unroll
            for (int o = 0; o < CEEG; ++o) acc[o] = 0.f;
            #pragma unroll 2
            for (int c = 0; c < CEEG; ++c) {
                float xv = xb[c*TLEN + t];
                #pragma unroll
                for (int o = 0; o < CEEG; ++o) acc[o] = fmaf(xv, sw[o*CEEG + c], acc[o]);
            }
            #pragma unroll
            for (int o = 0; o < CEEG; ++o) {
                hb[o*TLEN + t] = acc[o];
                sum[o]  += acc[o];
                sumsq[o] += acc[o]*acc[o];
            }
        }
    }
    int lane = tid & 63, wv = tid >> 6;
    #pragma unroll
    for (int o = 0; o < CEEG; ++o) {
        float s = sum[o], s2 = sumsq[o];
        for (int off = 32; off > 0; off >>= 1) {
            s  += __shfl_down(s,  off, 64);
            s2 += __shfl_down(s2, off, 64);
        }
        if (lane == 0) { red[wv][o] = s; red[wv][CEEG + o] = s2; }
    }
    __syncthreads();
    if (tid < 44) {
        part1[(size_t)b*44 + tid] = red[0][tid] + red[1][tid] + red[2][tid] + red[3][tid];
    }
}

// ================= K2: finalize BN1 params (1 block / channel) ==========
__global__ __launch_bounds__(64) void k2_bn1(const float* __restrict__ part1,
        const float* __restrict__ g, const float* __restrict__ bta, float* __restrict__ p1) {
    int c = blockIdx.x, t = threadIdx.x;
    float s = 0.f, s2 = 0.f;
    for (int blk = t; blk < BSZ; blk += 64) {
        s  += part1[(size_t)blk*44 + c];
        s2 += part1[(size_t)blk*44 + CEEG + c];
    }
    for (int off = 32; off > 0; off >>= 1) {
        s  += __shfl_down(s,  off, 64);
        s2 += __shfl_down(s2, off, 64);
    }
    if (t == 0) {
        double N = (double)BSZ * (double)TLEN;
        double mu = (double)s / N, var = (double)s2 / N - mu*mu;
        double scale = (double)g[c] / sqrt(var + 1e-5);
        p1[c] = (float)scale;
        p1[CEEG + c] = (float)((double)bta[c] - mu*scale);
    }
}

// ===== K3 v5: R4 structure (3o x 16t, dbuf, 1 barrier/c) + float4 prefetch ====
__global__ __launch_bounds__(256) void k3_conv2(const float* __restrict__ h1,
        const float* __restrict__ w2, const float* __restrict__ p1,
        float* __restrict__ h2, float* __restrict__ part2) {
    __shared__ float sin_[CEEG][160];       // staged input (BN1+ELU), 16B-aligned rows
    __shared__ float swt[2][C2*14];         // double-buffered weights [o][14]
    __shared__ float rStat[C2][20];         // per-(o, tgroup) partial sums
    int b = blockIdx.x;
    int tile = blockIdx.y;                  // 0..7
    int t0 = tile * 128;
    int tid = threadIdx.x;
    int og = tid & 31;                      // o base = 3*og
    int tg = tid >> 5;                      // t base = 16*tg
    int ob = 3*og;
    const float* hb = h1 + (size_t)b*CEEG*TLEN;

    // stage input window [t0, t0+139] with BN1+ELU; zero beyond TLEN
    for (int i = tid; i < CEEG*140; i += 256) {
        int c = i / 140, tt = i - c*140;
        float v = 0.f;
        int t = t0 + tt;
        if (t < TLEN) {
            float z = fmaf(hb[c*TLEN + t], p1[c], p1[CEEG + c]);
            v = z > 0.f ? z : expm1f(z);
        }
        sin_[c][tt] = v;
    }
    // stage weights for c=0 into buf 0: 288 float4 loads block-wide
    for (int i = tid; i < 288; i += 256) {
        int o = i / 3, u = i - 3*o;
        float4 w4 = *(const float4*)&w2[o*264 + 4*u];
        float* dst = &swt[0][o*14 + 4*u];
        *(float2*)&dst[0] = make_float2(w4.x, w4.y);
        *(float2*)&dst[2] = make_float2(w4.z, w4.w);
    }
    __syncthreads();

    float acc[3][16];
    #pragma unroll
    for (int j = 0; j < 3; ++j)
        #pragma unroll
        for (int i = 0; i < 16; ++i) acc[j][i] = 0.f;

    for (int c = 0; c < CEEG; ++c) {
        int buf = c & 1;
        // prefetch weights for c+1 into other buffer (float4 global, 2x b64 LDS)
        if (c + 1 < CEEG) {
            const float* wsrc = w2 + (c + 1)*12;
            for (int i = tid; i < 288; i += 256) {
                int o = i / 3, u = i - 3*o;
                float4 w4 = *(const float4*)&wsrc[o*264 + 4*u];
                float* dst = &swt[buf ^ 1][o*14 + 4*u];
                *(float2*)&dst[0] = make_float2(w4.x, w4.y);
                *(float2*)&dst[2] = make_float2(w4.z, w4.w);
            }
        }
        // load this thread's weights (float2, 2-way bank alias = free)
        float aw[3][12];
        #pragma unroll
        for (int j = 0; j < 3; ++j) {
            const float2* wr = (const float2*)&swt[buf][(ob + j)*14];
            #pragma unroll
            for (int h = 0; h < 6; ++h) {
                float2 wv2 = wr[h];
                aw[j][2*h] = wv2.x; aw[j][2*h + 1] = wv2.y;
            }
        }
        // load input window (float4 broadcast: 2 distinct addrs per wave)
        float bw[28];
        const float4* br = (const float4*)&sin_[c][tg*16];
        #pragma unroll
        for (int h = 0; h < 7; ++h) {
            float4 bv = br[h];
            bw[4*h] = bv.x; bw[4*h+1] = bv.y; bw[4*h+2] = bv.z; bw[4*h+3] = bv.w;
        }
        #pragma unroll
        for (int k = 0; k < KW; ++k) {
            #pragma unroll
            for (int j = 0; j < 3; ++j) {
                float a = aw[j][k];
                #pragma unroll
                for (int i = 0; i < 16; ++i)
                    acc[j][i] = fmaf(a, bw[i + k], acc[j][i]);
            }
        }
        __syncthreads();
    }

    // stores + BN2 partial stats
    float* h2b = h2 + (size_t)b*C2*TSTR;
    int tbase = t0 + tg*16;
    #pragma unroll
    for (int j = 0; j < 3; ++j) {
        int o = ob + j;
        float s = 0.f, s2 = 0.f;
        if (tbase + 15 < TOUT) {
            float* dst = &h2b[(size_t)o*TSTR + tbase];
            #pragma unroll
            for (int h = 0; h < 4; ++h) {
                *(float4*)&dst[4*h] = make_float4(acc[j][4*h], acc[j][4*h+1], acc[j][4*h+2], acc[j][4*h+3]);
                #pragma unroll
                for (int u = 0; u < 4; ++u) {
                    float v = acc[j][4*h + u];
                    s += v; s2 += v*v;
                }
            }
        } else {
            #pragma unroll
            for (int i = 0; i < 16; ++i) {
                int t = tbase + i;
                if (t < TOUT) {
                    float v = acc[j][i];
                    h2b[(size_t)o*TSTR + t] = v;
                    s += v; s2 += v*v;
                }
            }
        }
        rStat[o][2*tg]     = s;
        rStat[o][2*tg + 1] = s2;
    }
    __syncthreads();
    if (tid < C2) {
        float s = 0.f, s2 = 0.f;
        #pragma unroll
        for (int g2 = 0; g2 < 8; ++g2) { s += rStat[tid][2*g2]; s2 += rStat[tid][2*g2+1]; }
        float* pb = part2 + ((size_t)b*8 + tile)*192;
        pb[tid] = s; pb[96 + tid] = s2;
    }
}

// ================= K4: finalize BN2 params (1 block / channel) ==========
__global__ __launch_bounds__(256) void k4_bn2(const float* __restrict__ part2,
        const float* __restrict__ g, const float* __restrict__ bta, float* __restrict__ p2) {
    __shared__ float rs[4], rs2[4];
    int q = blockIdx.x, t = threadIdx.x;
    float s = 0.f, s2 = 0.f;
    for (int blk = t; blk < BSZ*8; blk += 256) {
        s  += part2[(size_t)blk*192 + q];
        s2 += part2[(size_t)blk*192 + 96 + q];
    }
    for (int off = 32; off > 0; off >>= 1) {
        s  += __shfl_down(s,  off, 64);
        s2 += __shfl_down(s2, off, 64);
    }
    int lane = t & 63, wv = t >> 6;
    if (lane == 0) { rs[wv] = s; rs2[wv] = s2; }
    __syncthreads();
    if (t == 0) {
        double S  = (double)rs[0]  + rs[1]  + rs[2]  + rs[3];
        double S2 = (double)rs2[0] + rs2[1] + rs2[2] + rs2[3];
        double N = (double)BSZ * (double)TOUT;
        double mu = S / N, var = S2 / N - mu*mu;
        double scale = (double)g[q] / sqrt(var + 1e-5);
        p2[q] = (float)scale;
        p2[C2 + q] = (float)((double)bta[q] - mu*scale);
    }
}

// ================= K5: BN2+ELU fused Gram matrices S[b][m] = X X^T ==========
__global__ __launch_bounds__(256) void k5_gram(const float* __restrict__ h2,
        const float* __restrict__ p2, float* __restrict__ S) {
    __shared__ float sx[32][68];
    int bm = blockIdx.x;
    int b = bm / 3, m = bm % 3;
    int tid = threadIdx.x;
    int r0 = (tid >> 4) * 2;
    int c0 = (tid & 15) * 2;
    float a00 = 0.f, a01 = 0.f, a10 = 0.f, a11 = 0.f;
    const float* hb = h2 + ((size_t)b*C2 + m*32)*TSTR;
    int row = tid >> 3;
    int ts  = (tid & 7) * 8;
    float sc = p2[m*32 + row], sh = p2[C2 + m*32 + row];
    for (int t0 = 0; t0 < TOUT; t0 += 64) {
        __syncthreads();
        #pragma unroll
        for (int j = 0; j < 8; ++j) {
            int t = t0 + ts + j;
            float v = 0.f;
            if (t < TOUT) {
                float z = fmaf(hb[(size_t)row*TSTR + t], sc, sh);
                v = z > 0.f ? z : expm1f(z);
            }
            sx[row][ts + j] = v;
        }
        __syncthreads();
        #pragma unroll
        for (int tt = 0; tt < 64; tt += 4) {
            float4 va0 = *(const float4*)&sx[r0][tt];
            float4 va1 = *(const float4*)&sx[r0+1][tt];
            float4 vb0 = *(const float4*)&sx[c0][tt];
            float4 vb1 = *(const float4*)&sx[c0+1][tt];
            a00 = fmaf(va0.x, vb0.x, fmaf(va0.y, vb0.y, fmaf(va0.z, vb0.z, fmaf(va0.w, vb0.w, a00))));
            a01 = fmaf(va0.x, vb1.x, fmaf(va0.y, vb1.y, fmaf(va0.z, vb1.z, fmaf(va0.w, vb1.w, a01))));
            a10 = fmaf(va1.x, vb0.x, fmaf(va1.y, vb0.y, fmaf(va1.z, vb0.z, fmaf(va1.w, vb0.w, a10))));
            a11 = fmaf(va1.x, vb1.x, fmaf(va1.y, vb1.y, fmaf(va1.z, vb1.z, fmaf(va1.w, vb1.w, a11))));
        }
    }
    float* Sb = S + (size_t)bm*1024;
    Sb[r0*32 + c0]       = a00;
    Sb[r0*32 + c0 + 1]   = a01;
    Sb[(r0+1)*32 + c0]   = a10;
    Sb[(r0+1)*32 + c0+1] = a11;
}

// ================= K6 v3 (R4-best): 256 thr/matrix, b64 V, f2 cs ======
__device__ __forceinline__ void pair_of(int r, int k, int& p, int& q) {
    if (k == 0) { p = r; q = 31; }
    else {
        int a = (r + k) % 31;
        int b2 = (r - k + 31) % 31;
        p = min(a, b2); q = max(a, b2);
    }
}

__global__ __launch_bounds__(256) void k6_eig(const float* __restrict__ S,
        const float* __restrict__ wq, const float* __restrict__ wk, const float* __restrict__ wv,
        float* __restrict__ QQt, float* __restrict__ KKt, float* __restrict__ Vp) {
    __shared__ float A[32][33];
    __shared__ float Vt[32][34];            // V transposed: Vt[col][row], even stride
    __shared__ float2 cs2[16];
    __shared__ float sW[3][512];
    __shared__ unsigned int ptab[31*16];
    __shared__ float Up[32][9];
    __shared__ float Aw[16][9];
    __shared__ float G[8][9];
    __shared__ float Lm[8][9];
    __shared__ float Mm[16][9];
    __shared__ float lam[32];
    int bm = blockIdx.x, b = bm / 3, m = bm % 3;
    int tid = threadIdx.x;
    const float* Sb = S + (size_t)bm*1024;
    for (int i = tid; i < 1024; i += 256) {
        int r_ = i >> 5, c_ = i & 31;
        A[r_][c_] = Sb[i];
        Vt[r_][c_] = (r_ == c_) ? 1.f : 0.f;
    }
    for (int i = tid; i < 512; i += 256) {
        sW[0][i] = wq[i]; sW[1][i] = wk[i]; sW[2][i] = wv[i];
    }
    for (int i = tid; i < 31*16; i += 256) {
        int r_ = i >> 4, k_ = i & 15;
        int p, q; pair_of(r_, k_, p, q);
        ptab[i] = (unsigned)p | ((unsigned)q << 16);
    }
    __syncthreads();

    int kk_ = tid >> 4, ll_ = tid & 15;
    int i0 = kk_ * 2;
    for (int sweep = 0; sweep < NSWEEP; ++sweep) {
        for (int r = 0; r < 31; ++r) {
            if (tid < 16) {
                unsigned pq = ptab[(r << 4) + tid];
                int p = pq & 0xffff, q = pq >> 16;
                float app = A[p][p], aqq = A[q][q], apq = A[p][q];
                float c = 1.f, s = 0.f;
                if (apq != 0.f) {
                    float tau = (aqq - app) / (2.f * apq);
                    float tt = (tau >= 0.f ? 1.f : -1.f) / (fabsf(tau) + sqrtf(1.f + tau*tau));
                    c = 1.f / sqrtf(1.f + tt*tt);
                    s = tt * c;
                    if (!(c == c) || !(s == s)) { c = 1.f; s = 0.f; }
                }
                cs2[tid] = make_float2(c, s);
            }
            __syncthreads();
            {
                unsigned pqk = ptab[(r << 4) + kk_];
                unsigned pql = ptab[(r << 4) + ll_];
                int p = pqk & 0xffff, q = pqk >> 16;
                int rr = pql & 0xffff, ss = pql >> 16;
                float2 ck2 = cs2[kk_], cl2 = cs2[ll_];
                float ck = ck2.x, sk = ck2.y, cl = cl2.x, sl = cl2.y;
                float apr = A[p][rr], aps = A[p][ss], aqr = A[q][rr], aqs = A[q][ss];
                float tpr = ck*apr - sk*aqr;
                float tqr = sk*apr + ck*aqr;
                float tps = ck*aps - sk*aqs;
                float tqs = sk*aps + ck*aqs;
                A[p][rr] = cl*tpr - sl*tps;
                A[p][ss] = sl*tpr + cl*tps;
                A[q][rr] = cl*tqr - sl*tqs;
                A[q][ss] = sl*tqr + cl*tqs;
                // V update (transposed layout): cols rr,ss of V = rows of Vt
                float2 vr = *(const float2*)&Vt[rr][i0];
                float2 vs = *(const float2*)&Vt[ss][i0];
                float2 nvr, nvs;
                nvr.x = cl*vr.x - sl*vs.x;
                nvr.y = cl*vr.y - sl*vs.y;
                nvs.x = sl*vr.x + cl*vs.x;
                nvs.y = sl*vr.y + cl*vs.y;
                *(float2*)&Vt[rr][i0] = nvr;
                *(float2*)&Vt[ss][i0] = nvs;
            }
            __syncthreads();
        }
    }

    // top-8 eigenvalue selection (descending) -> Up (Up[row][rank] = Vt[col][row])
    if (tid < 32) lam[tid] = A[tid][tid];
    __syncthreads();
    if (tid < 32) {
        float lj = lam[tid];
        int rank = 0;
        #pragma unroll
        for (int i = 0; i < 32; ++i) {
            float li = lam[i];
            rank += (li > lj) || (li == lj && i < tid);
        }
        if (rank < PDIM) {
            #pragma unroll
            for (int i = 0; i < 32; ++i) Up[i][rank] = Vt[tid][i];
        }
    }
    __syncthreads();

    // projections: P = A (A^T A)^{-1} A^T for A = W * Up  (== qr(A).Q @ Q^T)
    for (int widx = 0; widx < 3; ++widx) {
        if (widx == 2 && m != 2) break;   // V-projection only needed for m==2
        const float* W = sW[widx];
        if (tid < 128) {
            int o = tid >> 3, pp = tid & 7;
            float s = 0.f;
            #pragma unroll
            for (int i = 0; i < 32; ++i) s = fmaf(W[o*32 + i], Up[i][pp], s);
            Aw[o][pp] = s;
        }
        __syncthreads();
        if (tid < 64) {
            int xx = tid >> 3, yy = tid & 7;
            float s = 0.f;
            #pragma unroll
            for (int o = 0; o < 16; ++o) s = fmaf(Aw[o][xx], Aw[o][yy], s);
            G[xx][yy] = s;
        }
        __syncthreads();
        if (tid == 0) {
            float Lr[8][8];
            #pragma unroll
            for (int jj = 0; jj < 8; ++jj) {
                float d = G[jj][jj];
                #pragma unroll
                for (int kk = 0; kk < 8; ++kk) if (kk < jj) d -= Lr[jj][kk]*Lr[jj][kk];
                d = sqrtf(fmaxf(d, 1e-30f));
                float inv = 1.f / d;
                Lr[jj][jj] = d;
                Lm[jj][jj] = inv;     // store INVERSE of diagonal
                #pragma unroll
                for (int ii = 0; ii < 8; ++ii) if (ii > jj) {
                    float v = G[ii][jj];
                    #pragma unroll
                    for (int kk = 0; kk < 8; ++kk) if (kk < jj) v -= Lr[ii][kk]*Lr[jj][kk];
                    v *= inv;
                    Lr[ii][jj] = v;
                    Lm[ii][jj] = v;
                }
            }
        }
        __syncthreads();
        if (tid < 16) {
            int o = tid;
            float a[8], mv[8];
            #pragma unroll
            for (int pp = 0; pp < 8; ++pp) a[pp] = Aw[o][pp];
            #pragma unroll
            for (int jj = 0; jj < 8; ++jj) {
                float v = a[jj];
                #pragma unroll
                for (int kk = 0; kk < 8; ++kk) if (kk < jj) v -= Lm[jj][kk]*mv[kk];
                mv[jj] = v * Lm[jj][jj];
            }
            #pragma unroll
            for (int pp = 0; pp < 8; ++pp) Mm[o][pp] = mv[pp];
        }
        __syncthreads();
        {
            int d = tid >> 4, e = tid & 15;
            float s = 0.f;
            #pragma unroll
            for (int pp = 0; pp < 8; ++pp) s = fmaf(Mm[d][pp], Mm[e][pp], s);
            float* dst = (widx == 0) ? (QQt + (size_t)bm*256)
                       : (widx == 1) ? (KKt + (size_t)bm*256)
                       : (Vp + (size_t)b*256);
            dst[d*16 + e] = s;
        }
        __syncthreads();
    }
}

// ================= K7: attention scores + softmax(i=2) + output linear ==========
__global__ __launch_bounds__(64) void k7_out(const float* __restrict__ QQt,
        const float* __restrict__ KKt, const float* __restrict__ Vp,
        const float* __restrict__ lw, const float* __restrict__ lb,
        float* __restrict__ out) {
    __shared__ float sQ[3][256], sK[3][256], sVp[256], ssc[9], wj[3];
    int b = blockIdx.x, tid = threadIdx.x;
    for (int i = tid; i < 768; i += 64) {
        sQ[i >> 8][i & 255] = QQt[(size_t)b*768 + i];
        sK[i >> 8][i & 255] = KKt[(size_t)b*768 + i];
    }
    for (int i = tid; i < 256; i += 64) sVp[i] = Vp[(size_t)b*256 + i];
    __syncthreads();
    for (int pair = 0; pair < 9; ++pair) {
        int i = pair / 3, j = pair % 3;
        const float* Qj = sQ[j];
        const float* Ki = sK[i];
        float accp = 0.f;
        #pragma unroll
        for (int it = 0; it < 4; ++it) {
            int e = tid + 64*it;
            int d = e >> 4, ee = e & 15;
            float y = 0.f;
            #pragma unroll
            for (int f = 0; f < 16; ++f) {
                float dv = Qj[d*16 + f] - Ki[d*16 + f];
                float ev = Qj[ee*16 + f] - Ki[ee*16 + f];
                y = fmaf(dv, ev, y);
            }
            accp += y*y;
        }
        for (int off = 32; off > 0; off >>= 1) accp += __shfl_down(accp, off, 64);
        if (tid == 0) {
            float E = sqrtf(accp);
            ssc[pair] = 1.f / (1.f + log1pf(E));
        }
        __syncthreads();
    }
    if (tid < 3) {
        int j = tid;
        float e0 = expf(ssc[0*3 + j]), e1 = expf(ssc[1*3 + j]), e2 = expf(ssc[2*3 + j]);
        wj[j] = e2 / (e0 + e1 + e2);
    }
    __syncthreads();
    int o = tid >> 4, g = tid & 15;
    float part = 0.f;
    #pragma unroll
    for (int t = 0; t < 16; ++t) {
        int de = g*16 + t;
        float vv = sVp[de];
        float l0 = lw[o*768 + de];
        float l1 = lw[o*768 + 256 + de];
        float l2 = lw[o*768 + 512 + de];
        part = fmaf(vv, fmaf(wj[0], l0, fmaf(wj[1], l1, wj[2]*l2)), part);
    }
    for (int off = 8; off > 0; off >>= 1) part += __shfl_down(part, off, 16);
    if (g == 0) out[b*4 + o] = part + lb[o];
}

// ================= launch ==========
extern "C" void kernel_launch(void* const* d_in, const int* in_sizes, int n_in,
                              void* d_out, int out_size, void* d_ws, size_t ws_size,
                              hipStream_t stream) {
    const float* x  = (const float*)d_in[0];
    const float* w1 = (const float*)d_in[1];
    // d_in[2] conv1_b: cancels exactly in batch-norm (mean subtraction) -> unused
    const float* g1 = (const float*)d_in[3];
    const float* b1 = (const float*)d_in[4];
    const float* w2 = (const float*)d_in[5];
    // d_in[6] conv2_b: cancels exactly in batch-norm -> unused
    const float* g2 = (const float*)d_in[7];
    const float* b2 = (const float*)d_in[8];
    const float* wq = (const float*)d_in[9];
    const float* wk = (const float*)d_in[10];
    const float* wv = (const float*)d_in[11];
    const float* lw = (const float*)d_in[12];
    const float* lb = (const float*)d_in[13];

    float* ws   = (float*)d_ws;
    float* h1   = ws + OFF_H1;
    float* h2   = ws + OFF_H2;
    float* Sm   = ws + OFF_S;
    float* qqt  = ws + OFF_QQT;
    float* kkt  = ws + OFF_KKT;
    float* vpm  = ws + OFF_VP;
    float* p1a  = ws + OFF_P1;
    float* p2a  = ws + OFF_P2;
    float* bn1p = ws + OFF_BN1;
    float* bn2p = ws + OFF_BN2;

    k1_conv1<<<BSZ, 256, 0, stream>>>(x, w1, h1, p1a);
    k2_bn1<<<CEEG, 64, 0, stream>>>(p1a, g1, b1, bn1p);
    dim3 g3(BSZ, 8);
    k3_conv2<<<g3, 256, 0, stream>>>(h1, w2, bn1p, h2, p2a);
    k4_bn2<<<C2, 256, 0, stream>>>(p2a, g2, b2, bn2p);
    k5_gram<<<BSZ*3, 256, 0, stream>>>(h2, bn2p, Sm);
    k6_eig<<<BSZ*3, 256, 0, stream>>>(Sm, wq, wk, wv, qqt, kkt, vpm);
    k7_out<<<BSZ, 64, 0, stream>>>(qqt, kkt, vpm, lw, lb, (float*)d_out);
}

// Round 10
// 497.918 us; speedup vs baseline: 1.3399x; 1.0699x over previous
//
#include <hip/hip_runtime.h>
#include <math.h>

#define PDIM 8
#define BSZ 256
#define CEEG 22
#define TLEN 1000
#define KW 12
#define C2 96
#define TOUT 989
#define TSTR 992          // padded h2 row stride (16B-aligned float4 stores)
#define NSWEEP 6

// ---- workspace layout (in floats) ----
#define OFF_H1   ((size_t)0)
#define SZ_H1    ((size_t)BSZ*CEEG*TLEN)
#define OFF_H2   (OFF_H1 + SZ_H1)
#define SZ_H2    ((size_t)BSZ*C2*TSTR)
#define OFF_S    (OFF_H2 + SZ_H2)
#define SZ_S     ((size_t)BSZ*3*1024)
#define OFF_QQT  (OFF_S + SZ_S)
#define SZ_QQT   ((size_t)BSZ*3*256)
#define OFF_KKT  (OFF_QQT + SZ_QQT)
#define OFF_VP   (OFF_KKT + SZ_QQT)
#define SZ_VP    ((size_t)BSZ*256)
#define OFF_P1   (OFF_VP + SZ_VP)
#define SZ_P1    ((size_t)BSZ*44)
#define OFF_P2   (OFF_P1 + SZ_P1)
#define SZ_P2    ((size_t)BSZ*8*192)
#define OFF_BN1  (OFF_P2 + SZ_P2)
#define OFF_BN2  (OFF_BN1 + (size_t)64)

__device__ __forceinline__ float elu_f(float z) { return z > 0.f ? z : expm1f(z); }

// ================= K1: conv1 (22ch spatial filter) + BN1 partial stats ==========
__global__ __launch_bounds__(256) void k1_conv1(const float* __restrict__ x,
        const float* __restrict__ w1, float* __restrict__ h1,
        float* __restrict__ part1) {
    __shared__ float sw[CEEG*CEEG];       // [o][c]
    __shared__ float red[4][44];
    int b = blockIdx.x;
    int tid = threadIdx.x;
    for (int i = tid; i < CEEG*CEEG; i += 256) sw[i] = w1[i];
    __syncthreads();
    float sum[CEEG], sumsq[CEEG];
    #pragma unroll
    for (int o = 0; o < CEEG; ++o) { sum[o] = 0.f; sumsq[o] = 0.f; }
    const float* xb = x + (size_t)b*CEEG*TLEN;
    float* hb = h1 + (size_t)b*CEEG*TLEN;
    for (int it = 0; it < 4; ++it) {
        int t = it*256 + tid;
        if (t < TLEN) {
            float acc[CEEG];
            #pragma unroll
            for (int o = 0; o < CEEG; ++o) acc[o] = 0.f;
            #pragma unroll 2
            for (int c = 0; c < CEEG; ++c) {
                float xv = xb[c*TLEN + t];
                #pragma unroll
                for (int o = 0; o < CEEG; ++o) acc[o] = fmaf(xv, sw[o*CEEG + c], acc[o]);
            }
            #pragma unroll
            for (int o = 0; o < CEEG; ++o) {
                hb[o*TLEN + t] = acc[o];
                sum[o]  += acc[o];
                sumsq[o] += acc[o]*acc[o];
            }
        }
    }
    int lane = tid & 63, wv = tid >> 6;
    #pragma unroll
    for (int o = 0; o < CEEG; ++o) {
        float s = sum[o], s2 = sumsq[o];
        for (int off = 32; off > 0; off >>= 1) {
            s  += __shfl_down(s,  off, 64);
            s2 += __shfl_down(s2, off, 64);
        }
        if (lane == 0) { red[wv][o] = s; red[wv][CEEG + o] = s2; }
    }
    __syncthreads();
    if (tid < 44) {
        part1[(size_t)b*44 + tid] = red[0][tid] + red[1][tid] + red[2][tid] + red[3][tid];
    }
}

// ================= K2: finalize BN1 params (1 block / channel) ==========
__global__ __launch_bounds__(64) void k2_bn1(const float* __restrict__ part1,
        const float* __restrict__ g, const float* __restrict__ bta, float* __restrict__ p1) {
    int c = blockIdx.x, t = threadIdx.x;
    float s = 0.f, s2 = 0.f;
    for (int blk = t; blk < BSZ; blk += 64) {
        s  += part1[(size_t)blk*44 + c];
        s2 += part1[(size_t)blk*44 + CEEG + c];
    }
    for (int off = 32; off > 0; off >>= 1) {
        s  += __shfl_down(s,  off, 64);
        s2 += __shfl_down(s2, off, 64);
    }
    if (t == 0) {
        double N = (double)BSZ * (double)TLEN;
        double mu = (double)s / N, var = (double)s2 / N - mu*mu;
        double scale = (double)g[c] / sqrt(var + 1e-5);
        p1[c] = (float)scale;
        p1[CEEG + c] = (float)((double)bta[c] - mu*scale);
    }
}

// ===== K3 v5 (R9-best): 3o x 16t, dbuf, 1 barrier/c, float4 prefetch ====
__global__ __launch_bounds__(256) void k3_conv2(const float* __restrict__ h1,
        const float* __restrict__ w2, const float* __restrict__ p1,
        float* __restrict__ h2, float* __restrict__ part2) {
    __shared__ float sin_[CEEG][160];       // staged input (BN1+ELU), 16B-aligned rows
    __shared__ float swt[2][C2*14];         // double-buffered weights [o][14]
    __shared__ float rStat[C2][20];         // per-(o, tgroup) partial sums
    int b = blockIdx.x;
    int tile = blockIdx.y;                  // 0..7
    int t0 = tile * 128;
    int tid = threadIdx.x;
    int og = tid & 31;                      // o base = 3*og
    int tg = tid >> 5;                      // t base = 16*tg
    int ob = 3*og;
    const float* hb = h1 + (size_t)b*CEEG*TLEN;

    // stage input window [t0, t0+139] with BN1+ELU; zero beyond TLEN
    for (int i = tid; i < CEEG*140; i += 256) {
        int c = i / 140, tt = i - c*140;
        float v = 0.f;
        int t = t0 + tt;
        if (t < TLEN) {
            float z = fmaf(hb[c*TLEN + t], p1[c], p1[CEEG + c]);
            v = z > 0.f ? z : expm1f(z);
        }
        sin_[c][tt] = v;
    }
    // stage weights for c=0 into buf 0: 288 float4 loads block-wide
    for (int i = tid; i < 288; i += 256) {
        int o = i / 3, u = i - 3*o;
        float4 w4 = *(const float4*)&w2[o*264 + 4*u];
        float* dst = &swt[0][o*14 + 4*u];
        *(float2*)&dst[0] = make_float2(w4.x, w4.y);
        *(float2*)&dst[2] = make_float2(w4.z, w4.w);
    }
    __syncthreads();

    float acc[3][16];
    #pragma unroll
    for (int j = 0; j < 3; ++j)
        #pragma unroll
        for (int i = 0; i < 16; ++i) acc[j][i] = 0.f;

    for (int c = 0; c < CEEG; ++c) {
        int buf = c & 1;
        // prefetch weights for c+1 into other buffer (float4 global, 2x b64 LDS)
        if (c + 1 < CEEG) {
            const float* wsrc = w2 + (c + 1)*12;
            for (int i = tid; i < 288; i += 256) {
                int o = i / 3, u = i - 3*o;
                float4 w4 = *(const float4*)&wsrc[o*264 + 4*u];
                float* dst = &swt[buf ^ 1][o*14 + 4*u];
                *(float2*)&dst[0] = make_float2(w4.x, w4.y);
                *(float2*)&dst[2] = make_float2(w4.z, w4.w);
            }
        }
        // load this thread's weights (float2, 2-way bank alias = free)
        float aw[3][12];
        #pragma unroll
        for (int j = 0; j < 3; ++j) {
            const float2* wr = (const float2*)&swt[buf][(ob + j)*14];
            #pragma unroll
            for (int h = 0; h < 6; ++h) {
                float2 wv2 = wr[h];
                aw[j][2*h] = wv2.x; aw[j][2*h + 1] = wv2.y;
            }
        }
        // load input window (float4 broadcast: 2 distinct addrs per wave)
        float bw[28];
        const float4* br = (const float4*)&sin_[c][tg*16];
        #pragma unroll
        for (int h = 0; h < 7; ++h) {
            float4 bv = br[h];
            bw[4*h] = bv.x; bw[4*h+1] = bv.y; bw[4*h+2] = bv.z; bw[4*h+3] = bv.w;
        }
        #pragma unroll
        for (int k = 0; k < KW; ++k) {
            #pragma unroll
            for (int j = 0; j < 3; ++j) {
                float a = aw[j][k];
                #pragma unroll
                for (int i = 0; i < 16; ++i)
                    acc[j][i] = fmaf(a, bw[i + k], acc[j][i]);
            }
        }
        __syncthreads();
    }

    // stores + BN2 partial stats
    float* h2b = h2 + (size_t)b*C2*TSTR;
    int tbase = t0 + tg*16;
    #pragma unroll
    for (int j = 0; j < 3; ++j) {
        int o = ob + j;
        float s = 0.f, s2 = 0.f;
        if (tbase + 15 < TOUT) {
            float* dst = &h2b[(size_t)o*TSTR + tbase];
            #pragma unroll
            for (int h = 0; h < 4; ++h) {
                *(float4*)&dst[4*h] = make_float4(acc[j][4*h], acc[j][4*h+1], acc[j][4*h+2], acc[j][4*h+3]);
                #pragma unroll
                for (int u = 0; u < 4; ++u) {
                    float v = acc[j][4*h + u];
                    s += v; s2 += v*v;
                }
            }
        } else {
            #pragma unroll
            for (int i = 0; i < 16; ++i) {
                int t = tbase + i;
                if (t < TOUT) {
                    float v = acc[j][i];
                    h2b[(size_t)o*TSTR + t] = v;
                    s += v; s2 += v*v;
                }
            }
        }
        rStat[o][2*tg]     = s;
        rStat[o][2*tg + 1] = s2;
    }
    __syncthreads();
    if (tid < C2) {
        float s = 0.f, s2 = 0.f;
        #pragma unroll
        for (int g2 = 0; g2 < 8; ++g2) { s += rStat[tid][2*g2]; s2 += rStat[tid][2*g2+1]; }
        float* pb = part2 + ((size_t)b*8 + tile)*192;
        pb[tid] = s; pb[96 + tid] = s2;
    }
}

// ================= K4: finalize BN2 params (1 block / channel) ==========
__global__ __launch_bounds__(256) void k4_bn2(const float* __restrict__ part2,
        const float* __restrict__ g, const float* __restrict__ bta, float* __restrict__ p2) {
    __shared__ float rs[4], rs2[4];
    int q = blockIdx.x, t = threadIdx.x;
    float s = 0.f, s2 = 0.f;
    for (int blk = t; blk < BSZ*8; blk += 256) {
        s  += part2[(size_t)blk*192 + q];
        s2 += part2[(size_t)blk*192 + 96 + q];
    }
    for (int off = 32; off > 0; off >>= 1) {
        s  += __shfl_down(s,  off, 64);
        s2 += __shfl_down(s2, off, 64);
    }
    int lane = t & 63, wv = t >> 6;
    if (lane == 0) { rs[wv] = s; rs2[wv] = s2; }
    __syncthreads();
    if (t == 0) {
        double S  = (double)rs[0]  + rs[1]  + rs[2]  + rs[3];
        double S2 = (double)rs2[0] + rs2[1] + rs2[2] + rs2[3];
        double N = (double)BSZ * (double)TOUT;
        double mu = S / N, var = S2 / N - mu*mu;
        double scale = (double)g[q] / sqrt(var + 1e-5);
        p2[q] = (float)scale;
        p2[C2 + q] = (float)((double)bta[q] - mu*scale);
    }
}

// ===== K5 v2: Gram, 4x4 tiles, wave-private staging, no inner barriers ==========
__global__ __launch_bounds__(256) void k5_gram(const float* __restrict__ h2,
        const float* __restrict__ p2, float* __restrict__ S) {
    __shared__ float smem[4*2176];          // per-wave [32][68]; overlaid red [64][17]
    int bm = blockIdx.x;
    int b = bm / 3, m = bm % 3;
    int tid = threadIdx.x;
    int w = tid >> 6, lane = tid & 63;
    float* sx = smem + w*2176;
    const float* hb = h2 + ((size_t)b*C2 + m*32)*TSTR;
    int srow = lane >> 1;
    int scol = (lane & 1) * 32;
    float sc = p2[m*32 + srow], sh = p2[C2 + m*32 + srow];
    int r0 = (lane >> 3) << 2, c0 = (lane & 7) << 2;
    float acc[4][4];
    #pragma unroll
    for (int i = 0; i < 4; ++i)
        #pragma unroll
        for (int j = 0; j < 4; ++j) acc[i][j] = 0.f;

    // interleaved 64-chunks: wave w takes t0 = (w + 4k)*64
    for (int t0 = w*64; t0 < TOUT; t0 += 256) {
        const float* src = &hb[(size_t)srow*TSTR + t0 + scol];
        float* drow = &sx[srow*68 + scol];
        if (t0 + 63 < TOUT) {
            #pragma unroll
            for (int j = 0; j < 8; ++j) {
                float4 xv = *(const float4*)&src[4*j];
                float4 v;
                v.x = elu_f(fmaf(xv.x, sc, sh));
                v.y = elu_f(fmaf(xv.y, sc, sh));
                v.z = elu_f(fmaf(xv.z, sc, sh));
                v.w = elu_f(fmaf(xv.w, sc, sh));
                *(float4*)&drow[4*j] = v;
            }
        } else {
            #pragma unroll
            for (int j = 0; j < 8; ++j) {
                float4 xv = *(const float4*)&src[4*j];
                int tb = t0 + scol + 4*j;
                float4 v;
                v.x = (tb + 0 < TOUT) ? elu_f(fmaf(xv.x, sc, sh)) : 0.f;
                v.y = (tb + 1 < TOUT) ? elu_f(fmaf(xv.y, sc, sh)) : 0.f;
                v.z = (tb + 2 < TOUT) ? elu_f(fmaf(xv.z, sc, sh)) : 0.f;
                v.w = (tb + 3 < TOUT) ? elu_f(fmaf(xv.w, sc, sh)) : 0.f;
                *(float4*)&drow[4*j] = v;
            }
        }
        // same-wave RAW: in-order LDS + compiler lgkmcnt, no barrier needed
        #pragma unroll
        for (int tc = 0; tc < 16; ++tc) {
            float4 a0 = *(const float4*)&sx[(r0+0)*68 + tc*4];
            float4 a1 = *(const float4*)&sx[(r0+1)*68 + tc*4];
            float4 a2 = *(const float4*)&sx[(r0+2)*68 + tc*4];
            float4 a3 = *(const float4*)&sx[(r0+3)*68 + tc*4];
            float4 b0 = *(const float4*)&sx[(c0+0)*68 + tc*4];
            float4 b1 = *(const float4*)&sx[(c0+1)*68 + tc*4];
            float4 b2 = *(const float4*)&sx[(c0+2)*68 + tc*4];
            float4 b3 = *(const float4*)&sx[(c0+3)*68 + tc*4];
            #pragma unroll
            for (int i = 0; i < 4; ++i) {
                float4 ai = (i == 0) ? a0 : (i == 1) ? a1 : (i == 2) ? a2 : a3;
                acc[i][0] = fmaf(ai.x, b0.x, fmaf(ai.y, b0.y, fmaf(ai.z, b0.z, fmaf(ai.w, b0.w, acc[i][0]))));
                acc[i][1] = fmaf(ai.x, b1.x, fmaf(ai.y, b1.y, fmaf(ai.z, b1.z, fmaf(ai.w, b1.w, acc[i][1]))));
                acc[i][2] = fmaf(ai.x, b2.x, fmaf(ai.y, b2.y, fmaf(ai.z, b2.z, fmaf(ai.w, b2.w, acc[i][2]))));
                acc[i][3] = fmaf(ai.x, b3.x, fmaf(ai.y, b3.y, fmaf(ai.z, b3.z, fmaf(ai.w, b3.w, acc[i][3]))));
            }
        }
    }

    // write partials into own region (same-wave WAR safe), then cross-wave reduce
    float* red = smem + w*2176;
    #pragma unroll
    for (int i = 0; i < 4; ++i)
        #pragma unroll
        for (int j = 0; j < 4; ++j)
            red[lane*17 + i*4 + j] = acc[i][j];
    __syncthreads();
    int e0 = tid * 4;
    int r = e0 >> 5, c = e0 & 31;
    int tl = (r >> 2)*8 + (c >> 2);
    int sb = (r & 3)*4;
    float o0 = 0.f, o1 = 0.f, o2 = 0.f, o3 = 0.f;
    #pragma unroll
    for (int ww = 0; ww < 4; ++ww) {
        const float* rp = smem + ww*2176 + tl*17 + sb;
        o0 += rp[0]; o1 += rp[1]; o2 += rp[2]; o3 += rp[3];
    }
    float* Sb2 = S + (size_t)bm*1024;
    *(float4*)&Sb2[e0] = make_float4(o0, o1, o2, o3);
}

// ================= K6 v3 (R4-best): 256 thr/matrix, b64 V, f2 cs ======
__device__ __forceinline__ void pair_of(int r, int k, int& p, int& q) {
    if (k == 0) { p = r; q = 31; }
    else {
        int a = (r + k) % 31;
        int b2 = (r - k + 31) % 31;
        p = min(a, b2); q = max(a, b2);
    }
}

__global__ __launch_bounds__(256) void k6_eig(const float* __restrict__ S,
        const float* __restrict__ wq, const float* __restrict__ wk, const float* __restrict__ wv,
        float* __restrict__ QQt, float* __restrict__ KKt, float* __restrict__ Vp) {
    __shared__ float A[32][33];
    __shared__ float Vt[32][34];            // V transposed: Vt[col][row], even stride
    __shared__ float2 cs2[16];
    __shared__ float sW[3][512];
    __shared__ unsigned int ptab[31*16];
    __shared__ float Up[32][9];
    __shared__ float Aw[16][9];
    __shared__ float G[8][9];
    __shared__ float Lm[8][9];
    __shared__ float Mm[16][9];
    __shared__ float lam[32];
    int bm = blockIdx.x, b = bm / 3, m = bm % 3;
    int tid = threadIdx.x;
    const float* Sb = S + (size_t)bm*1024;
    for (int i = tid; i < 1024; i += 256) {
        int r_ = i >> 5, c_ = i & 31;
        A[r_][c_] = Sb[i];
        Vt[r_][c_] = (r_ == c_) ? 1.f : 0.f;
    }
    for (int i = tid; i < 512; i += 256) {
        sW[0][i] = wq[i]; sW[1][i] = wk[i]; sW[2][i] = wv[i];
    }
    for (int i = tid; i < 31*16; i += 256) {
        int r_ = i >> 4, k_ = i & 15;
        int p, q; pair_of(r_, k_, p, q);
        ptab[i] = (unsigned)p | ((unsigned)q << 16);
    }
    __syncthreads();

    int kk_ = tid >> 4, ll_ = tid & 15;
    int i0 = kk_ * 2;
    for (int sweep = 0; sweep < NSWEEP; ++sweep) {
        for (int r = 0; r < 31; ++r) {
            if (tid < 16) {
                unsigned pq = ptab[(r << 4) + tid];
                int p = pq & 0xffff, q = pq >> 16;
                float app = A[p][p], aqq = A[q][q], apq = A[p][q];
                float c = 1.f, s = 0.f;
                if (apq != 0.f) {
                    float tau = (aqq - app) / (2.f * apq);
                    float tt = (tau >= 0.f ? 1.f : -1.f) / (fabsf(tau) + sqrtf(1.f + tau*tau));
                    c = 1.f / sqrtf(1.f + tt*tt);
                    s = tt * c;
                    if (!(c == c) || !(s == s)) { c = 1.f; s = 0.f; }
                }
                cs2[tid] = make_float2(c, s);
            }
            __syncthreads();
            {
                unsigned pqk = ptab[(r << 4) + kk_];
                unsigned pql = ptab[(r << 4) + ll_];
                int p = pqk & 0xffff, q = pqk >> 16;
                int rr = pql & 0xffff, ss = pql >> 16;
                float2 ck2 = cs2[kk_], cl2 = cs2[ll_];
                float ck = ck2.x, sk = ck2.y, cl = cl2.x, sl = cl2.y;
                float apr = A[p][rr], aps = A[p][ss], aqr = A[q][rr], aqs = A[q][ss];
                float tpr = ck*apr - sk*aqr;
                float tqr = sk*apr + ck*aqr;
                float tps = ck*aps - sk*aqs;
                float tqs = sk*aps + ck*aqs;
                A[p][rr] = cl*tpr - sl*tps;
                A[p][ss] = sl*tpr + cl*tps;
                A[q][rr] = cl*tqr - sl*tqs;
                A[q][ss] = sl*tqr + cl*tqs;
                // V update (transposed layout): cols rr,ss of V = rows of Vt
                float2 vr = *(const float2*)&Vt[rr][i0];
                float2 vs = *(const float2*)&Vt[ss][i0];
                float2 nvr, nvs;
                nvr.x = cl*vr.x - sl*vs.x;
                nvr.y = cl*vr.y - sl*vs.y;
                nvs.x = sl*vr.x + cl*vs.x;
                nvs.y = sl*vr.y + cl*vs.y;
                *(float2*)&Vt[rr][i0] = nvr;
                *(float2*)&Vt[ss][i0] = nvs;
            }
            __syncthreads();
        }
    }

    // top-8 eigenvalue selection (descending) -> Up (Up[row][rank] = Vt[col][row])
    if (tid < 32) lam[tid] = A[tid][tid];
    __syncthreads();
    if (tid < 32) {
        float lj = lam[tid];
        int rank = 0;
        #pragma unroll
        for (int i = 0; i < 32; ++i) {
            float li = lam[i];
            rank += (li > lj) || (li == lj && i < tid);
        }
        if (rank < PDIM) {
            #pragma unroll
            for (int i = 0; i < 32; ++i) Up[i][rank] = Vt[tid][i];
        }
    }
    __syncthreads();

    // projections: P = A (A^T A)^{-1} A^T for A = W * Up  (== qr(A).Q @ Q^T)
    for (int widx = 0; widx < 3; ++widx) {
        if (widx == 2 && m != 2) break;   // V-projection only needed for m==2
        const float* W = sW[widx];
        if (tid < 128) {
            int o = tid >> 3, pp = tid & 7;
            float s = 0.f;
            #pragma unroll
            for (int i = 0; i < 32; ++i) s = fmaf(W[o*32 + i], Up[i][pp], s);
            Aw[o][pp] = s;
        }
        __syncthreads();
        if (tid < 64) {
            int xx = tid >> 3, yy = tid & 7;
            float s = 0.f;
            #pragma unroll
            for (int o = 0; o < 16; ++o) s = fmaf(Aw[o][xx], Aw[o][yy], s);
            G[xx][yy] = s;
        }
        __syncthreads();
        if (tid == 0) {
            float Lr[8][8];
            #pragma unroll
            for (int jj = 0; jj < 8; ++jj) {
                float d = G[jj][jj];
                #pragma unroll
                for (int kk = 0; kk < 8; ++kk) if (kk < jj) d -= Lr[jj][kk]*Lr[jj][kk];
                d = sqrtf(fmaxf(d, 1e-30f));
                float inv = 1.f / d;
                Lr[jj][jj] = d;
                Lm[jj][jj] = inv;     // store INVERSE of diagonal
                #pragma unroll
                for (int ii = 0; ii < 8; ++ii) if (ii > jj) {
                    float v = G[ii][jj];
                    #pragma unroll
                    for (int kk = 0; kk < 8; ++kk) if (kk < jj) v -= Lr[ii][kk]*Lr[jj][kk];
                    v *= inv;
                    Lr[ii][jj] = v;
                    Lm[ii][jj] = v;
                }
            }
        }
        __syncthreads();
        if (tid < 16) {
            int o = tid;
            float a[8], mv[8];
            #pragma unroll
            for (int pp = 0; pp < 8; ++pp) a[pp] = Aw[o][pp];
            #pragma unroll
            for (int jj = 0; jj < 8; ++jj) {
                float v = a[jj];
                #pragma unroll
                for (int kk = 0; kk < 8; ++kk) if (kk < jj) v -= Lm[jj][kk]*mv[kk];
                mv[jj] = v * Lm[jj][jj];
            }
            #pragma unroll
            for (int pp = 0; pp < 8; ++pp) Mm[o][pp] = mv[pp];
        }
        __syncthreads();
        {
            int d = tid >> 4, e = tid & 15;
            float s = 0.f;
            #pragma unroll
            for (int pp = 0; pp < 8; ++pp) s = fmaf(Mm[d][pp], Mm[e][pp], s);
            float* dst = (widx == 0) ? (QQt + (size_t)bm*256)
                       : (widx == 1) ? (KKt + (size_t)bm*256)
                       : (Vp + (size_t)b*256);
            dst[d*16 + e] = s;
        }
        __syncthreads();
    }
}

// ================= K7: attention scores + softmax(i=2) + output linear ==========
__global__ __launch_bounds__(64) void k7_out(const float* __restrict__ QQt,
        const float* __restrict__ KKt, const float* __restrict__ Vp,
        const float* __restrict__ lw, const float* __restrict__ lb,
        float* __restrict__ out) {
    __shared__ float sQ[3][256], sK[3][256], sVp[256], ssc[9], wj[3];
    int b = blockIdx.x, tid = threadIdx.x;
    for (int i = tid; i < 768; i += 64) {
        sQ[i >> 8][i & 255] = QQt[(size_t)b*768 + i];
        sK[i >> 8][i & 255] = KKt[(size_t)b*768 + i];
    }
    for (int i = tid; i < 256; i += 64) sVp[i] = Vp[(size_t)b*256 + i];
    __syncthreads();
    for (int pair = 0; pair < 9; ++pair) {
        int i = pair / 3, j = pair % 3;
        const float* Qj = sQ[j];
        const float* Ki = sK[i];
        float accp = 0.f;
        #pragma unroll
        for (int it = 0; it < 4; ++it) {
            int e = tid + 64*it;
            int d = e >> 4, ee = e & 15;
            float y = 0.f;
            #pragma unroll
            for (int f = 0; f < 16; ++f) {
                float dv = Qj[d*16 + f] - Ki[d*16 + f];
                float ev = Qj[ee*16 + f] - Ki[ee*16 + f];
                y = fmaf(dv, ev, y);
            }
            accp += y*y;
        }
        for (int off = 32; off > 0; off >>= 1) accp += __shfl_down(accp, off, 64);
        if (tid == 0) {
            float E = sqrtf(accp);
            ssc[pair] = 1.f / (1.f + log1pf(E));
        }
        __syncthreads();
    }
    if (tid < 3) {
        int j = tid;
        float e0 = expf(ssc[0*3 + j]), e1 = expf(ssc[1*3 + j]), e2 = expf(ssc[2*3 + j]);
        wj[j] = e2 / (e0 + e1 + e2);
    }
    __syncthreads();
    int o = tid >> 4, g = tid & 15;
    float part = 0.f;
    #pragma unroll
    for (int t = 0; t < 16; ++t) {
        int de = g*16 + t;
        float vv = sVp[de];
        float l0 = lw[o*768 + de];
        float l1 = lw[o*768 + 256 + de];
        float l2 = lw[o*768 + 512 + de];
        part = fmaf(vv, fmaf(wj[0], l0, fmaf(wj[1], l1, wj[2]*l2)), part);
    }
    for (int off = 8; off > 0; off >>= 1) part += __shfl_down(part, off, 16);
    if (g == 0) out[b*4 + o] = part + lb[o];
}

// ================= launch ==========
extern "C" void kernel_launch(void* const* d_in, const int* in_sizes, int n_in,
                              void* d_out, int out_size, void* d_ws, size_t ws_size,
                              hipStream_t stream) {
    const float* x  = (const float*)d_in[0];
    const float* w1 = (const float*)d_in[1];
    // d_in[2] conv1_b: cancels exactly in batch-norm (mean subtraction) -> unused
    const float* g1 = (const float*)d_in[3];
    const float* b1 = (const float*)d_in[4];
    const float* w2 = (const float*)d_in[5];
    // d_in[6] conv2_b: cancels exactly in batch-norm -> unused
    const float* g2 = (const float*)d_in[7];
    const float* b2 = (const float*)d_in[8];
    const float* wq = (const float*)d_in[9];
    const float* wk = (const float*)d_in[10];
    const float* wv = (const float*)d_in[11];
    const float* lw = (const float*)d_in[12];
    const float* lb = (const float*)d_in[13];

    float* ws   = (float*)d_ws;
    float* h1   = ws + OFF_H1;
    float* h2   = ws + OFF_H2;
    float* Sm   = ws + OFF_S;
    float* qqt  = ws + OFF_QQT;
    float* kkt  = ws + OFF_KKT;
    float* vpm  = ws + OFF_VP;
    float* p1a  = ws + OFF_P1;
    float* p2a  = ws + OFF_P2;
    float* bn1p = ws + OFF_BN1;
    float* bn2p = ws + OFF_BN2;

    k1_conv1<<<BSZ, 256, 0, stream>>>(x, w1, h1, p1a);
    k2_bn1<<<CEEG, 64, 0, stream>>>(p1a, g1, b1, bn1p);
    dim3 g3(BSZ, 8);
    k3_conv2<<<g3, 256, 0, stream>>>(h1, w2, bn1p, h2, p2a);
    k4_bn2<<<C2, 256, 0, stream>>>(p2a, g2, b2, bn2p);
    k5_gram<<<BSZ*3, 256, 0, stream>>>(h2, bn2p, Sm);
    k6_eig<<<BSZ*3, 256, 0, stream>>>(Sm, wq, wk, wv, qqt, kkt, vpm);
    k7_out<<<BSZ, 64, 0, stream>>>(qqt, kkt, vpm, lw, lb, (float*)d_out);
}

// Round 11
// 493.723 us; speedup vs baseline: 1.3513x; 1.0085x over previous
//
#include <hip/hip_runtime.h>
#include <math.h>

#define PDIM 8
#define BSZ 256
#define CEEG 22
#define TLEN 1000
#define KW 12
#define C2 96
#define TOUT 989
#define TSTR 992          // padded h2 row stride (16B-aligned float4 stores)
#define NSWEEP 6
#define NT16 16           // k3 t-tiles of 64
#define NPART (BSZ*NT16)  // BN2 stat partial groups

typedef __attribute__((ext_vector_type(8))) short short8;
typedef __attribute__((ext_vector_type(4))) float floatx4;

// ---- workspace layout (in floats) ----
#define OFF_H1   ((size_t)0)
#define SZ_H1    ((size_t)BSZ*CEEG*TLEN)
#define OFF_H2   (OFF_H1 + SZ_H1)
#define SZ_H2    ((size_t)BSZ*C2*TSTR)
#define OFF_S    (OFF_H2 + SZ_H2)
#define SZ_S     ((size_t)BSZ*3*1024)
// Whi/Wlo (bf16, 96x288 each = 13824 floats) ALIAS the S region: written by k0w,
// consumed by k3, then S is (re)written later by k5. No lifetime overlap.
#define OFF_WH   (OFF_S)
#define OFF_WL   (OFF_S + (size_t)13824)
#define OFF_QQT  (OFF_S + SZ_S)
#define SZ_QQT   ((size_t)BSZ*3*256)
#define OFF_KKT  (OFF_QQT + SZ_QQT)
#define OFF_VP   (OFF_KKT + SZ_QQT)
#define SZ_VP    ((size_t)BSZ*256)
#define OFF_P1   (OFF_VP + SZ_VP)
#define SZ_P1    ((size_t)BSZ*44)
#define OFF_P2   (OFF_P1 + SZ_P1)
#define SZ_P2    ((size_t)NPART*192)
#define OFF_BN1  (OFF_P2 + SZ_P2)
#define OFF_BN2  (OFF_BN1 + (size_t)64)

__device__ __forceinline__ float elu_f(float z) { return z > 0.f ? z : expm1f(z); }

__device__ __forceinline__ unsigned short f2bf(float x) {
    unsigned u = __float_as_uint(x);
    u += 0x7fffu + ((u >> 16) & 1u);
    return (unsigned short)(u >> 16);
}
__device__ __forceinline__ float bf2f(unsigned short h) {
    return __uint_as_float(((unsigned)h) << 16);
}

// ================= K0w: precompute split-bf16 weights Whi/Wlo [96][288] ==========
__global__ __launch_bounds__(256) void k0_wsplit(const float* __restrict__ w2,
        unsigned short* __restrict__ Whi, unsigned short* __restrict__ Wlo) {
    int i = blockIdx.x*256 + threadIdx.x;
    if (i >= 96*288) return;
    int o = i / 288, kap = i - o*288;
    float v = (kap < 264) ? w2[o*264 + kap] : 0.f;
    unsigned short h = f2bf(v);
    float lo = v - bf2f(h);
    Whi[i] = h;
    Wlo[i] = f2bf(lo);
}

// ================= K1: conv1 (22ch spatial filter) + BN1 partial stats ==========
__global__ __launch_bounds__(256) void k1_conv1(const float* __restrict__ x,
        const float* __restrict__ w1, float* __restrict__ h1,
        float* __restrict__ part1) {
    __shared__ float sw[CEEG*CEEG];       // [o][c]
    __shared__ float red[4][44];
    int b = blockIdx.x;
    int tid = threadIdx.x;
    for (int i = tid; i < CEEG*CEEG; i += 256) sw[i] = w1[i];
    __syncthreads();
    float sum[CEEG], sumsq[CEEG];
    #pragma unroll
    for (int o = 0; o < CEEG; ++o) { sum[o] = 0.f; sumsq[o] = 0.f; }
    const float* xb = x + (size_t)b*CEEG*TLEN;
    float* hb = h1 + (size_t)b*CEEG*TLEN;
    for (int it = 0; it < 4; ++it) {
        int t = it*256 + tid;
        if (t < TLEN) {
            float acc[CEEG];
            #pragma unroll
            for (int o = 0; o < CEEG; ++o) acc[o] = 0.f;
            #pragma unroll 2
            for (int c = 0; c < CEEG; ++c) {
                float xv = xb[c*TLEN + t];
                #pragma unroll
                for (int o = 0; o < CEEG; ++o) acc[o] = fmaf(xv, sw[o*CEEG + c], acc[o]);
            }
            #pragma unroll
            for (int o = 0; o < CEEG; ++o) {
                hb[o*TLEN + t] = acc[o];
                sum[o]  += acc[o];
                sumsq[o] += acc[o]*acc[o];
            }
        }
    }
    int lane = tid & 63, wv = tid >> 6;
    #pragma unroll
    for (int o = 0; o < CEEG; ++o) {
        float s = sum[o], s2 = sumsq[o];
        for (int off = 32; off > 0; off >>= 1) {
            s  += __shfl_down(s,  off, 64);
            s2 += __shfl_down(s2, off, 64);
        }
        if (lane == 0) { red[wv][o] = s; red[wv][CEEG + o] = s2; }
    }
    __syncthreads();
    if (tid < 44) {
        part1[(size_t)b*44 + tid] = red[0][tid] + red[1][tid] + red[2][tid] + red[3][tid];
    }
}

// ================= K2: finalize BN1 params (1 block / channel) ==========
__global__ __launch_bounds__(64) void k2_bn1(const float* __restrict__ part1,
        const float* __restrict__ g, const float* __restrict__ bta, float* __restrict__ p1) {
    int c = blockIdx.x, t = threadIdx.x;
    float s = 0.f, s2 = 0.f;
    for (int blk = t; blk < BSZ; blk += 64) {
        s  += part1[(size_t)blk*44 + c];
        s2 += part1[(size_t)blk*44 + CEEG + c];
    }
    for (int off = 32; off > 0; off >>= 1) {
        s  += __shfl_down(s,  off, 64);
        s2 += __shfl_down(s2, off, 64);
    }
    if (t == 0) {
        double N = (double)BSZ * (double)TLEN;
        double mu = (double)s / N, var = (double)s2 / N - mu*mu;
        double scale = (double)g[c] / sqrt(var + 1e-5);
        p1[c] = (float)scale;
        p1[CEEG + c] = (float)((double)bta[c] - mu*scale);
    }
}

// ===== K3 v6: conv2 as split-bf16 MFMA GEMM. 128 thr (2 waves), 64-t tiles ====
// C[96][64] = W[96][288] x X[288][64], X = im2col(ELU(BN1(h1))), K padded 264->288.
// Split: W*X ~= Whi*Xhi + Whi*Xlo + Wlo*Xhi  (3 MFMAs / frag pair).
__global__ __launch_bounds__(128) void k3_conv2(const float* __restrict__ h1,
        const unsigned short* __restrict__ WhiG, const unsigned short* __restrict__ WloG,
        const float* __restrict__ p1, float* __restrict__ h2, float* __restrict__ part2) {
    __shared__ float E[22*80];              // BN1+ELU input window [c][80], tt<76 used
    __shared__ unsigned short ctab[288];    // kappa -> E offset (c*80+k), 0xFFFF = pad
    __shared__ short AhiL[96*40];           // A chunk [o][40], 32 used, 16B-aligned rows
    __shared__ short AloL[96*40];
    __shared__ short XhiL[64*40];           // Xt chunk [t][40], 32 used
    __shared__ short XloL[64*40];
    int b = blockIdx.x;
    int tile = blockIdx.y;                  // 0..15
    int t0 = tile * 64;
    int tid = threadIdx.x;
    int lane = tid & 63, w = tid >> 6;
    int r16 = lane & 15, q = lane >> 4;
    const float* hb = h1 + (size_t)b*CEEG*TLEN;

    // stage E window [t0, t0+75] with BN1+ELU; zero beyond TLEN
    for (int i = tid; i < 22*76; i += 128) {
        int c = i / 76, tt = i - c*76;
        int t = t0 + tt;
        float v = 0.f;
        if (t < TLEN) v = elu_f(fmaf(hb[c*TLEN + t], p1[c], p1[CEEG + c]));
        E[c*80 + tt] = v;
    }
    for (int i = tid; i < 288; i += 128) {
        int c = i / 12, k = i - c*12;
        ctab[i] = (i < 264) ? (unsigned short)(c*80 + k) : (unsigned short)0xFFFF;
    }

    floatx4 acc[3][4];
    #pragma unroll
    for (int m = 0; m < 3; ++m)
        #pragma unroll
        for (int nf = 0; nf < 4; ++nf) acc[m][nf] = (floatx4){0.f, 0.f, 0.f, 0.f};

    int tX = tid >> 1;                       // this thread's Xt row (0..63)
    int khalf = (tid & 1) << 4;              // kappa half: 0 or 16

    for (int kc = 0; kc < 9; ++kc) {
        __syncthreads();                     // prev compute done before overwrite
        // --- build A chunk (global bf16 -> LDS, 8B units) ---
        for (int u = tid; u < 768; u += 128) {
            int r = u >> 3, cu = u & 7;
            int gs = r*288 + kc*32 + cu*4;
            *(uint2*)&AhiL[r*40 + cu*4] = *(const uint2*)&WhiG[gs];
            *(uint2*)&AloL[r*40 + cu*4] = *(const uint2*)&WloG[gs];
        }
        // --- build Xt chunk: split-bf16 of im2col ---
        {
            const unsigned short* ct = &ctab[kc*32 + khalf];
            unsigned* dh = (unsigned*)&XhiL[tX*40 + khalf];
            unsigned* dl = (unsigned*)&XloL[tX*40 + khalf];
            #pragma unroll
            for (int jp = 0; jp < 8; ++jp) {
                unsigned short o0 = ct[2*jp], o1 = ct[2*jp + 1];
                float v0 = (o0 != 0xFFFFu) ? E[o0 + tX] : 0.f;
                float v1 = (o1 != 0xFFFFu) ? E[o1 + tX] : 0.f;
                unsigned short h0 = f2bf(v0), h1v = f2bf(v1);
                unsigned short l0 = f2bf(v0 - bf2f(h0));
                unsigned short l1 = f2bf(v1 - bf2f(h1v));
                dh[jp] = (unsigned)h0 | ((unsigned)h1v << 16);
                dl[jp] = (unsigned)l0 | ((unsigned)l1 << 16);
            }
        }
        __syncthreads();
        // --- MFMA: wave w owns m-tiles 3w..3w+2 ---
        short8 ah[3], al[3];
        #pragma unroll
        for (int m = 0; m < 3; ++m) {
            int mr = (w*3 + m)*16 + r16;
            ah[m] = *(const short8*)&AhiL[mr*40 + q*8];
            al[m] = *(const short8*)&AloL[mr*40 + q*8];
        }
        #pragma unroll
        for (int nf = 0; nf < 4; ++nf) {
            int tn = nf*16 + r16;
            short8 bh = *(const short8*)&XhiL[tn*40 + q*8];
            short8 bl = *(const short8*)&XloL[tn*40 + q*8];
            #pragma unroll
            for (int m = 0; m < 3; ++m) {
                acc[m][nf] = __builtin_amdgcn_mfma_f32_16x16x32_bf16(ah[m], bh, acc[m][nf], 0, 0, 0);
                acc[m][nf] = __builtin_amdgcn_mfma_f32_16x16x32_bf16(ah[m], bl, acc[m][nf], 0, 0, 0);
                acc[m][nf] = __builtin_amdgcn_mfma_f32_16x16x32_bf16(al[m], bh, acc[m][nf], 0, 0, 0);
            }
        }
    }

    // epilogue: C/D layout col=lane&15 (t), row=q*4+reg (o). Store + BN2 partials.
    float* h2b = h2 + (size_t)b*C2*TSTR;
    float* pb = part2 + ((size_t)b*NT16 + tile)*192;
    #pragma unroll
    for (int m = 0; m < 3; ++m) {
        float s[4] = {0.f, 0.f, 0.f, 0.f}, s2[4] = {0.f, 0.f, 0.f, 0.f};
        #pragma unroll
        for (int nf = 0; nf < 4; ++nf) {
            int t = t0 + nf*16 + r16;
            bool ok = t < TOUT;
            #pragma unroll
            for (int reg = 0; reg < 4; ++reg) {
                float v = acc[m][nf][reg];
                if (ok) {
                    int o = (w*3 + m)*16 + q*4 + reg;
                    h2b[(size_t)o*TSTR + t] = v;
                    s[reg] += v; s2[reg] += v*v;
                }
            }
        }
        #pragma unroll
        for (int reg = 0; reg < 4; ++reg) {
            float a = s[reg], b2 = s2[reg];
            #pragma unroll
            for (int d = 8; d > 0; d >>= 1) {
                a  += __shfl_down(a,  d, 16);
                b2 += __shfl_down(b2, d, 16);
            }
            if (r16 == 0) {
                int o = (w*3 + m)*16 + q*4 + reg;
                pb[o] = a; pb[96 + o] = b2;
            }
        }
    }
}

// ================= K4: finalize BN2 params (1 block / channel) ==========
__global__ __launch_bounds__(256) void k4_bn2(const float* __restrict__ part2,
        const float* __restrict__ g, const float* __restrict__ bta, float* __restrict__ p2) {
    __shared__ float rs[4], rs2[4];
    int q = blockIdx.x, t = threadIdx.x;
    float s = 0.f, s2 = 0.f;
    for (int blk = t; blk < NPART; blk += 256) {
        s  += part2[(size_t)blk*192 + q];
        s2 += part2[(size_t)blk*192 + 96 + q];
    }
    for (int off = 32; off > 0; off >>= 1) {
        s  += __shfl_down(s,  off, 64);
        s2 += __shfl_down(s2, off, 64);
    }
    int lane = t & 63, wv = t >> 6;
    if (lane == 0) { rs[wv] = s; rs2[wv] = s2; }
    __syncthreads();
    if (t == 0) {
        double S  = (double)rs[0]  + rs[1]  + rs[2]  + rs[3];
        double S2 = (double)rs2[0] + rs2[1] + rs2[2] + rs2[3];
        double N = (double)BSZ * (double)TOUT;
        double mu = S / N, var = S2 / N - mu*mu;
        double scale = (double)g[q] / sqrt(var + 1e-5);
        p2[q] = (float)scale;
        p2[C2 + q] = (float)((double)bta[q] - mu*scale);
    }
}

// ===== K5 v2: Gram, 4x4 tiles, wave-private staging, no inner barriers ==========
__global__ __launch_bounds__(256) void k5_gram(const float* __restrict__ h2,
        const float* __restrict__ p2, float* __restrict__ S) {
    __shared__ float smem[4*2176];          // per-wave [32][68]; overlaid red [64][17]
    int bm = blockIdx.x;
    int b = bm / 3, m = bm % 3;
    int tid = threadIdx.x;
    int w = tid >> 6, lane = tid & 63;
    float* sx = smem + w*2176;
    const float* hb = h2 + ((size_t)b*C2 + m*32)*TSTR;
    int srow = lane >> 1;
    int scol = (lane & 1) * 32;
    float sc = p2[m*32 + srow], sh = p2[C2 + m*32 + srow];
    int r0 = (lane >> 3) << 2, c0 = (lane & 7) << 2;
    float acc[4][4];
    #pragma unroll
    for (int i = 0; i < 4; ++i)
        #pragma unroll
        for (int j = 0; j < 4; ++j) acc[i][j] = 0.f;

    for (int t0 = w*64; t0 < TOUT; t0 += 256) {
        const float* src = &hb[(size_t)srow*TSTR + t0 + scol];
        float* drow = &sx[srow*68 + scol];
        if (t0 + 63 < TOUT) {
            #pragma unroll
            for (int j = 0; j < 8; ++j) {
                float4 xv = *(const float4*)&src[4*j];
                float4 v;
                v.x = elu_f(fmaf(xv.x, sc, sh));
                v.y = elu_f(fmaf(xv.y, sc, sh));
                v.z = elu_f(fmaf(xv.z, sc, sh));
                v.w = elu_f(fmaf(xv.w, sc, sh));
                *(float4*)&drow[4*j] = v;
            }
        } else {
            #pragma unroll
            for (int j = 0; j < 8; ++j) {
                float4 xv = *(const float4*)&src[4*j];
                int tb = t0 + scol + 4*j;
                float4 v;
                v.x = (tb + 0 < TOUT) ? elu_f(fmaf(xv.x, sc, sh)) : 0.f;
                v.y = (tb + 1 < TOUT) ? elu_f(fmaf(xv.y, sc, sh)) : 0.f;
                v.z = (tb + 2 < TOUT) ? elu_f(fmaf(xv.z, sc, sh)) : 0.f;
                v.w = (tb + 3 < TOUT) ? elu_f(fmaf(xv.w, sc, sh)) : 0.f;
                *(float4*)&drow[4*j] = v;
            }
        }
        #pragma unroll
        for (int tc = 0; tc < 16; ++tc) {
            float4 a0 = *(const float4*)&sx[(r0+0)*68 + tc*4];
            float4 a1 = *(const float4*)&sx[(r0+1)*68 + tc*4];
            float4 a2 = *(const float4*)&sx[(r0+2)*68 + tc*4];
            float4 a3 = *(const float4*)&sx[(r0+3)*68 + tc*4];
            float4 b0 = *(const float4*)&sx[(c0+0)*68 + tc*4];
            float4 b1 = *(const float4*)&sx[(c0+1)*68 + tc*4];
            float4 b2 = *(const float4*)&sx[(c0+2)*68 + tc*4];
            float4 b3 = *(const float4*)&sx[(c0+3)*68 + tc*4];
            #pragma unroll
            for (int i = 0; i < 4; ++i) {
                float4 ai = (i == 0) ? a0 : (i == 1) ? a1 : (i == 2) ? a2 : a3;
                acc[i][0] = fmaf(ai.x, b0.x, fmaf(ai.y, b0.y, fmaf(ai.z, b0.z, fmaf(ai.w, b0.w, acc[i][0]))));
                acc[i][1] = fmaf(ai.x, b1.x, fmaf(ai.y, b1.y, fmaf(ai.z, b1.z, fmaf(ai.w, b1.w, acc[i][1]))));
                acc[i][2] = fmaf(ai.x, b2.x, fmaf(ai.y, b2.y, fmaf(ai.z, b2.z, fmaf(ai.w, b2.w, acc[i][2]))));
                acc[i][3] = fmaf(ai.x, b3.x, fmaf(ai.y, b3.y, fmaf(ai.z, b3.z, fmaf(ai.w, b3.w, acc[i][3]))));
            }
        }
    }

    float* red = smem + w*2176;
    #pragma unroll
    for (int i = 0; i < 4; ++i)
        #pragma unroll
        for (int j = 0; j < 4; ++j)
            red[lane*17 + i*4 + j] = acc[i][j];
    __syncthreads();
    int e0 = tid * 4;
    int r = e0 >> 5, c = e0 & 31;
    int tl = (r >> 2)*8 + (c >> 2);
    int sb = (r & 3)*4;
    float o0 = 0.f, o1 = 0.f, o2 = 0.f, o3 = 0.f;
    #pragma unroll
    for (int ww = 0; ww < 4; ++ww) {
        const float* rp = smem + ww*2176 + tl*17 + sb;
        o0 += rp[0]; o1 += rp[1]; o2 += rp[2]; o3 += rp[3];
    }
    float* Sb2 = S + (size_t)bm*1024;
    *(float4*)&Sb2[e0] = make_float4(o0, o1, o2, o3);
}

// ================= K6 v3 (R4-best): 256 thr/matrix, b64 V, f2 cs ======
__device__ __forceinline__ void pair_of(int r, int k, int& p, int& q) {
    if (k == 0) { p = r; q = 31; }
    else {
        int a = (r + k) % 31;
        int b2 = (r - k + 31) % 31;
        p = min(a, b2); q = max(a, b2);
    }
}

__global__ __launch_bounds__(256) void k6_eig(const float* __restrict__ S,
        const float* __restrict__ wq, const float* __restrict__ wk, const float* __restrict__ wv,
        float* __restrict__ QQt, float* __restrict__ KKt, float* __restrict__ Vp) {
    __shared__ float A[32][33];
    __shared__ float Vt[32][34];            // V transposed: Vt[col][row], even stride
    __shared__ float2 cs2[16];
    __shared__ float sW[3][512];
    __shared__ unsigned int ptab[31*16];
    __shared__ float Up[32][9];
    __shared__ float Aw[16][9];
    __shared__ float G[8][9];
    __shared__ float Lm[8][9];
    __shared__ float Mm[16][9];
    __shared__ float lam[32];
    int bm = blockIdx.x, b = bm / 3, m = bm % 3;
    int tid = threadIdx.x;
    const float* Sb = S + (size_t)bm*1024;
    for (int i = tid; i < 1024; i += 256) {
        int r_ = i >> 5, c_ = i & 31;
        A[r_][c_] = Sb[i];
        Vt[r_][c_] = (r_ == c_) ? 1.f : 0.f;
    }
    for (int i = tid; i < 512; i += 256) {
        sW[0][i] = wq[i]; sW[1][i] = wk[i]; sW[2][i] = wv[i];
    }
    for (int i = tid; i < 31*16; i += 256) {
        int r_ = i >> 4, k_ = i & 15;
        int p, q; pair_of(r_, k_, p, q);
        ptab[i] = (unsigned)p | ((unsigned)q << 16);
    }
    __syncthreads();

    int kk_ = tid >> 4, ll_ = tid & 15;
    int i0 = kk_ * 2;
    for (int sweep = 0; sweep < NSWEEP; ++sweep) {
        for (int r = 0; r < 31; ++r) {
            if (tid < 16) {
                unsigned pq = ptab[(r << 4) + tid];
                int p = pq & 0xffff, q = pq >> 16;
                float app = A[p][p], aqq = A[q][q], apq = A[p][q];
                float c = 1.f, s = 0.f;
                if (apq != 0.f) {
                    float tau = (aqq - app) / (2.f * apq);
                    float tt = (tau >= 0.f ? 1.f : -1.f) / (fabsf(tau) + sqrtf(1.f + tau*tau));
                    c = 1.f / sqrtf(1.f + tt*tt);
                    s = tt * c;
                    if (!(c == c) || !(s == s)) { c = 1.f; s = 0.f; }
                }
                cs2[tid] = make_float2(c, s);
            }
            __syncthreads();
            {
                unsigned pqk = ptab[(r << 4) + kk_];
                unsigned pql = ptab[(r << 4) + ll_];
                int p = pqk & 0xffff, q = pqk >> 16;
                int rr = pql & 0xffff, ss = pql >> 16;
                float2 ck2 = cs2[kk_], cl2 = cs2[ll_];
                float ck = ck2.x, sk = ck2.y, cl = cl2.x, sl = cl2.y;
                float apr = A[p][rr], aps = A[p][ss], aqr = A[q][rr], aqs = A[q][ss];
                float tpr = ck*apr - sk*aqr;
                float tqr = sk*apr + ck*aqr;
                float tps = ck*aps - sk*aqs;
                float tqs = sk*aps + ck*aqs;
                A[p][rr] = cl*tpr - sl*tps;
                A[p][ss] = sl*tpr + cl*tps;
                A[q][rr] = cl*tqr - sl*tqs;
                A[q][ss] = sl*tqr + cl*tqs;
                float2 vr = *(const float2*)&Vt[rr][i0];
                float2 vs = *(const float2*)&Vt[ss][i0];
                float2 nvr, nvs;
                nvr.x = cl*vr.x - sl*vs.x;
                nvr.y = cl*vr.y - sl*vs.y;
                nvs.x = sl*vr.x + cl*vs.x;
                nvs.y = sl*vr.y + cl*vs.y;
                *(float2*)&Vt[rr][i0] = nvr;
                *(float2*)&Vt[ss][i0] = nvs;
            }
            __syncthreads();
        }
    }

    // top-8 eigenvalue selection (descending) -> Up (Up[row][rank] = Vt[col][row])
    if (tid < 32) lam[tid] = A[tid][tid];
    __syncthreads();
    if (tid < 32) {
        float lj = lam[tid];
        int rank = 0;
        #pragma unroll
        for (int i = 0; i < 32; ++i) {
            float li = lam[i];
            rank += (li > lj) || (li == lj && i < tid);
        }
        if (rank < PDIM) {
            #pragma unroll
            for (int i = 0; i < 32; ++i) Up[i][rank] = Vt[tid][i];
        }
    }
    __syncthreads();

    // projections: P = A (A^T A)^{-1} A^T for A = W * Up  (== qr(A).Q @ Q^T)
    for (int widx = 0; widx < 3; ++widx) {
        if (widx == 2 && m != 2) break;   // V-projection only needed for m==2
        const float* W = sW[widx];
        if (tid < 128) {
            int o = tid >> 3, pp = tid & 7;
            float s = 0.f;
            #pragma unroll
            for (int i = 0; i < 32; ++i) s = fmaf(W[o*32 + i], Up[i][pp], s);
            Aw[o][pp] = s;
        }
        __syncthreads();
        if (tid < 64) {
            int xx = tid >> 3, yy = tid & 7;
            float s = 0.f;
            #pragma unroll
            for (int o = 0; o < 16; ++o) s = fmaf(Aw[o][xx], Aw[o][yy], s);
            G[xx][yy] = s;
        }
        __syncthreads();
        if (tid == 0) {
            float Lr[8][8];
            #pragma unroll
            for (int jj = 0; jj < 8; ++jj) {
                float d = G[jj][jj];
                #pragma unroll
                for (int kk = 0; kk < 8; ++kk) if (kk < jj) d -= Lr[jj][kk]*Lr[jj][kk];
                d = sqrtf(fmaxf(d, 1e-30f));
                float inv = 1.f / d;
                Lr[jj][jj] = d;
                Lm[jj][jj] = inv;     // store INVERSE of diagonal
                #pragma unroll
                for (int ii = 0; ii < 8; ++ii) if (ii > jj) {
                    float v = G[ii][jj];
                    #pragma unroll
                    for (int kk = 0; kk < 8; ++kk) if (kk < jj) v -= Lr[ii][kk]*Lr[jj][kk];
                    v *= inv;
                    Lr[ii][jj] = v;
                    Lm[ii][jj] = v;
                }
            }
        }
        __syncthreads();
        if (tid < 16) {
            int o = tid;
            float a[8], mv[8];
            #pragma unroll
            for (int pp = 0; pp < 8; ++pp) a[pp] = Aw[o][pp];
            #pragma unroll
            for (int jj = 0; jj < 8; ++jj) {
                float v = a[jj];
                #pragma unroll
                for (int kk = 0; kk < 8; ++kk) if (kk < jj) v -= Lm[jj][kk]*mv[kk];
                mv[jj] = v * Lm[jj][jj];
            }
            #pragma unroll
            for (int pp = 0; pp < 8; ++pp) Mm[o][pp] = mv[pp];
        }
        __syncthreads();
        {
            int d = tid >> 4, e = tid & 15;
            float s = 0.f;
            #pragma unroll
            for (int pp = 0; pp < 8; ++pp) s = fmaf(Mm[d][pp], Mm[e][pp], s);
            float* dst = (widx == 0) ? (QQt + (size_t)bm*256)
                       : (widx == 1) ? (KKt + (size_t)bm*256)
                       : (Vp + (size_t)b*256);
            dst[d*16 + e] = s;
        }
        __syncthreads();
    }
}

// ================= K7: attention scores + softmax(i=2) + output linear ==========
__global__ __launch_bounds__(64) void k7_out(const float* __restrict__ QQt,
        const float* __restrict__ KKt, const float* __restrict__ Vp,
        const float* __restrict__ lw, const float* __restrict__ lb,
        float* __restrict__ out) {
    __shared__ float sQ[3][256], sK[3][256], sVp[256], ssc[9], wj[3];
    int b = blockIdx.x, tid = threadIdx.x;
    for (int i = tid; i < 768; i += 64) {
        sQ[i >> 8][i & 255] = QQt[(size_t)b*768 + i];
        sK[i >> 8][i & 255] = KKt[(size_t)b*768 + i];
    }
    for (int i = tid; i < 256; i += 64) sVp[i] = Vp[(size_t)b*256 + i];
    __syncthreads();
    for (int pair = 0; pair < 9; ++pair) {
        int i = pair / 3, j = pair % 3;
        const float* Qj = sQ[j];
        const float* Ki = sK[i];
        float accp = 0.f;
        #pragma unroll
        for (int it = 0; it < 4; ++it) {
            int e = tid + 64*it;
            int d = e >> 4, ee = e & 15;
            float y = 0.f;
            #pragma unroll
            for (int f = 0; f < 16; ++f) {
                float dv = Qj[d*16 + f] - Ki[d*16 + f];
                float ev = Qj[ee*16 + f] - Ki[ee*16 + f];
                y = fmaf(dv, ev, y);
            }
            accp += y*y;
        }
        for (int off = 32; off > 0; off >>= 1) accp += __shfl_down(accp, off, 64);
        if (tid == 0) {
            float E = sqrtf(accp);
            ssc[pair] = 1.f / (1.f + log1pf(E));
        }
        __syncthreads();
    }
    if (tid < 3) {
        int j = tid;
        float e0 = expf(ssc[0*3 + j]), e1 = expf(ssc[1*3 + j]), e2 = expf(ssc[2*3 + j]);
        wj[j] = e2 / (e0 + e1 + e2);
    }
    __syncthreads();
    int o = tid >> 4, g = tid & 15;
    float part = 0.f;
    #pragma unroll
    for (int t = 0; t < 16; ++t) {
        int de = g*16 + t;
        float vv = sVp[de];
        float l0 = lw[o*768 + de];
        float l1 = lw[o*768 + 256 + de];
        float l2 = lw[o*768 + 512 + de];
        part = fmaf(vv, fmaf(wj[0], l0, fmaf(wj[1], l1, wj[2]*l2)), part);
    }
    for (int off = 8; off > 0; off >>= 1) part += __shfl_down(part, off, 16);
    if (g == 0) out[b*4 + o] = part + lb[o];
}

// ================= launch ==========
extern "C" void kernel_launch(void* const* d_in, const int* in_sizes, int n_in,
                              void* d_out, int out_size, void* d_ws, size_t ws_size,
                              hipStream_t stream) {
    const float* x  = (const float*)d_in[0];
    const float* w1 = (const float*)d_in[1];
    // d_in[2] conv1_b: cancels exactly in batch-norm (mean subtraction) -> unused
    const float* g1 = (const float*)d_in[3];
    const float* b1 = (const float*)d_in[4];
    const float* w2 = (const float*)d_in[5];
    // d_in[6] conv2_b: cancels exactly in batch-norm -> unused
    const float* g2 = (const float*)d_in[7];
    const float* b2 = (const float*)d_in[8];
    const float* wq = (const float*)d_in[9];
    const float* wk = (const float*)d_in[10];
    const float* wv = (const float*)d_in[11];
    const float* lw = (const float*)d_in[12];
    const float* lb = (const float*)d_in[13];

    float* ws   = (float*)d_ws;
    float* h1   = ws + OFF_H1;
    float* h2   = ws + OFF_H2;
    float* Sm   = ws + OFF_S;
    unsigned short* WhiG = (unsigned short*)(ws + OFF_WH);
    unsigned short* WloG = (unsigned short*)(ws + OFF_WL);
    float* qqt  = ws + OFF_QQT;
    float* kkt  = ws + OFF_KKT;
    float* vpm  = ws + OFF_VP;
    float* p1a  = ws + OFF_P1;
    float* p2a  = ws + OFF_P2;
    float* bn1p = ws + OFF_BN1;
    float* bn2p = ws + OFF_BN2;

    k0_wsplit<<<(96*288 + 255)/256, 256, 0, stream>>>(w2, WhiG, WloG);
    k1_conv1<<<BSZ, 256, 0, stream>>>(x, w1, h1, p1a);
    k2_bn1<<<CEEG, 64, 0, stream>>>(p1a, g1, b1, bn1p);
    dim3 g3(BSZ, NT16);
    k3_conv2<<<g3, 128, 0, stream>>>(h1, WhiG, WloG, bn1p, h2, p2a);
    k4_bn2<<<C2, 256, 0, stream>>>(p2a, g2, b2, bn2p);
    k5_gram<<<BSZ*3, 256, 0, stream>>>(h2, bn2p, Sm);
    k6_eig<<<BSZ*3, 256, 0, stream>>>(Sm, wq, wk, wv, qqt, kkt, vpm);
    k7_out<<<BSZ, 64, 0, stream>>>(qqt, kkt, vpm, lw, lb, (float*)d_out);
}

// Round 12
// 404.991 us; speedup vs baseline: 1.6473x; 1.2191x over previous
//
#include <hip/hip_runtime.h>
#include <math.h>

#define PDIM 8
#define BSZ 256
#define CEEG 22
#define TLEN 1000
#define KW 12
#define C2 96
#define TOUT 989
#define TSTR 992          // padded h2 row stride (16B-aligned float4 stores)
#define NSWEEP 6
#define NT8 8             // k3 t-tiles of 128
#define NPART (BSZ*NT8*2) // BN2 stat partial groups (2 n-groups per tile)

typedef __attribute__((ext_vector_type(8))) short short8;
typedef __attribute__((ext_vector_type(4))) float floatx4;

// ---- workspace layout (in floats) ----
#define OFF_H1   ((size_t)0)
#define SZ_H1    ((size_t)BSZ*CEEG*TLEN)
#define OFF_H2   (OFF_H1 + SZ_H1)
#define SZ_H2    ((size_t)BSZ*C2*TSTR)
#define OFF_S    (OFF_H2 + SZ_H2)
#define SZ_S     ((size_t)BSZ*3*1024)
// Whi/Wlo (bf16, 96x288 each) ALIAS the S region: written by k0w, consumed by
// k3, then S is (re)written later by k5. No lifetime overlap.
#define OFF_WH   (OFF_S)
#define OFF_WL   (OFF_S + (size_t)13824)
#define OFF_QQT  (OFF_S + SZ_S)
#define SZ_QQT   ((size_t)BSZ*3*256)
#define OFF_KKT  (OFF_QQT + SZ_QQT)
#define OFF_VP   (OFF_KKT + SZ_QQT)
#define SZ_VP    ((size_t)BSZ*256)
#define OFF_P1   (OFF_VP + SZ_VP)
#define SZ_P1    ((size_t)BSZ*44)
#define OFF_P2   (OFF_P1 + SZ_P1)
#define SZ_P2    ((size_t)NPART*192)
#define OFF_BN1  (OFF_P2 + SZ_P2)
#define OFF_BN2  (OFF_BN1 + (size_t)64)

__device__ __forceinline__ float elu_f(float z) { return z > 0.f ? z : expm1f(z); }

__device__ __forceinline__ unsigned short f2bf(float x) {
    unsigned u = __float_as_uint(x);
    u += 0x7fffu + ((u >> 16) & 1u);
    return (unsigned short)(u >> 16);
}
__device__ __forceinline__ float bf2f(unsigned short h) {
    return __uint_as_float(((unsigned)h) << 16);
}

// ================= K0w: precompute split-bf16 weights Whi/Wlo [96][288] ==========
__global__ __launch_bounds__(256) void k0_wsplit(const float* __restrict__ w2,
        unsigned short* __restrict__ Whi, unsigned short* __restrict__ Wlo) {
    int i = blockIdx.x*256 + threadIdx.x;
    if (i >= 96*288) return;
    int o = i / 288, kap = i - o*288;
    float v = (kap < 264) ? w2[o*264 + kap] : 0.f;
    unsigned short h = f2bf(v);
    float lo = v - bf2f(h);
    Whi[i] = h;
    Wlo[i] = f2bf(lo);
}

// ================= K1: conv1 (22ch spatial filter) + BN1 partial stats ==========
__global__ __launch_bounds__(256) void k1_conv1(const float* __restrict__ x,
        const float* __restrict__ w1, float* __restrict__ h1,
        float* __restrict__ part1) {
    __shared__ float sw[CEEG*CEEG];       // [o][c]
    __shared__ float red[4][44];
    int b = blockIdx.x;
    int tid = threadIdx.x;
    for (int i = tid; i < CEEG*CEEG; i += 256) sw[i] = w1[i];
    __syncthreads();
    float sum[CEEG], sumsq[CEEG];
    #pragma unroll
    for (int o = 0; o < CEEG; ++o) { sum[o] = 0.f; sumsq[o] = 0.f; }
    const float* xb = x + (size_t)b*CEEG*TLEN;
    float* hb = h1 + (size_t)b*CEEG*TLEN;
    for (int it = 0; it < 4; ++it) {
        int t = it*256 + tid;
        if (t < TLEN) {
            float acc[CEEG];
            #pragma unroll
            for (int o = 0; o < CEEG; ++o) acc[o] = 0.f;
            #pragma unroll 2
            for (int c = 0; c < CEEG; ++c) {
                float xv = xb[c*TLEN + t];
                #pragma unroll
                for (int o = 0; o < CEEG; ++o) acc[o] = fmaf(xv, sw[o*CEEG + c], acc[o]);
            }
            #pragma unroll
            for (int o = 0; o < CEEG; ++o) {
                hb[o*TLEN + t] = acc[o];
                sum[o]  += acc[o];
                sumsq[o] += acc[o]*acc[o];
            }
        }
    }
    int lane = tid & 63, wv = tid >> 6;
    #pragma unroll
    for (int o = 0; o < CEEG; ++o) {
        float s = sum[o], s2 = sumsq[o];
        for (int off = 32; off > 0; off >>= 1) {
            s  += __shfl_down(s,  off, 64);
            s2 += __shfl_down(s2, off, 64);
        }
        if (lane == 0) { red[wv][o] = s; red[wv][CEEG + o] = s2; }
    }
    __syncthreads();
    if (tid < 44) {
        part1[(size_t)b*44 + tid] = red[0][tid] + red[1][tid] + red[2][tid] + red[3][tid];
    }
}

// ================= K2: finalize BN1 params (1 block / channel) ==========
__global__ __launch_bounds__(64) void k2_bn1(const float* __restrict__ part1,
        const float* __restrict__ g, const float* __restrict__ bta, float* __restrict__ p1) {
    int c = blockIdx.x, t = threadIdx.x;
    float s = 0.f, s2 = 0.f;
    for (int blk = t; blk < BSZ; blk += 64) {
        s  += part1[(size_t)blk*44 + c];
        s2 += part1[(size_t)blk*44 + CEEG + c];
    }
    for (int off = 32; off > 0; off >>= 1) {
        s  += __shfl_down(s,  off, 64);
        s2 += __shfl_down(s2, off, 64);
    }
    if (t == 0) {
        double N = (double)BSZ * (double)TLEN;
        double mu = (double)s / N, var = (double)s2 / N - mu*mu;
        double scale = (double)g[c] / sqrt(var + 1e-5);
        p1[c] = (float)scale;
        p1[CEEG + c] = (float)((double)bta[c] - mu*scale);
    }
}

// ===== K3 v7: split-bf16 MFMA GEMM, 256 thr (4 waves), t-tile 128 ====
// C[96][128] = W[96][288] x X[288][128]. Waves: mg = w&1 (o half), ng = w>>1
// (t half). A-frags: global->register direct, double-buffered. Xt: LDS bf16
// hi/lo via truncation split; whole-16B-chunk tasks (uniform bank spread).
__global__ __launch_bounds__(256) void k3_conv2(const float* __restrict__ h1,
        const unsigned short* __restrict__ WhiG, const unsigned short* __restrict__ WloG,
        const float* __restrict__ p1, float* __restrict__ h2, float* __restrict__ part2) {
    __shared__ float E[22*152];             // BN1+ELU window [c][tt<139]
    __shared__ unsigned short ctab[288];    // kappa -> E offset (c*152+k), 0xFFFF = pad
    __shared__ short XhiL[128*40];          // Xt chunk [t][40], 32 used
    __shared__ short XloL[128*40];
    int b = blockIdx.x;
    int tile = blockIdx.y;                  // 0..7
    int t0 = tile * 128;
    int tid = threadIdx.x;
    int lane = tid & 63, w = tid >> 6;
    int r16 = lane & 15, q = lane >> 4;
    int mg = w & 1, ng = w >> 1;
    const float* hb = h1 + (size_t)b*CEEG*TLEN;

    // stage E window [t0, t0+138] with BN1+ELU; zero beyond TLEN
    for (int i = tid; i < 22*139; i += 256) {
        int c = i / 139, tt = i - c*139;
        int t = t0 + tt;
        float v = 0.f;
        if (t < TLEN) v = elu_f(fmaf(hb[c*TLEN + t], p1[c], p1[CEEG + c]));
        E[c*152 + tt] = v;
    }
    for (int i = tid; i < 288; i += 256) {
        int c = i / 12, k = i - c*12;
        ctab[i] = (i < 264) ? (unsigned short)(c*152 + k) : (unsigned short)0xFFFF;
    }

    // A-frag row pointers (this lane's 16B segment per m-tile)
    const unsigned short* ahP[3];
    const unsigned short* alP[3];
    #pragma unroll
    for (int m = 0; m < 3; ++m) {
        int row = mg*48 + m*16 + r16;
        ahP[m] = WhiG + row*288 + q*8;
        alP[m] = WloG + row*288 + q*8;
    }
    short8 ahC[3], alC[3];
    #pragma unroll
    for (int m = 0; m < 3; ++m) {
        ahC[m] = *(const short8*)&ahP[m][0];
        alC[m] = *(const short8*)&alP[m][0];
    }

    floatx4 acc[3][4];
    #pragma unroll
    for (int m = 0; m < 3; ++m)
        #pragma unroll
        for (int nf = 0; nf < 4; ++nf) acc[m][nf] = (floatx4){0.f, 0.f, 0.f, 0.f};

    __syncthreads();                        // E ready

    // build Xt for chunk 0 (tasks: u -> row u>>2, 16B chunk u&3)
    #pragma unroll
    for (int s = 0; s < 2; ++s) {
        int u = tid + s*256;
        int t = u >> 2, c4 = u & 3;
        const unsigned short* ct = &ctab[c4*8];
        unsigned dh[4], dl[4];
        #pragma unroll
        for (int jp = 0; jp < 4; ++jp) {
            unsigned short o0 = ct[2*jp], o1 = ct[2*jp+1];
            float v0 = (o0 != 0xFFFFu) ? E[o0 + t] : 0.f;
            float v1 = (o1 != 0xFFFFu) ? E[o1 + t] : 0.f;
            unsigned u0 = __float_as_uint(v0), u1 = __float_as_uint(v1);
            dh[jp] = (u0 >> 16) | (u1 & 0xFFFF0000u);
            float l0 = v0 - __uint_as_float(u0 & 0xFFFF0000u);
            float l1 = v1 - __uint_as_float(u1 & 0xFFFF0000u);
            dl[jp] = (__float_as_uint(l0) >> 16) | (__float_as_uint(l1) & 0xFFFF0000u);
        }
        *(uint4*)&XhiL[t*40 + c4*8] = make_uint4(dh[0], dh[1], dh[2], dh[3]);
        *(uint4*)&XloL[t*40 + c4*8] = make_uint4(dl[0], dl[1], dl[2], dl[3]);
    }
    __syncthreads();                        // Xt(0) ready

    for (int kc = 0; kc < 9; ++kc) {
        // prefetch A-frags for kc+1 (registers; waits overlap MFMA below)
        short8 ahN[3], alN[3];
        if (kc + 1 < 9) {
            #pragma unroll
            for (int m = 0; m < 3; ++m) {
                ahN[m] = *(const short8*)&ahP[m][(kc+1)*32];
                alN[m] = *(const short8*)&alP[m][(kc+1)*32];
            }
        }
        // MFMA on chunk kc
        #pragma unroll
        for (int nf = 0; nf < 4; ++nf) {
            int tn = (ng*4 + nf)*16 + r16;
            short8 bh = *(const short8*)&XhiL[tn*40 + q*8];
            short8 bl = *(const short8*)&XloL[tn*40 + q*8];
            #pragma unroll
            for (int m = 0; m < 3; ++m) {
                acc[m][nf] = __builtin_amdgcn_mfma_f32_16x16x32_bf16(ahC[m], bh, acc[m][nf], 0, 0, 0);
                acc[m][nf] = __builtin_amdgcn_mfma_f32_16x16x32_bf16(ahC[m], bl, acc[m][nf], 0, 0, 0);
                acc[m][nf] = __builtin_amdgcn_mfma_f32_16x16x32_bf16(alC[m], bh, acc[m][nf], 0, 0, 0);
            }
        }
        if (kc + 1 < 9) {
            __syncthreads();                // Xt(kc) consumed block-wide
            #pragma unroll
            for (int s = 0; s < 2; ++s) {
                int u = tid + s*256;
                int t = u >> 2, c4 = u & 3;
                const unsigned short* ct = &ctab[(kc+1)*32 + c4*8];
                unsigned dh[4], dl[4];
                #pragma unroll
                for (int jp = 0; jp < 4; ++jp) {
                    unsigned short o0 = ct[2*jp], o1 = ct[2*jp+1];
                    float v0 = (o0 != 0xFFFFu) ? E[o0 + t] : 0.f;
                    float v1 = (o1 != 0xFFFFu) ? E[o1 + t] : 0.f;
                    unsigned u0 = __float_as_uint(v0), u1 = __float_as_uint(v1);
                    dh[jp] = (u0 >> 16) | (u1 & 0xFFFF0000u);
                    float l0 = v0 - __uint_as_float(u0 & 0xFFFF0000u);
                    float l1 = v1 - __uint_as_float(u1 & 0xFFFF0000u);
                    dl[jp] = (__float_as_uint(l0) >> 16) | (__float_as_uint(l1) & 0xFFFF0000u);
                }
                *(uint4*)&XhiL[t*40 + c4*8] = make_uint4(dh[0], dh[1], dh[2], dh[3]);
                *(uint4*)&XloL[t*40 + c4*8] = make_uint4(dl[0], dl[1], dl[2], dl[3]);
            }
            __syncthreads();                // Xt(kc+1) ready
            #pragma unroll
            for (int m = 0; m < 3; ++m) { ahC[m] = ahN[m]; alC[m] = alN[m]; }
        }
    }

    // epilogue: C/D col=lane&15 (t), row=q*4+reg (o). Store + BN2 partials.
    float* h2b = h2 + (size_t)b*C2*TSTR;
    float* pb = part2 + (((size_t)b*NT8 + tile)*2 + ng)*192;
    #pragma unroll
    for (int m = 0; m < 3; ++m) {
        float s[4] = {0.f, 0.f, 0.f, 0.f}, s2[4] = {0.f, 0.f, 0.f, 0.f};
        #pragma unroll
        for (int nf = 0; nf < 4; ++nf) {
            int t = t0 + (ng*4 + nf)*16 + r16;
            bool ok = t < TOUT;
            #pragma unroll
            for (int reg = 0; reg < 4; ++reg) {
                float v = acc[m][nf][reg];
                if (ok) {
                    int o = mg*48 + m*16 + q*4 + reg;
                    h2b[(size_t)o*TSTR + t] = v;
                    s[reg] += v; s2[reg] += v*v;
                }
            }
        }
        #pragma unroll
        for (int reg = 0; reg < 4; ++reg) {
            float a = s[reg], b2 = s2[reg];
            #pragma unroll
            for (int d = 8; d > 0; d >>= 1) {
                a  += __shfl_down(a,  d, 16);
                b2 += __shfl_down(b2, d, 16);
            }
            if (r16 == 0) {
                int o = mg*48 + m*16 + q*4 + reg;
                pb[o] = a; pb[96 + o] = b2;
            }
        }
    }
}

// ================= K4: finalize BN2 params (1 block / channel) ==========
__global__ __launch_bounds__(256) void k4_bn2(const float* __restrict__ part2,
        const float* __restrict__ g, const float* __restrict__ bta, float* __restrict__ p2) {
    __shared__ float rs[4], rs2[4];
    int q = blockIdx.x, t = threadIdx.x;
    float s = 0.f, s2 = 0.f;
    for (int blk = t; blk < NPART; blk += 256) {
        s  += part2[(size_t)blk*192 + q];
        s2 += part2[(size_t)blk*192 + 96 + q];
    }
    for (int off = 32; off > 0; off >>= 1) {
        s  += __shfl_down(s,  off, 64);
        s2 += __shfl_down(s2, off, 64);
    }
    int lane = t & 63, wv = t >> 6;
    if (lane == 0) { rs[wv] = s; rs2[wv] = s2; }
    __syncthreads();
    if (t == 0) {
        double S  = (double)rs[0]  + rs[1]  + rs[2]  + rs[3];
        double S2 = (double)rs2[0] + rs2[1] + rs2[2] + rs2[3];
        double N = (double)BSZ * (double)TOUT;
        double mu = S / N, var = S2 / N - mu*mu;
        double scale = (double)g[q] / sqrt(var + 1e-5);
        p2[q] = (float)scale;
        p2[C2 + q] = (float)((double)bta[q] - mu*scale);
    }
}

// ===== K5 v2: Gram, 4x4 tiles, wave-private staging, no inner barriers ==========
__global__ __launch_bounds__(256) void k5_gram(const float* __restrict__ h2,
        const float* __restrict__ p2, float* __restrict__ S) {
    __shared__ float smem[4*2176];          // per-wave [32][68]; overlaid red [64][17]
    int bm = blockIdx.x;
    int b = bm / 3, m = bm % 3;
    int tid = threadIdx.x;
    int w = tid >> 6, lane = tid & 63;
    float* sx = smem + w*2176;
    const float* hb = h2 + ((size_t)b*C2 + m*32)*TSTR;
    int srow = lane >> 1;
    int scol = (lane & 1) * 32;
    float sc = p2[m*32 + srow], sh = p2[C2 + m*32 + srow];
    int r0 = (lane >> 3) << 2, c0 = (lane & 7) << 2;
    float acc[4][4];
    #pragma unroll
    for (int i = 0; i < 4; ++i)
        #pragma unroll
        for (int j = 0; j < 4; ++j) acc[i][j] = 0.f;

    for (int t0 = w*64; t0 < TOUT; t0 += 256) {
        const float* src = &hb[(size_t)srow*TSTR + t0 + scol];
        float* drow = &sx[srow*68 + scol];
        if (t0 + 63 < TOUT) {
            #pragma unroll
            for (int j = 0; j < 8; ++j) {
                float4 xv = *(const float4*)&src[4*j];
                float4 v;
                v.x = elu_f(fmaf(xv.x, sc, sh));
                v.y = elu_f(fmaf(xv.y, sc, sh));
                v.z = elu_f(fmaf(xv.z, sc, sh));
                v.w = elu_f(fmaf(xv.w, sc, sh));
                *(float4*)&drow[4*j] = v;
            }
        } else {
            #pragma unroll
            for (int j = 0; j < 8; ++j) {
                float4 xv = *(const float4*)&src[4*j];
                int tb = t0 + scol + 4*j;
                float4 v;
                v.x = (tb + 0 < TOUT) ? elu_f(fmaf(xv.x, sc, sh)) : 0.f;
                v.y = (tb + 1 < TOUT) ? elu_f(fmaf(xv.y, sc, sh)) : 0.f;
                v.z = (tb + 2 < TOUT) ? elu_f(fmaf(xv.z, sc, sh)) : 0.f;
                v.w = (tb + 3 < TOUT) ? elu_f(fmaf(xv.w, sc, sh)) : 0.f;
                *(float4*)&drow[4*j] = v;
            }
        }
        #pragma unroll
        for (int tc = 0; tc < 16; ++tc) {
            float4 a0 = *(const float4*)&sx[(r0+0)*68 + tc*4];
            float4 a1 = *(const float4*)&sx[(r0+1)*68 + tc*4];
            float4 a2 = *(const float4*)&sx[(r0+2)*68 + tc*4];
            float4 a3 = *(const float4*)&sx[(r0+3)*68 + tc*4];
            float4 b0 = *(const float4*)&sx[(c0+0)*68 + tc*4];
            float4 b1 = *(const float4*)&sx[(c0+1)*68 + tc*4];
            float4 b2 = *(const float4*)&sx[(c0+2)*68 + tc*4];
            float4 b3 = *(const float4*)&sx[(c0+3)*68 + tc*4];
            #pragma unroll
            for (int i = 0; i < 4; ++i) {
                float4 ai = (i == 0) ? a0 : (i == 1) ? a1 : (i == 2) ? a2 : a3;
                acc[i][0] = fmaf(ai.x, b0.x, fmaf(ai.y, b0.y, fmaf(ai.z, b0.z, fmaf(ai.w, b0.w, acc[i][0]))));
                acc[i][1] = fmaf(ai.x, b1.x, fmaf(ai.y, b1.y, fmaf(ai.z, b1.z, fmaf(ai.w, b1.w, acc[i][1]))));
                acc[i][2] = fmaf(ai.x, b2.x, fmaf(ai.y, b2.y, fmaf(ai.z, b2.z, fmaf(ai.w, b2.w, acc[i][2]))));
                acc[i][3] = fmaf(ai.x, b3.x, fmaf(ai.y, b3.y, fmaf(ai.z, b3.z, fmaf(ai.w, b3.w, acc[i][3]))));
            }
        }
    }

    float* red = smem + w*2176;
    #pragma unroll
    for (int i = 0; i < 4; ++i)
        #pragma unroll
        for (int j = 0; j < 4; ++j)
            red[lane*17 + i*4 + j] = acc[i][j];
    __syncthreads();
    int e0 = tid * 4;
    int r = e0 >> 5, c = e0 & 31;
    int tl = (r >> 2)*8 + (c >> 2);
    int sb = (r & 3)*4;
    float o0 = 0.f, o1 = 0.f, o2 = 0.f, o3 = 0.f;
    #pragma unroll
    for (int ww = 0; ww < 4; ++ww) {
        const float* rp = smem + ww*2176 + tl*17 + sb;
        o0 += rp[0]; o1 += rp[1]; o2 += rp[2]; o3 += rp[3];
    }
    float* Sb2 = S + (size_t)bm*1024;
    *(float4*)&Sb2[e0] = make_float4(o0, o1, o2, o3);
}

// ================= K6 v3 (R4-best): 256 thr/matrix, b64 V, f2 cs ======
__device__ __forceinline__ void pair_of(int r, int k, int& p, int& q) {
    if (k == 0) { p = r; q = 31; }
    else {
        int a = (r + k) % 31;
        int b2 = (r - k + 31) % 31;
        p = min(a, b2); q = max(a, b2);
    }
}

__global__ __launch_bounds__(256) void k6_eig(const float* __restrict__ S,
        const float* __restrict__ wq, const float* __restrict__ wk, const float* __restrict__ wv,
        float* __restrict__ QQt, float* __restrict__ KKt, float* __restrict__ Vp) {
    __shared__ float A[32][33];
    __shared__ float Vt[32][34];            // V transposed: Vt[col][row], even stride
    __shared__ float2 cs2[16];
    __shared__ float sW[3][512];
    __shared__ unsigned int ptab[31*16];
    __shared__ float Up[32][9];
    __shared__ float Aw[16][9];
    __shared__ float G[8][9];
    __shared__ float Lm[8][9];
    __shared__ float Mm[16][9];
    __shared__ float lam[32];
    int bm = blockIdx.x, b = bm / 3, m = bm % 3;
    int tid = threadIdx.x;
    const float* Sb = S + (size_t)bm*1024;
    for (int i = tid; i < 1024; i += 256) {
        int r_ = i >> 5, c_ = i & 31;
        A[r_][c_] = Sb[i];
        Vt[r_][c_] = (r_ == c_) ? 1.f : 0.f;
    }
    for (int i = tid; i < 512; i += 256) {
        sW[0][i] = wq[i]; sW[1][i] = wk[i]; sW[2][i] = wv[i];
    }
    for (int i = tid; i < 31*16; i += 256) {
        int r_ = i >> 4, k_ = i & 15;
        int p, q; pair_of(r_, k_, p, q);
        ptab[i] = (unsigned)p | ((unsigned)q << 16);
    }
    __syncthreads();

    int kk_ = tid >> 4, ll_ = tid & 15;
    int i0 = kk_ * 2;
    for (int sweep = 0; sweep < NSWEEP; ++sweep) {
        for (int r = 0; r < 31; ++r) {
            if (tid < 16) {
                unsigned pq = ptab[(r << 4) + tid];
                int p = pq & 0xffff, q = pq >> 16;
                float app = A[p][p], aqq = A[q][q], apq = A[p][q];
                float c = 1.f, s = 0.f;
                if (apq != 0.f) {
                    float tau = (aqq - app) / (2.f * apq);
                    float tt = (tau >= 0.f ? 1.f : -1.f) / (fabsf(tau) + sqrtf(1.f + tau*tau));
                    c = 1.f / sqrtf(1.f + tt*tt);
                    s = tt * c;
                    if (!(c == c) || !(s == s)) { c = 1.f; s = 0.f; }
                }
                cs2[tid] = make_float2(c, s);
            }
            __syncthreads();
            {
                unsigned pqk = ptab[(r << 4) + kk_];
                unsigned pql = ptab[(r << 4) + ll_];
                int p = pqk & 0xffff, q = pqk >> 16;
                int rr = pql & 0xffff, ss = pql >> 16;
                float2 ck2 = cs2[kk_], cl2 = cs2[ll_];
                float ck = ck2.x, sk = ck2.y, cl = cl2.x, sl = cl2.y;
                float apr = A[p][rr], aps = A[p][ss], aqr = A[q][rr], aqs = A[q][ss];
                float tpr = ck*apr - sk*aqr;
                float tqr = sk*apr + ck*aqr;
                float tps = ck*aps - sk*aqs;
                float tqs = sk*aps + ck*aqs;
                A[p][rr] = cl*tpr - sl*tps;
                A[p][ss] = sl*tpr + cl*tps;
                A[q][rr] = cl*tqr - sl*tqs;
                A[q][ss] = sl*tqr + cl*tqs;
                float2 vr = *(const float2*)&Vt[rr][i0];
                float2 vs = *(const float2*)&Vt[ss][i0];
                float2 nvr, nvs;
                nvr.x = cl*vr.x - sl*vs.x;
                nvr.y = cl*vr.y - sl*vs.y;
                nvs.x = sl*vr.x + cl*vs.x;
                nvs.y = sl*vr.y + cl*vs.y;
                *(float2*)&Vt[rr][i0] = nvr;
                *(float2*)&Vt[ss][i0] = nvs;
            }
            __syncthreads();
        }
    }

    // top-8 eigenvalue selection (descending) -> Up (Up[row][rank] = Vt[col][row])
    if (tid < 32) lam[tid] = A[tid][tid];
    __syncthreads();
    if (tid < 32) {
        float lj = lam[tid];
        int rank = 0;
        #pragma unroll
        for (int i = 0; i < 32; ++i) {
            float li = lam[i];
            rank += (li > lj) || (li == lj && i < tid);
        }
        if (rank < PDIM) {
            #pragma unroll
            for (int i = 0; i < 32; ++i) Up[i][rank] = Vt[tid][i];
        }
    }
    __syncthreads();

    // projections: P = A (A^T A)^{-1} A^T for A = W * Up  (== qr(A).Q @ Q^T)
    for (int widx = 0; widx < 3; ++widx) {
        if (widx == 2 && m != 2) break;   // V-projection only needed for m==2
        const float* W = sW[widx];
        if (tid < 128) {
            int o = tid >> 3, pp = tid & 7;
            float s = 0.f;
            #pragma unroll
            for (int i = 0; i < 32; ++i) s = fmaf(W[o*32 + i], Up[i][pp], s);
            Aw[o][pp] = s;
        }
        __syncthreads();
        if (tid < 64) {
            int xx = tid >> 3, yy = tid & 7;
            float s = 0.f;
            #pragma unroll
            for (int o = 0; o < 16; ++o) s = fmaf(Aw[o][xx], Aw[o][yy], s);
            G[xx][yy] = s;
        }
        __syncthreads();
        if (tid == 0) {
            float Lr[8][8];
            #pragma unroll
            for (int jj = 0; jj < 8; ++jj) {
                float d = G[jj][jj];
                #pragma unroll
                for (int kk = 0; kk < 8; ++kk) if (kk < jj) d -= Lr[jj][kk]*Lr[jj][kk];
                d = sqrtf(fmaxf(d, 1e-30f));
                float inv = 1.f / d;
                Lr[jj][jj] = d;
                Lm[jj][jj] = inv;     // store INVERSE of diagonal
                #pragma unroll
                for (int ii = 0; ii < 8; ++ii) if (ii > jj) {
                    float v = G[ii][jj];
                    #pragma unroll
                    for (int kk = 0; kk < 8; ++kk) if (kk < jj) v -= Lr[ii][kk]*Lr[jj][kk];
                    v *= inv;
                    Lr[ii][jj] = v;
                    Lm[ii][jj] = v;
                }
            }
        }
        __syncthreads();
        if (tid < 16) {
            int o = tid;
            float a[8], mv[8];
            #pragma unroll
            for (int pp = 0; pp < 8; ++pp) a[pp] = Aw[o][pp];
            #pragma unroll
            for (int jj = 0; jj < 8; ++jj) {
                float v = a[jj];
                #pragma unroll
                for (int kk = 0; kk < 8; ++kk) if (kk < jj) v -= Lm[jj][kk]*mv[kk];
                mv[jj] = v * Lm[jj][jj];
            }
            #pragma unroll
            for (int pp = 0; pp < 8; ++pp) Mm[o][pp] = mv[pp];
        }
        __syncthreads();
        {
            int d = tid >> 4, e = tid & 15;
            float s = 0.f;
            #pragma unroll
            for (int pp = 0; pp < 8; ++pp) s = fmaf(Mm[d][pp], Mm[e][pp], s);
            float* dst = (widx == 0) ? (QQt + (size_t)bm*256)
                       : (widx == 1) ? (KKt + (size_t)bm*256)
                       : (Vp + (size_t)b*256);
            dst[d*16 + e] = s;
        }
        __syncthreads();
    }
}

// ================= K7: attention scores + softmax(i=2) + output linear ==========
__global__ __launch_bounds__(64) void k7_out(const float* __restrict__ QQt,
        const float* __restrict__ KKt, const float* __restrict__ Vp,
        const float* __restrict__ lw, const float* __restrict__ lb,
        float* __restrict__ out) {
    __shared__ float sQ[3][256], sK[3][256], sVp[256], ssc[9], wj[3];
    int b = blockIdx.x, tid = threadIdx.x;
    for (int i = tid; i < 768; i += 64) {
        sQ[i >> 8][i & 255] = QQt[(size_t)b*768 + i];
        sK[i >> 8][i & 255] = KKt[(size_t)b*768 + i];
    }
    for (int i = tid; i < 256; i += 64) sVp[i] = Vp[(size_t)b*256 + i];
    __syncthreads();
    for (int pair = 0; pair < 9; ++pair) {
        int i = pair / 3, j = pair % 3;
        const float* Qj = sQ[j];
        const float* Ki = sK[i];
        float accp = 0.f;
        #pragma unroll
        for (int it = 0; it < 4; ++it) {
            int e = tid + 64*it;
            int d = e >> 4, ee = e & 15;
            float y = 0.f;
            #pragma unroll
            for (int f = 0; f < 16; ++f) {
                float dv = Qj[d*16 + f] - Ki[d*16 + f];
                float ev = Qj[ee*16 + f] - Ki[ee*16 + f];
                y = fmaf(dv, ev, y);
            }
            accp += y*y;
        }
        for (int off = 32; off > 0; off >>= 1) accp += __shfl_down(accp, off, 64);
        if (tid == 0) {
            float E = sqrtf(accp);
            ssc[pair] = 1.f / (1.f + log1pf(E));
        }
        __syncthreads();
    }
    if (tid < 3) {
        int j = tid;
        float e0 = expf(ssc[0*3 + j]), e1 = expf(ssc[1*3 + j]), e2 = expf(ssc[2*3 + j]);
        wj[j] = e2 / (e0 + e1 + e2);
    }
    __syncthreads();
    int o = tid >> 4, g = tid & 15;
    float part = 0.f;
    #pragma unroll
    for (int t = 0; t < 16; ++t) {
        int de = g*16 + t;
        float vv = sVp[de];
        float l0 = lw[o*768 + de];
        float l1 = lw[o*768 + 256 + de];
        float l2 = lw[o*768 + 512 + de];
        part = fmaf(vv, fmaf(wj[0], l0, fmaf(wj[1], l1, wj[2]*l2)), part);
    }
    for (int off = 8; off > 0; off >>= 1) part += __shfl_down(part, off, 16);
    if (g == 0) out[b*4 + o] = part + lb[o];
}

// ================= launch ==========
extern "C" void kernel_launch(void* const* d_in, const int* in_sizes, int n_in,
                              void* d_out, int out_size, void* d_ws, size_t ws_size,
                              hipStream_t stream) {
    const float* x  = (const float*)d_in[0];
    const float* w1 = (const float*)d_in[1];
    // d_in[2] conv1_b: cancels exactly in batch-norm (mean subtraction) -> unused
    const float* g1 = (const float*)d_in[3];
    const float* b1 = (const float*)d_in[4];
    const float* w2 = (const float*)d_in[5];
    // d_in[6] conv2_b: cancels exactly in batch-norm -> unused
    const float* g2 = (const float*)d_in[7];
    const float* b2 = (const float*)d_in[8];
    const float* wq = (const float*)d_in[9];
    const float* wk = (const float*)d_in[10];
    const float* wv = (const float*)d_in[11];
    const float* lw = (const float*)d_in[12];
    const float* lb = (const float*)d_in[13];

    float* ws   = (float*)d_ws;
    float* h1   = ws + OFF_H1;
    float* h2   = ws + OFF_H2;
    float* Sm   = ws + OFF_S;
    unsigned short* WhiG = (unsigned short*)(ws + OFF_WH);
    unsigned short* WloG = (unsigned short*)(ws + OFF_WL);
    float* qqt  = ws + OFF_QQT;
    float* kkt  = ws + OFF_KKT;
    float* vpm  = ws + OFF_VP;
    float* p1a  = ws + OFF_P1;
    float* p2a  = ws + OFF_P2;
    float* bn1p = ws + OFF_BN1;
    float* bn2p = ws + OFF_BN2;

    k0_wsplit<<<(96*288 + 255)/256, 256, 0, stream>>>(w2, WhiG, WloG);
    k1_conv1<<<BSZ, 256, 0, stream>>>(x, w1, h1, p1a);
    k2_bn1<<<CEEG, 64, 0, stream>>>(p1a, g1, b1, bn1p);
    dim3 g3(BSZ, NT8);
    k3_conv2<<<g3, 256, 0, stream>>>(h1, WhiG, WloG, bn1p, h2, p2a);
    k4_bn2<<<C2, 256, 0, stream>>>(p2a, g2, b2, bn2p);
    k5_gram<<<BSZ*3, 256, 0, stream>>>(h2, bn2p, Sm);
    k6_eig<<<BSZ*3, 256, 0, stream>>>(Sm, wq, wk, wv, qqt, kkt, vpm);
    k7_out<<<BSZ, 64, 0, stream>>>(qqt, kkt, vpm, lw, lb, (float*)d_out);
}

// Round 13
// 386.383 us; speedup vs baseline: 1.7266x; 1.0482x over previous
//
#include <hip/hip_runtime.h>
#include <math.h>

#define PDIM 8
#define BSZ 256
#define CEEG 22
#define TLEN 1000
#define KW 12
#define C2 96
#define TOUT 989
#define TSTR 992          // padded h2 row stride (16B-aligned float4 stores)
#define NSWEEP 5
#define NT8 8             // k3 t-tiles of 128
#define NPART (BSZ*NT8*2) // BN2 stat partial groups (2 n-groups per tile)

typedef __attribute__((ext_vector_type(8))) short short8;
typedef __attribute__((ext_vector_type(4))) float floatx4;

// ---- workspace layout (in floats) ----
#define OFF_H1   ((size_t)0)
#define SZ_H1    ((size_t)BSZ*CEEG*TLEN)
#define OFF_H2   (OFF_H1 + SZ_H1)
#define SZ_H2    ((size_t)BSZ*C2*TSTR)
#define OFF_S    (OFF_H2 + SZ_H2)
#define SZ_S     ((size_t)BSZ*3*1024)
// Whi/Wlo (bf16, 96x288 each) ALIAS the S region: written by k0w, consumed by
// k3, then S is (re)written later by k5. No lifetime overlap.
#define OFF_WH   (OFF_S)
#define OFF_WL   (OFF_S + (size_t)13824)
#define OFF_QQT  (OFF_S + SZ_S)
#define SZ_QQT   ((size_t)BSZ*3*256)
#define OFF_KKT  (OFF_QQT + SZ_QQT)
#define OFF_VP   (OFF_KKT + SZ_QQT)
#define SZ_VP    ((size_t)BSZ*256)
#define OFF_P1   (OFF_VP + SZ_VP)
#define SZ_P1    ((size_t)BSZ*44)
#define OFF_P2   (OFF_P1 + SZ_P1)
#define SZ_P2    ((size_t)NPART*192)
#define OFF_BN1  (OFF_P2 + SZ_P2)
#define OFF_BN2  (OFF_BN1 + (size_t)64)

__device__ __forceinline__ float elu_f(float z) { return z > 0.f ? z : expm1f(z); }

__device__ __forceinline__ unsigned short f2bf(float x) {
    unsigned u = __float_as_uint(x);
    u += 0x7fffu + ((u >> 16) & 1u);
    return (unsigned short)(u >> 16);
}
__device__ __forceinline__ float bf2f(unsigned short h) {
    return __uint_as_float(((unsigned)h) << 16);
}

// ================= K0w: precompute split-bf16 weights Whi/Wlo [96][288] ==========
__global__ __launch_bounds__(256) void k0_wsplit(const float* __restrict__ w2,
        unsigned short* __restrict__ Whi, unsigned short* __restrict__ Wlo) {
    int i = blockIdx.x*256 + threadIdx.x;
    if (i >= 96*288) return;
    int o = i / 288, kap = i - o*288;
    float v = (kap < 264) ? w2[o*264 + kap] : 0.f;
    unsigned short h = f2bf(v);
    float lo = v - bf2f(h);
    Whi[i] = h;
    Wlo[i] = f2bf(lo);
}

// ================= K1: conv1 (22ch spatial filter) + BN1 partial stats ==========
__global__ __launch_bounds__(256) void k1_conv1(const float* __restrict__ x,
        const float* __restrict__ w1, float* __restrict__ h1,
        float* __restrict__ part1) {
    __shared__ float sw[CEEG*CEEG];       // [o][c]
    __shared__ float red[4][44];
    int b = blockIdx.x;
    int tid = threadIdx.x;
    for (int i = tid; i < CEEG*CEEG; i += 256) sw[i] = w1[i];
    __syncthreads();
    float sum[CEEG], sumsq[CEEG];
    #pragma unroll
    for (int o = 0; o < CEEG; ++o) { sum[o] = 0.f; sumsq[o] = 0.f; }
    const float* xb = x + (size_t)b*CEEG*TLEN;
    float* hb = h1 + (size_t)b*CEEG*TLEN;
    for (int it = 0; it < 4; ++it) {
        int t = it*256 + tid;
        if (t < TLEN) {
            float acc[CEEG];
            #pragma unroll
            for (int o = 0; o < CEEG; ++o) acc[o] = 0.f;
            #pragma unroll 2
            for (int c = 0; c < CEEG; ++c) {
                float xv = xb[c*TLEN + t];
                #pragma unroll
                for (int o = 0; o < CEEG; ++o) acc[o] = fmaf(xv, sw[o*CEEG + c], acc[o]);
            }
            #pragma unroll
            for (int o = 0; o < CEEG; ++o) {
                hb[o*TLEN + t] = acc[o];
                sum[o]  += acc[o];
                sumsq[o] += acc[o]*acc[o];
            }
        }
    }
    int lane = tid & 63, wv = tid >> 6;
    #pragma unroll
    for (int o = 0; o < CEEG; ++o) {
        float s = sum[o], s2 = sumsq[o];
        for (int off = 32; off > 0; off >>= 1) {
            s  += __shfl_down(s,  off, 64);
            s2 += __shfl_down(s2, off, 64);
        }
        if (lane == 0) { red[wv][o] = s; red[wv][CEEG + o] = s2; }
    }
    __syncthreads();
    if (tid < 44) {
        part1[(size_t)b*44 + tid] = red[0][tid] + red[1][tid] + red[2][tid] + red[3][tid];
    }
}

// ================= K2: finalize BN1 params (1 block / channel) ==========
__global__ __launch_bounds__(64) void k2_bn1(const float* __restrict__ part1,
        const float* __restrict__ g, const float* __restrict__ bta, float* __restrict__ p1) {
    int c = blockIdx.x, t = threadIdx.x;
    float s = 0.f, s2 = 0.f;
    for (int blk = t; blk < BSZ; blk += 64) {
        s  += part1[(size_t)blk*44 + c];
        s2 += part1[(size_t)blk*44 + CEEG + c];
    }
    for (int off = 32; off > 0; off >>= 1) {
        s  += __shfl_down(s,  off, 64);
        s2 += __shfl_down(s2, off, 64);
    }
    if (t == 0) {
        double N = (double)BSZ * (double)TLEN;
        double mu = (double)s / N, var = (double)s2 / N - mu*mu;
        double scale = (double)g[c] / sqrt(var + 1e-5);
        p1[c] = (float)scale;
        p1[CEEG + c] = (float)((double)bta[c] - mu*scale);
    }
}

// ===== K3 v7: split-bf16 MFMA GEMM, 256 thr (4 waves), t-tile 128 ====
// C[96][128] = W[96][288] x X[288][128]. Waves: mg = w&1 (o half), ng = w>>1
// (t half). A-frags: global->register direct, double-buffered. Xt: LDS bf16
// hi/lo via truncation split; whole-16B-chunk tasks (uniform bank spread).
__global__ __launch_bounds__(256) void k3_conv2(const float* __restrict__ h1,
        const unsigned short* __restrict__ WhiG, const unsigned short* __restrict__ WloG,
        const float* __restrict__ p1, float* __restrict__ h2, float* __restrict__ part2) {
    __shared__ float E[22*152];             // BN1+ELU window [c][tt<139]
    __shared__ unsigned short ctab[288];    // kappa -> E offset (c*152+k), 0xFFFF = pad
    __shared__ short XhiL[128*40];          // Xt chunk [t][40], 32 used
    __shared__ short XloL[128*40];
    int b = blockIdx.x;
    int tile = blockIdx.y;                  // 0..7
    int t0 = tile * 128;
    int tid = threadIdx.x;
    int lane = tid & 63, w = tid >> 6;
    int r16 = lane & 15, q = lane >> 4;
    int mg = w & 1, ng = w >> 1;
    const float* hb = h1 + (size_t)b*CEEG*TLEN;

    // stage E window [t0, t0+138] with BN1+ELU; zero beyond TLEN
    for (int i = tid; i < 22*139; i += 256) {
        int c = i / 139, tt = i - c*139;
        int t = t0 + tt;
        float v = 0.f;
        if (t < TLEN) v = elu_f(fmaf(hb[c*TLEN + t], p1[c], p1[CEEG + c]));
        E[c*152 + tt] = v;
    }
    for (int i = tid; i < 288; i += 256) {
        int c = i / 12, k = i - c*12;
        ctab[i] = (i < 264) ? (unsigned short)(c*152 + k) : (unsigned short)0xFFFF;
    }

    // A-frag row pointers (this lane's 16B segment per m-tile)
    const unsigned short* ahP[3];
    const unsigned short* alP[3];
    #pragma unroll
    for (int m = 0; m < 3; ++m) {
        int row = mg*48 + m*16 + r16;
        ahP[m] = WhiG + row*288 + q*8;
        alP[m] = WloG + row*288 + q*8;
    }
    short8 ahC[3], alC[3];
    #pragma unroll
    for (int m = 0; m < 3; ++m) {
        ahC[m] = *(const short8*)&ahP[m][0];
        alC[m] = *(const short8*)&alP[m][0];
    }

    floatx4 acc[3][4];
    #pragma unroll
    for (int m = 0; m < 3; ++m)
        #pragma unroll
        for (int nf = 0; nf < 4; ++nf) acc[m][nf] = (floatx4){0.f, 0.f, 0.f, 0.f};

    __syncthreads();                        // E ready

    // build Xt for chunk 0 (tasks: u -> row u>>2, 16B chunk u&3)
    #pragma unroll
    for (int s = 0; s < 2; ++s) {
        int u = tid + s*256;
        int t = u >> 2, c4 = u & 3;
        const unsigned short* ct = &ctab[c4*8];
        unsigned dh[4], dl[4];
        #pragma unroll
        for (int jp = 0; jp < 4; ++jp) {
            unsigned short o0 = ct[2*jp], o1 = ct[2*jp+1];
            float v0 = (o0 != 0xFFFFu) ? E[o0 + t] : 0.f;
            float v1 = (o1 != 0xFFFFu) ? E[o1 + t] : 0.f;
            unsigned u0 = __float_as_uint(v0), u1 = __float_as_uint(v1);
            dh[jp] = (u0 >> 16) | (u1 & 0xFFFF0000u);
            float l0 = v0 - __uint_as_float(u0 & 0xFFFF0000u);
            float l1 = v1 - __uint_as_float(u1 & 0xFFFF0000u);
            dl[jp] = (__float_as_uint(l0) >> 16) | (__float_as_uint(l1) & 0xFFFF0000u);
        }
        *(uint4*)&XhiL[t*40 + c4*8] = make_uint4(dh[0], dh[1], dh[2], dh[3]);
        *(uint4*)&XloL[t*40 + c4*8] = make_uint4(dl[0], dl[1], dl[2], dl[3]);
    }
    __syncthreads();                        // Xt(0) ready

    for (int kc = 0; kc < 9; ++kc) {
        // prefetch A-frags for kc+1 (registers; waits overlap MFMA below)
        short8 ahN[3], alN[3];
        if (kc + 1 < 9) {
            #pragma unroll
            for (int m = 0; m < 3; ++m) {
                ahN[m] = *(const short8*)&ahP[m][(kc+1)*32];
                alN[m] = *(const short8*)&alP[m][(kc+1)*32];
            }
        }
        // MFMA on chunk kc
        #pragma unroll
        for (int nf = 0; nf < 4; ++nf) {
            int tn = (ng*4 + nf)*16 + r16;
            short8 bh = *(const short8*)&XhiL[tn*40 + q*8];
            short8 bl = *(const short8*)&XloL[tn*40 + q*8];
            #pragma unroll
            for (int m = 0; m < 3; ++m) {
                acc[m][nf] = __builtin_amdgcn_mfma_f32_16x16x32_bf16(ahC[m], bh, acc[m][nf], 0, 0, 0);
                acc[m][nf] = __builtin_amdgcn_mfma_f32_16x16x32_bf16(ahC[m], bl, acc[m][nf], 0, 0, 0);
                acc[m][nf] = __builtin_amdgcn_mfma_f32_16x16x32_bf16(alC[m], bh, acc[m][nf], 0, 0, 0);
            }
        }
        if (kc + 1 < 9) {
            __syncthreads();                // Xt(kc) consumed block-wide
            #pragma unroll
            for (int s = 0; s < 2; ++s) {
                int u = tid + s*256;
                int t = u >> 2, c4 = u & 3;
                const unsigned short* ct = &ctab[(kc+1)*32 + c4*8];
                unsigned dh[4], dl[4];
                #pragma unroll
                for (int jp = 0; jp < 4; ++jp) {
                    unsigned short o0 = ct[2*jp], o1 = ct[2*jp+1];
                    float v0 = (o0 != 0xFFFFu) ? E[o0 + t] : 0.f;
                    float v1 = (o1 != 0xFFFFu) ? E[o1 + t] : 0.f;
                    unsigned u0 = __float_as_uint(v0), u1 = __float_as_uint(v1);
                    dh[jp] = (u0 >> 16) | (u1 & 0xFFFF0000u);
                    float l0 = v0 - __uint_as_float(u0 & 0xFFFF0000u);
                    float l1 = v1 - __uint_as_float(u1 & 0xFFFF0000u);
                    dl[jp] = (__float_as_uint(l0) >> 16) | (__float_as_uint(l1) & 0xFFFF0000u);
                }
                *(uint4*)&XhiL[t*40 + c4*8] = make_uint4(dh[0], dh[1], dh[2], dh[3]);
                *(uint4*)&XloL[t*40 + c4*8] = make_uint4(dl[0], dl[1], dl[2], dl[3]);
            }
            __syncthreads();                // Xt(kc+1) ready
            #pragma unroll
            for (int m = 0; m < 3; ++m) { ahC[m] = ahN[m]; alC[m] = alN[m]; }
        }
    }

    // epilogue: C/D col=lane&15 (t), row=q*4+reg (o). Store + BN2 partials.
    float* h2b = h2 + (size_t)b*C2*TSTR;
    float* pb = part2 + (((size_t)b*NT8 + tile)*2 + ng)*192;
    #pragma unroll
    for (int m = 0; m < 3; ++m) {
        float s[4] = {0.f, 0.f, 0.f, 0.f}, s2[4] = {0.f, 0.f, 0.f, 0.f};
        #pragma unroll
        for (int nf = 0; nf < 4; ++nf) {
            int t = t0 + (ng*4 + nf)*16 + r16;
            bool ok = t < TOUT;
            #pragma unroll
            for (int reg = 0; reg < 4; ++reg) {
                float v = acc[m][nf][reg];
                if (ok) {
                    int o = mg*48 + m*16 + q*4 + reg;
                    h2b[(size_t)o*TSTR + t] = v;
                    s[reg] += v; s2[reg] += v*v;
                }
            }
        }
        #pragma unroll
        for (int reg = 0; reg < 4; ++reg) {
            float a = s[reg], b2 = s2[reg];
            #pragma unroll
            for (int d = 8; d > 0; d >>= 1) {
                a  += __shfl_down(a,  d, 16);
                b2 += __shfl_down(b2, d, 16);
            }
            if (r16 == 0) {
                int o = mg*48 + m*16 + q*4 + reg;
                pb[o] = a; pb[96 + o] = b2;
            }
        }
    }
}

// ================= K4: finalize BN2 params (1 block / channel) ==========
__global__ __launch_bounds__(256) void k4_bn2(const float* __restrict__ part2,
        const float* __restrict__ g, const float* __restrict__ bta, float* __restrict__ p2) {
    __shared__ float rs[4], rs2[4];
    int q = blockIdx.x, t = threadIdx.x;
    float s = 0.f, s2 = 0.f;
    for (int blk = t; blk < NPART; blk += 256) {
        s  += part2[(size_t)blk*192 + q];
        s2 += part2[(size_t)blk*192 + 96 + q];
    }
    for (int off = 32; off > 0; off >>= 1) {
        s  += __shfl_down(s,  off, 64);
        s2 += __shfl_down(s2, off, 64);
    }
    int lane = t & 63, wv = t >> 6;
    if (lane == 0) { rs[wv] = s; rs2[wv] = s2; }
    __syncthreads();
    if (t == 0) {
        double S  = (double)rs[0]  + rs[1]  + rs[2]  + rs[3];
        double S2 = (double)rs2[0] + rs2[1] + rs2[2] + rs2[3];
        double N = (double)BSZ * (double)TOUT;
        double mu = S / N, var = S2 / N - mu*mu;
        double scale = (double)g[q] / sqrt(var + 1e-5);
        p2[q] = (float)scale;
        p2[C2 + q] = (float)((double)bta[q] - mu*scale);
    }
}

// ===== K5 v2: Gram, 4x4 tiles, wave-private staging, no inner barriers ==========
__global__ __launch_bounds__(256) void k5_gram(const float* __restrict__ h2,
        const float* __restrict__ p2, float* __restrict__ S) {
    __shared__ float smem[4*2176];          // per-wave [32][68]; overlaid red [64][17]
    int bm = blockIdx.x;
    int b = bm / 3, m = bm % 3;
    int tid = threadIdx.x;
    int w = tid >> 6, lane = tid & 63;
    float* sx = smem + w*2176;
    const float* hb = h2 + ((size_t)b*C2 + m*32)*TSTR;
    int srow = lane >> 1;
    int scol = (lane & 1) * 32;
    float sc = p2[m*32 + srow], sh = p2[C2 + m*32 + srow];
    int r0 = (lane >> 3) << 2, c0 = (lane & 7) << 2;
    float acc[4][4];
    #pragma unroll
    for (int i = 0; i < 4; ++i)
        #pragma unroll
        for (int j = 0; j < 4; ++j) acc[i][j] = 0.f;

    for (int t0 = w*64; t0 < TOUT; t0 += 256) {
        const float* src = &hb[(size_t)srow*TSTR + t0 + scol];
        float* drow = &sx[srow*68 + scol];
        if (t0 + 63 < TOUT) {
            #pragma unroll
            for (int j = 0; j < 8; ++j) {
                float4 xv = *(const float4*)&src[4*j];
                float4 v;
                v.x = elu_f(fmaf(xv.x, sc, sh));
                v.y = elu_f(fmaf(xv.y, sc, sh));
                v.z = elu_f(fmaf(xv.z, sc, sh));
                v.w = elu_f(fmaf(xv.w, sc, sh));
                *(float4*)&drow[4*j] = v;
            }
        } else {
            #pragma unroll
            for (int j = 0; j < 8; ++j) {
                float4 xv = *(const float4*)&src[4*j];
                int tb = t0 + scol + 4*j;
                float4 v;
                v.x = (tb + 0 < TOUT) ? elu_f(fmaf(xv.x, sc, sh)) : 0.f;
                v.y = (tb + 1 < TOUT) ? elu_f(fmaf(xv.y, sc, sh)) : 0.f;
                v.z = (tb + 2 < TOUT) ? elu_f(fmaf(xv.z, sc, sh)) : 0.f;
                v.w = (tb + 3 < TOUT) ? elu_f(fmaf(xv.w, sc, sh)) : 0.f;
                *(float4*)&drow[4*j] = v;
            }
        }
        #pragma unroll
        for (int tc = 0; tc < 16; ++tc) {
            float4 a0 = *(const float4*)&sx[(r0+0)*68 + tc*4];
            float4 a1 = *(const float4*)&sx[(r0+1)*68 + tc*4];
            float4 a2 = *(const float4*)&sx[(r0+2)*68 + tc*4];
            float4 a3 = *(const float4*)&sx[(r0+3)*68 + tc*4];
            float4 b0 = *(const float4*)&sx[(c0+0)*68 + tc*4];
            float4 b1 = *(const float4*)&sx[(c0+1)*68 + tc*4];
            float4 b2 = *(const float4*)&sx[(c0+2)*68 + tc*4];
            float4 b3 = *(const float4*)&sx[(c0+3)*68 + tc*4];
            #pragma unroll
            for (int i = 0; i < 4; ++i) {
                float4 ai = (i == 0) ? a0 : (i == 1) ? a1 : (i == 2) ? a2 : a3;
                acc[i][0] = fmaf(ai.x, b0.x, fmaf(ai.y, b0.y, fmaf(ai.z, b0.z, fmaf(ai.w, b0.w, acc[i][0]))));
                acc[i][1] = fmaf(ai.x, b1.x, fmaf(ai.y, b1.y, fmaf(ai.z, b1.z, fmaf(ai.w, b1.w, acc[i][1]))));
                acc[i][2] = fmaf(ai.x, b2.x, fmaf(ai.y, b2.y, fmaf(ai.z, b2.z, fmaf(ai.w, b2.w, acc[i][2]))));
                acc[i][3] = fmaf(ai.x, b3.x, fmaf(ai.y, b3.y, fmaf(ai.z, b3.z, fmaf(ai.w, b3.w, acc[i][3]))));
            }
        }
    }

    float* red = smem + w*2176;
    #pragma unroll
    for (int i = 0; i < 4; ++i)
        #pragma unroll
        for (int j = 0; j < 4; ++j)
            red[lane*17 + i*4 + j] = acc[i][j];
    __syncthreads();
    int e0 = tid * 4;
    int r = e0 >> 5, c = e0 & 31;
    int tl = (r >> 2)*8 + (c >> 2);
    int sb = (r & 3)*4;
    float o0 = 0.f, o1 = 0.f, o2 = 0.f, o3 = 0.f;
    #pragma unroll
    for (int ww = 0; ww < 4; ++ww) {
        const float* rp = smem + ww*2176 + tl*17 + sb;
        o0 += rp[0]; o1 += rp[1]; o2 += rp[2]; o3 += rp[3];
    }
    float* Sb2 = S + (size_t)bm*1024;
    *(float4*)&Sb2[e0] = make_float4(o0, o1, o2, o3);
}

// ================= K6 v3: 256 thr/matrix, b64 V, f2 cs; A stride 35 ======
__device__ __forceinline__ void pair_of(int r, int k, int& p, int& q) {
    if (k == 0) { p = r; q = 31; }
    else {
        int a = (r + k) % 31;
        int b2 = (r - k + 31) % 31;
        p = min(a, b2); q = max(a, b2);
    }
}

__global__ __launch_bounds__(256) void k6_eig(const float* __restrict__ S,
        const float* __restrict__ wq, const float* __restrict__ wk, const float* __restrict__ wv,
        float* __restrict__ QQt, float* __restrict__ KKt, float* __restrict__ Vp) {
    __shared__ float A[32][35];             // stride 35: bank=(3p+rr)%32, scrambles
    __shared__ float Vt[32][34];            // V transposed: Vt[col][row], even stride
    __shared__ float2 cs2[16];
    __shared__ float sW[3][512];
    __shared__ unsigned int ptab[31*16];
    __shared__ float Up[32][9];
    __shared__ float Aw[16][9];
    __shared__ float G[8][9];
    __shared__ float Lm[8][9];
    __shared__ float Mm[16][9];
    __shared__ float lam[32];
    int bm = blockIdx.x, b = bm / 3, m = bm % 3;
    int tid = threadIdx.x;
    const float* Sb = S + (size_t)bm*1024;
    for (int i = tid; i < 1024; i += 256) {
        int r_ = i >> 5, c_ = i & 31;
        A[r_][c_] = Sb[i];
        Vt[r_][c_] = (r_ == c_) ? 1.f : 0.f;
    }
    for (int i = tid; i < 512; i += 256) {
        sW[0][i] = wq[i]; sW[1][i] = wk[i]; sW[2][i] = wv[i];
    }
    for (int i = tid; i < 31*16; i += 256) {
        int r_ = i >> 4, k_ = i & 15;
        int p, q; pair_of(r_, k_, p, q);
        ptab[i] = (unsigned)p | ((unsigned)q << 16);
    }
    __syncthreads();

    int kk_ = tid >> 4, ll_ = tid & 15;
    int i0 = kk_ * 2;
    for (int sweep = 0; sweep < NSWEEP; ++sweep) {
        for (int r = 0; r < 31; ++r) {
            if (tid < 16) {
                unsigned pq = ptab[(r << 4) + tid];
                int p = pq & 0xffff, q = pq >> 16;
                float app = A[p][p], aqq = A[q][q], apq = A[p][q];
                float c = 1.f, s = 0.f;
                if (apq != 0.f) {
                    float tau = (aqq - app) / (2.f * apq);
                    float tt = (tau >= 0.f ? 1.f : -1.f) / (fabsf(tau) + sqrtf(1.f + tau*tau));
                    c = 1.f / sqrtf(1.f + tt*tt);
                    s = tt * c;
                    if (!(c == c) || !(s == s)) { c = 1.f; s = 0.f; }
                }
                cs2[tid] = make_float2(c, s);
            }
            __syncthreads();
            {
                unsigned pqk = ptab[(r << 4) + kk_];
                unsigned pql = ptab[(r << 4) + ll_];
                int p = pqk & 0xffff, q = pqk >> 16;
                int rr = pql & 0xffff, ss = pql >> 16;
                float2 ck2 = cs2[kk_], cl2 = cs2[ll_];
                float ck = ck2.x, sk = ck2.y, cl = cl2.x, sl = cl2.y;
                float apr = A[p][rr], aps = A[p][ss], aqr = A[q][rr], aqs = A[q][ss];
                float tpr = ck*apr - sk*aqr;
                float tqr = sk*apr + ck*aqr;
                float tps = ck*aps - sk*aqs;
                float tqs = sk*aps + ck*aqs;
                A[p][rr] = cl*tpr - sl*tps;
                A[p][ss] = sl*tpr + cl*tps;
                A[q][rr] = cl*tqr - sl*tqs;
                A[q][ss] = sl*tqr + cl*tqs;
                float2 vr = *(const float2*)&Vt[rr][i0];
                float2 vs = *(const float2*)&Vt[ss][i0];
                float2 nvr, nvs;
                nvr.x = cl*vr.x - sl*vs.x;
                nvr.y = cl*vr.y - sl*vs.y;
                nvs.x = sl*vr.x + cl*vs.x;
                nvs.y = sl*vr.y + cl*vs.y;
                *(float2*)&Vt[rr][i0] = nvr;
                *(float2*)&Vt[ss][i0] = nvs;
            }
            __syncthreads();
        }
    }

    // top-8 eigenvalue selection (descending) -> Up (Up[row][rank] = Vt[col][row])
    if (tid < 32) lam[tid] = A[tid][tid];
    __syncthreads();
    if (tid < 32) {
        float lj = lam[tid];
        int rank = 0;
        #pragma unroll
        for (int i = 0; i < 32; ++i) {
            float li = lam[i];
            rank += (li > lj) || (li == lj && i < tid);
        }
        if (rank < PDIM) {
            #pragma unroll
            for (int i = 0; i < 32; ++i) Up[i][rank] = Vt[tid][i];
        }
    }
    __syncthreads();

    // projections: P = A (A^T A)^{-1} A^T for A = W * Up  (== qr(A).Q @ Q^T)
    for (int widx = 0; widx < 3; ++widx) {
        if (widx == 2 && m != 2) break;   // V-projection only needed for m==2
        const float* W = sW[widx];
        if (tid < 128) {
            int o = tid >> 3, pp = tid & 7;
            float s = 0.f;
            #pragma unroll
            for (int i = 0; i < 32; ++i) s = fmaf(W[o*32 + i], Up[i][pp], s);
            Aw[o][pp] = s;
        }
        __syncthreads();
        if (tid < 64) {
            int xx = tid >> 3, yy = tid & 7;
            float s = 0.f;
            #pragma unroll
            for (int o = 0; o < 16; ++o) s = fmaf(Aw[o][xx], Aw[o][yy], s);
            G[xx][yy] = s;
        }
        __syncthreads();
        if (tid == 0) {
            float Lr[8][8];
            #pragma unroll
            for (int jj = 0; jj < 8; ++jj) {
                float d = G[jj][jj];
                #pragma unroll
                for (int kk = 0; kk < 8; ++kk) if (kk < jj) d -= Lr[jj][kk]*Lr[jj][kk];
                d = sqrtf(fmaxf(d, 1e-30f));
                float inv = 1.f / d;
                Lr[jj][jj] = d;
                Lm[jj][jj] = inv;     // store INVERSE of diagonal
                #pragma unroll
                for (int ii = 0; ii < 8; ++ii) if (ii > jj) {
                    float v = G[ii][jj];
                    #pragma unroll
                    for (int kk = 0; kk < 8; ++kk) if (kk < jj) v -= Lr[ii][kk]*Lr[jj][kk];
                    v *= inv;
                    Lr[ii][jj] = v;
                    Lm[ii][jj] = v;
                }
            }
        }
        __syncthreads();
        if (tid < 16) {
            int o = tid;
            float a[8], mv[8];
            #pragma unroll
            for (int pp = 0; pp < 8; ++pp) a[pp] = Aw[o][pp];
            #pragma unroll
            for (int jj = 0; jj < 8; ++jj) {
                float v = a[jj];
                #pragma unroll
                for (int kk = 0; kk < 8; ++kk) if (kk < jj) v -= Lm[jj][kk]*mv[kk];
                mv[jj] = v * Lm[jj][jj];
            }
            #pragma unroll
            for (int pp = 0; pp < 8; ++pp) Mm[o][pp] = mv[pp];
        }
        __syncthreads();
        {
            int d = tid >> 4, e = tid & 15;
            float s = 0.f;
            #pragma unroll
            for (int pp = 0; pp < 8; ++pp) s = fmaf(Mm[d][pp], Mm[e][pp], s);
            float* dst = (widx == 0) ? (QQt + (size_t)bm*256)
                       : (widx == 1) ? (KKt + (size_t)bm*256)
                       : (Vp + (size_t)b*256);
            dst[d*16 + e] = s;
        }
        __syncthreads();
    }
}

// ================= K7: attention scores + softmax(i=2) + output linear ==========
__global__ __launch_bounds__(64) void k7_out(const float* __restrict__ QQt,
        const float* __restrict__ KKt, const float* __restrict__ Vp,
        const float* __restrict__ lw, const float* __restrict__ lb,
        float* __restrict__ out) {
    __shared__ float sQ[3][256], sK[3][256], sVp[256], ssc[9], wj[3];
    int b = blockIdx.x, tid = threadIdx.x;
    for (int i = tid; i < 768; i += 64) {
        sQ[i >> 8][i & 255] = QQt[(size_t)b*768 + i];
        sK[i >> 8][i & 255] = KKt[(size_t)b*768 + i];
    }
    for (int i = tid; i < 256; i += 64) sVp[i] = Vp[(size_t)b*256 + i];
    __syncthreads();
    for (int pair = 0; pair < 9; ++pair) {
        int i = pair / 3, j = pair % 3;
        const float* Qj = sQ[j];
        const float* Ki = sK[i];
        float accp = 0.f;
        #pragma unroll
        for (int it = 0; it < 4; ++it) {
            int e = tid + 64*it;
            int d = e >> 4, ee = e & 15;
            float y = 0.f;
            #pragma unroll
            for (int f = 0; f < 16; ++f) {
                float dv = Qj[d*16 + f] - Ki[d*16 + f];
                float ev = Qj[ee*16 + f] - Ki[ee*16 + f];
                y = fmaf(dv, ev, y);
            }
            accp += y*y;
        }
        for (int off = 32; off > 0; off >>= 1) accp += __shfl_down(accp, off, 64);
        if (tid == 0) {
            float E = sqrtf(accp);
            ssc[pair] = 1.f / (1.f + log1pf(E));
        }
        __syncthreads();
    }
    if (tid < 3) {
        int j = tid;
        float e0 = expf(ssc[0*3 + j]), e1 = expf(ssc[1*3 + j]), e2 = expf(ssc[2*3 + j]);
        wj[j] = e2 / (e0 + e1 + e2);
    }
    __syncthreads();
    int o = tid >> 4, g = tid & 15;
    float part = 0.f;
    #pragma unroll
    for (int t = 0; t < 16; ++t) {
        int de = g*16 + t;
        float vv = sVp[de];
        float l0 = lw[o*768 + de];
        float l1 = lw[o*768 + 256 + de];
        float l2 = lw[o*768 + 512 + de];
        part = fmaf(vv, fmaf(wj[0], l0, fmaf(wj[1], l1, wj[2]*l2)), part);
    }
    for (int off = 8; off > 0; off >>= 1) part += __shfl_down(part, off, 16);
    if (g == 0) out[b*4 + o] = part + lb[o];
}

// ================= launch ==========
extern "C" void kernel_launch(void* const* d_in, const int* in_sizes, int n_in,
                              void* d_out, int out_size, void* d_ws, size_t ws_size,
                              hipStream_t stream) {
    const float* x  = (const float*)d_in[0];
    const float* w1 = (const float*)d_in[1];
    // d_in[2] conv1_b: cancels exactly in batch-norm (mean subtraction) -> unused
    const float* g1 = (const float*)d_in[3];
    const float* b1 = (const float*)d_in[4];
    const float* w2 = (const float*)d_in[5];
    // d_in[6] conv2_b: cancels exactly in batch-norm -> unused
    const float* g2 = (const float*)d_in[7];
    const float* b2 = (const float*)d_in[8];
    const float* wq = (const float*)d_in[9];
    const float* wk = (const float*)d_in[10];
    const float* wv = (const float*)d_in[11];
    const float* lw = (const float*)d_in[12];
    const float* lb = (const float*)d_in[13];

    float* ws   = (float*)d_ws;
    float* h1   = ws + OFF_H1;
    float* h2   = ws + OFF_H2;
    float* Sm   = ws + OFF_S;
    unsigned short* WhiG = (unsigned short*)(ws + OFF_WH);
    unsigned short* WloG = (unsigned short*)(ws + OFF_WL);
    float* qqt  = ws + OFF_QQT;
    float* kkt  = ws + OFF_KKT;
    float* vpm  = ws + OFF_VP;
    float* p1a  = ws + OFF_P1;
    float* p2a  = ws + OFF_P2;
    float* bn1p = ws + OFF_BN1;
    float* bn2p = ws + OFF_BN2;

    k0_wsplit<<<(96*288 + 255)/256, 256, 0, stream>>>(w2, WhiG, WloG);
    k1_conv1<<<BSZ, 256, 0, stream>>>(x, w1, h1, p1a);
    k2_bn1<<<CEEG, 64, 0, stream>>>(p1a, g1, b1, bn1p);
    dim3 g3(BSZ, NT8);
    k3_conv2<<<g3, 256, 0, stream>>>(h1, WhiG, WloG, bn1p, h2, p2a);
    k4_bn2<<<C2, 256, 0, stream>>>(p2a, g2, b2, bn2p);
    k5_gram<<<BSZ*3, 256, 0, stream>>>(h2, bn2p, Sm);
    k6_eig<<<BSZ*3, 256, 0, stream>>>(Sm, wq, wk, wv, qqt, kkt, vpm);
    k7_out<<<BSZ, 64, 0, stream>>>(qqt, kkt, vpm, lw, lb, (float*)d_out);
}

// Round 15
// 381.330 us; speedup vs baseline: 1.7495x; 1.0133x over previous
//
#include <hip/hip_runtime.h>
#include <math.h>

#define PDIM 8
#define BSZ 256
#define CEEG 22
#define TLEN 1000
#define KW 12
#define C2 96
#define TOUT 989
#define TSTR 992          // padded h2 row stride (16B-aligned float4 stores)
#define NSWEEP 5          // 4 FAILS (absmax 3.6e-2); 5 = machine floor. LOCKED.
#define NT8 8             // k3 t-tiles of 128
#define NPART (BSZ*NT8*2) // BN2 stat partial groups (2 n-groups per tile)

typedef __attribute__((ext_vector_type(8))) short short8;
typedef __attribute__((ext_vector_type(4))) float floatx4;

// ---- workspace layout (in floats) ----
#define OFF_H1   ((size_t)0)
#define SZ_H1    ((size_t)BSZ*CEEG*TLEN)
#define OFF_H2   (OFF_H1 + SZ_H1)
#define SZ_H2    ((size_t)BSZ*C2*TSTR)
#define OFF_S    (OFF_H2 + SZ_H2)
#define SZ_S     ((size_t)BSZ*3*1024)
// Whi/Wlo (bf16, 96x288 each) ALIAS the S region: written by k0w, consumed by
// k3, then S is (re)written later by k5. No lifetime overlap.
#define OFF_WH   (OFF_S)
#define OFF_WL   (OFF_S + (size_t)13824)
#define OFF_QQT  (OFF_S + SZ_S)
#define SZ_QQT   ((size_t)BSZ*3*256)
#define OFF_KKT  (OFF_QQT + SZ_QQT)
#define OFF_VP   (OFF_KKT + SZ_QQT)
#define SZ_VP    ((size_t)BSZ*256)
#define OFF_P1   (OFF_VP + SZ_VP)
#define SZ_P1    ((size_t)BSZ*44)
#define OFF_P2   (OFF_P1 + SZ_P1)
#define SZ_P2    ((size_t)NPART*192)
#define OFF_BN1  (OFF_P2 + SZ_P2)
#define OFF_BN2  (OFF_BN1 + (size_t)64)

__device__ __forceinline__ float elu_f(float z) { return z > 0.f ? z : expm1f(z); }

__device__ __forceinline__ unsigned short f2bf(float x) {
    unsigned u = __float_as_uint(x);
    u += 0x7fffu + ((u >> 16) & 1u);
    return (unsigned short)(u >> 16);
}
__device__ __forceinline__ float bf2f(unsigned short h) {
    return __uint_as_float(((unsigned)h) << 16);
}

// ================= K0w: precompute split-bf16 weights Whi/Wlo [96][288] ==========
__global__ __launch_bounds__(256) void k0_wsplit(const float* __restrict__ w2,
        unsigned short* __restrict__ Whi, unsigned short* __restrict__ Wlo) {
    int i = blockIdx.x*256 + threadIdx.x;
    if (i >= 96*288) return;
    int o = i / 288, kap = i - o*288;
    float v = (kap < 264) ? w2[o*264 + kap] : 0.f;
    unsigned short h = f2bf(v);
    float lo = v - bf2f(h);
    Whi[i] = h;
    Wlo[i] = f2bf(lo);
}

// ================= K1: conv1 (22ch spatial filter) + BN1 partial stats ==========
__global__ __launch_bounds__(256) void k1_conv1(const float* __restrict__ x,
        const float* __restrict__ w1, float* __restrict__ h1,
        float* __restrict__ part1) {
    __shared__ float sw[CEEG*CEEG];       // [o][c]
    __shared__ float red[4][44];
    int b = blockIdx.x;
    int tid = threadIdx.x;
    for (int i = tid; i < CEEG*CEEG; i += 256) sw[i] = w1[i];
    __syncthreads();
    float sum[CEEG], sumsq[CEEG];
    #pragma unroll
    for (int o = 0; o < CEEG; ++o) { sum[o] = 0.f; sumsq[o] = 0.f; }
    const float* xb = x + (size_t)b*CEEG*TLEN;
    float* hb = h1 + (size_t)b*CEEG*TLEN;
    for (int it = 0; it < 4; ++it) {
        int t = it*256 + tid;
        if (t < TLEN) {
            float acc[CEEG];
            #pragma unroll
            for (int o = 0; o < CEEG; ++o) acc[o] = 0.f;
            #pragma unroll 2
            for (int c = 0; c < CEEG; ++c) {
                float xv = xb[c*TLEN + t];
                #pragma unroll
                for (int o = 0; o < CEEG; ++o) acc[o] = fmaf(xv, sw[o*CEEG + c], acc[o]);
            }
            #pragma unroll
            for (int o = 0; o < CEEG; ++o) {
                hb[o*TLEN + t] = acc[o];
                sum[o]  += acc[o];
                sumsq[o] += acc[o]*acc[o];
            }
        }
    }
    int lane = tid & 63, wv = tid >> 6;
    #pragma unroll
    for (int o = 0; o < CEEG; ++o) {
        float s = sum[o], s2 = sumsq[o];
        for (int off = 32; off > 0; off >>= 1) {
            s  += __shfl_down(s,  off, 64);
            s2 += __shfl_down(s2, off, 64);
        }
        if (lane == 0) { red[wv][o] = s; red[wv][CEEG + o] = s2; }
    }
    __syncthreads();
    if (tid < 44) {
        part1[(size_t)b*44 + tid] = red[0][tid] + red[1][tid] + red[2][tid] + red[3][tid];
    }
}

// ================= K2: finalize BN1 params (1 block / channel) ==========
__global__ __launch_bounds__(64) void k2_bn1(const float* __restrict__ part1,
        const float* __restrict__ g, const float* __restrict__ bta, float* __restrict__ p1) {
    int c = blockIdx.x, t = threadIdx.x;
    float s = 0.f, s2 = 0.f;
    for (int blk = t; blk < BSZ; blk += 64) {
        s  += part1[(size_t)blk*44 + c];
        s2 += part1[(size_t)blk*44 + CEEG + c];
    }
    for (int off = 32; off > 0; off >>= 1) {
        s  += __shfl_down(s,  off, 64);
        s2 += __shfl_down(s2, off, 64);
    }
    if (t == 0) {
        double N = (double)BSZ * (double)TLEN;
        double mu = (double)s / N, var = (double)s2 / N - mu*mu;
        double scale = (double)g[c] / sqrt(var + 1e-5);
        p1[c] = (float)scale;
        p1[CEEG + c] = (float)((double)bta[c] - mu*scale);
    }
}

// ===== K3 v8: split-bf16 MFMA GEMM, 256 thr, packed-E (hi|lo u32) Xt build ====
// C[96][128] = W[96][288] x X[288][128]. Waves: mg = w&1 (o half), ng = w>>1
// (t half). A-frags: global->register direct, double-buffered. E packed as
// u32 (hi16<<16)|(lo16 trunc) once; Xt build is pure bit-ops.
__global__ __launch_bounds__(256) void k3_conv2(const float* __restrict__ h1,
        const unsigned short* __restrict__ WhiG, const unsigned short* __restrict__ WloG,
        const float* __restrict__ p1, float* __restrict__ h2, float* __restrict__ part2) {
    __shared__ unsigned Epack[22*152];      // (hi16<<16)|(lo16), [c][tt<139]
    __shared__ unsigned short ctab[288];    // kappa -> E offset (c*152+k), 0xFFFF = pad
    __shared__ short XhiL[128*40];          // Xt chunk [t][40], 32 used
    __shared__ short XloL[128*40];
    int b = blockIdx.x;
    int tile = blockIdx.y;                  // 0..7
    int t0 = tile * 128;
    int tid = threadIdx.x;
    int lane = tid & 63, w = tid >> 6;
    int r16 = lane & 15, q = lane >> 4;
    int mg = w & 1, ng = w >> 1;
    const float* hb = h1 + (size_t)b*CEEG*TLEN;

    // stage E window [t0, t0+138] with BN1+ELU, packed hi|lo; zero beyond TLEN
    for (int i = tid; i < 22*139; i += 256) {
        int c = i / 139, tt = i - c*139;
        int t = t0 + tt;
        unsigned pk = 0u;
        if (t < TLEN) {
            float v = elu_f(fmaf(hb[c*TLEN + t], p1[c], p1[CEEG + c]));
            unsigned uv = __float_as_uint(v);
            unsigned hi = uv & 0xFFFF0000u;
            float lo = v - __uint_as_float(hi);
            pk = hi | (__float_as_uint(lo) >> 16);
        }
        Epack[c*152 + tt] = pk;
    }
    for (int i = tid; i < 288; i += 256) {
        int c = i / 12, k = i - c*12;
        ctab[i] = (i < 264) ? (unsigned short)(c*152 + k) : (unsigned short)0xFFFF;
    }

    // A-frag row pointers (this lane's 16B segment per m-tile)
    const unsigned short* ahP[3];
    const unsigned short* alP[3];
    #pragma unroll
    for (int m = 0; m < 3; ++m) {
        int row = mg*48 + m*16 + r16;
        ahP[m] = WhiG + row*288 + q*8;
        alP[m] = WloG + row*288 + q*8;
    }
    short8 ahC[3], alC[3];
    #pragma unroll
    for (int m = 0; m < 3; ++m) {
        ahC[m] = *(const short8*)&ahP[m][0];
        alC[m] = *(const short8*)&alP[m][0];
    }

    floatx4 acc[3][4];
    #pragma unroll
    for (int m = 0; m < 3; ++m)
        #pragma unroll
        for (int nf = 0; nf < 4; ++nf) acc[m][nf] = (floatx4){0.f, 0.f, 0.f, 0.f};

    __syncthreads();                        // Epack ready

    // build Xt for chunk 0 (tasks: u -> row u>>2, 16B chunk u&3)
    #pragma unroll
    for (int s = 0; s < 2; ++s) {
        int u = tid + s*256;
        int t = u >> 2, c4 = u & 3;
        const unsigned short* ct = &ctab[c4*8];
        unsigned dh[4], dl[4];
        #pragma unroll
        for (int jp = 0; jp < 4; ++jp) {
            unsigned short o0 = ct[2*jp], o1 = ct[2*jp+1];
            unsigned p0 = (o0 != 0xFFFFu) ? Epack[o0 + t] : 0u;
            unsigned p1v = (o1 != 0xFFFFu) ? Epack[o1 + t] : 0u;
            dh[jp] = (p0 >> 16) | (p1v & 0xFFFF0000u);
            dl[jp] = (p0 << 16 >> 16) | (p1v << 16);
        }
        *(uint4*)&XhiL[t*40 + c4*8] = make_uint4(dh[0], dh[1], dh[2], dh[3]);
        *(uint4*)&XloL[t*40 + c4*8] = make_uint4(dl[0], dl[1], dl[2], dl[3]);
    }
    __syncthreads();                        // Xt(0) ready

    for (int kc = 0; kc < 9; ++kc) {
        // prefetch A-frags for kc+1 (registers; waits overlap MFMA below)
        short8 ahN[3], alN[3];
        if (kc + 1 < 9) {
            #pragma unroll
            for (int m = 0; m < 3; ++m) {
                ahN[m] = *(const short8*)&ahP[m][(kc+1)*32];
                alN[m] = *(const short8*)&alP[m][(kc+1)*32];
            }
        }
        // MFMA on chunk kc
        #pragma unroll
        for (int nf = 0; nf < 4; ++nf) {
            int tn = (ng*4 + nf)*16 + r16;
            short8 bh = *(const short8*)&XhiL[tn*40 + q*8];
            short8 bl = *(const short8*)&XloL[tn*40 + q*8];
            #pragma unroll
            for (int m = 0; m < 3; ++m) {
                acc[m][nf] = __builtin_amdgcn_mfma_f32_16x16x32_bf16(ahC[m], bh, acc[m][nf], 0, 0, 0);
                acc[m][nf] = __builtin_amdgcn_mfma_f32_16x16x32_bf16(ahC[m], bl, acc[m][nf], 0, 0, 0);
                acc[m][nf] = __builtin_amdgcn_mfma_f32_16x16x32_bf16(alC[m], bh, acc[m][nf], 0, 0, 0);
            }
        }
        if (kc + 1 < 9) {
            __syncthreads();                // Xt(kc) consumed block-wide
            #pragma unroll
            for (int s = 0; s < 2; ++s) {
                int u = tid + s*256;
                int t = u >> 2, c4 = u & 3;
                const unsigned short* ct = &ctab[(kc+1)*32 + c4*8];
                unsigned dh[4], dl[4];
                #pragma unroll
                for (int jp = 0; jp < 4; ++jp) {
                    unsigned short o0 = ct[2*jp], o1 = ct[2*jp+1];
                    unsigned p0 = (o0 != 0xFFFFu) ? Epack[o0 + t] : 0u;
                    unsigned p1v = (o1 != 0xFFFFu) ? Epack[o1 + t] : 0u;
                    dh[jp] = (p0 >> 16) | (p1v & 0xFFFF0000u);
                    dl[jp] = (p0 << 16 >> 16) | (p1v << 16);
                }
                *(uint4*)&XhiL[t*40 + c4*8] = make_uint4(dh[0], dh[1], dh[2], dh[3]);
                *(uint4*)&XloL[t*40 + c4*8] = make_uint4(dl[0], dl[1], dl[2], dl[3]);
            }
            __syncthreads();                // Xt(kc+1) ready
            #pragma unroll
            for (int m = 0; m < 3; ++m) { ahC[m] = ahN[m]; alC[m] = alN[m]; }
        }
    }

    // epilogue: C/D col=lane&15 (t), row=q*4+reg (o). Store + BN2 partials.
    float* h2b = h2 + (size_t)b*C2*TSTR;
    float* pb = part2 + (((size_t)b*NT8 + tile)*2 + ng)*192;
    #pragma unroll
    for (int m = 0; m < 3; ++m) {
        float s[4] = {0.f, 0.f, 0.f, 0.f}, s2[4] = {0.f, 0.f, 0.f, 0.f};
        #pragma unroll
        for (int nf = 0; nf < 4; ++nf) {
            int t = t0 + (ng*4 + nf)*16 + r16;
            bool ok = t < TOUT;
            #pragma unroll
            for (int reg = 0; reg < 4; ++reg) {
                float v = acc[m][nf][reg];
                if (ok) {
                    int o = mg*48 + m*16 + q*4 + reg;
                    h2b[(size_t)o*TSTR + t] = v;
                    s[reg] += v; s2[reg] += v*v;
                }
            }
        }
        #pragma unroll
        for (int reg = 0; reg < 4; ++reg) {
            float a = s[reg], b2 = s2[reg];
            #pragma unroll
            for (int d = 8; d > 0; d >>= 1) {
                a  += __shfl_down(a,  d, 16);
                b2 += __shfl_down(b2, d, 16);
            }
            if (r16 == 0) {
                int o = mg*48 + m*16 + q*4 + reg;
                pb[o] = a; pb[96 + o] = b2;
            }
        }
    }
}

// ================= K4: finalize BN2 params (1 block / channel) ==========
__global__ __launch_bounds__(256) void k4_bn2(const float* __restrict__ part2,
        const float* __restrict__ g, const float* __restrict__ bta, float* __restrict__ p2) {
    __shared__ float rs[4], rs2[4];
    int q = blockIdx.x, t = threadIdx.x;
    float s = 0.f, s2 = 0.f;
    for (int blk = t; blk < NPART; blk += 256) {
        s  += part2[(size_t)blk*192 + q];
        s2 += part2[(size_t)blk*192 + 96 + q];
    }
    for (int off = 32; off > 0; off >>= 1) {
        s  += __shfl_down(s,  off, 64);
        s2 += __shfl_down(s2, off, 64);
    }
    int lane = t & 63, wv = t >> 6;
    if (lane == 0) { rs[wv] = s; rs2[wv] = s2; }
    __syncthreads();
    if (t == 0) {
        double S  = (double)rs[0]  + rs[1]  + rs[2]  + rs[3];
        double S2 = (double)rs2[0] + rs2[1] + rs2[2] + rs2[3];
        double N = (double)BSZ * (double)TOUT;
        double mu = S / N, var = S2 / N - mu*mu;
        double scale = (double)g[q] / sqrt(var + 1e-5);
        p2[q] = (float)scale;
        p2[C2 + q] = (float)((double)bta[q] - mu*scale);
    }
}

// ===== K5 v2: Gram, 4x4 tiles, wave-private staging, no inner barriers ==========
__global__ __launch_bounds__(256) void k5_gram(const float* __restrict__ h2,
        const float* __restrict__ p2, float* __restrict__ S) {
    __shared__ float smem[4*2176];          // per-wave [32][68]; overlaid red [64][17]
    int bm = blockIdx.x;
    int b = bm / 3, m = bm % 3;
    int tid = threadIdx.x;
    int w = tid >> 6, lane = tid & 63;
    float* sx = smem + w*2176;
    const float* hb = h2 + ((size_t)b*C2 + m*32)*TSTR;
    int srow = lane >> 1;
    int scol = (lane & 1) * 32;
    float sc = p2[m*32 + srow], sh = p2[C2 + m*32 + srow];
    int r0 = (lane >> 3) << 2, c0 = (lane & 7) << 2;
    float acc[4][4];
    #pragma unroll
    for (int i = 0; i < 4; ++i)
        #pragma unroll
        for (int j = 0; j < 4; ++j) acc[i][j] = 0.f;

    for (int t0 = w*64; t0 < TOUT; t0 += 256) {
        const float* src = &hb[(size_t)srow*TSTR + t0 + scol];
        float* drow = &sx[srow*68 + scol];
        if (t0 + 63 < TOUT) {
            #pragma unroll
            for (int j = 0; j < 8; ++j) {
                float4 xv = *(const float4*)&src[4*j];
                float4 v;
                v.x = elu_f(fmaf(xv.x, sc, sh));
                v.y = elu_f(fmaf(xv.y, sc, sh));
                v.z = elu_f(fmaf(xv.z, sc, sh));
                v.w = elu_f(fmaf(xv.w, sc, sh));
                *(float4*)&drow[4*j] = v;
            }
        } else {
            #pragma unroll
            for (int j = 0; j < 8; ++j) {
                float4 xv = *(const float4*)&src[4*j];
                int tb = t0 + scol + 4*j;
                float4 v;
                v.x = (tb + 0 < TOUT) ? elu_f(fmaf(xv.x, sc, sh)) : 0.f;
                v.y = (tb + 1 < TOUT) ? elu_f(fmaf(xv.y, sc, sh)) : 0.f;
                v.z = (tb + 2 < TOUT) ? elu_f(fmaf(xv.z, sc, sh)) : 0.f;
                v.w = (tb + 3 < TOUT) ? elu_f(fmaf(xv.w, sc, sh)) : 0.f;
                *(float4*)&drow[4*j] = v;
            }
        }
        #pragma unroll
        for (int tc = 0; tc < 16; ++tc) {
            float4 a0 = *(const float4*)&sx[(r0+0)*68 + tc*4];
            float4 a1 = *(const float4*)&sx[(r0+1)*68 + tc*4];
            float4 a2 = *(const float4*)&sx[(r0+2)*68 + tc*4];
            float4 a3 = *(const float4*)&sx[(r0+3)*68 + tc*4];
            float4 b0 = *(const float4*)&sx[(c0+0)*68 + tc*4];
            float4 b1 = *(const float4*)&sx[(c0+1)*68 + tc*4];
            float4 b2 = *(const float4*)&sx[(c0+2)*68 + tc*4];
            float4 b3 = *(const float4*)&sx[(c0+3)*68 + tc*4];
            #pragma unroll
            for (int i = 0; i < 4; ++i) {
                float4 ai = (i == 0) ? a0 : (i == 1) ? a1 : (i == 2) ? a2 : a3;
                acc[i][0] = fmaf(ai.x, b0.x, fmaf(ai.y, b0.y, fmaf(ai.z, b0.z, fmaf(ai.w, b0.w, acc[i][0]))));
                acc[i][1] = fmaf(ai.x, b1.x, fmaf(ai.y, b1.y, fmaf(ai.z, b1.z, fmaf(ai.w, b1.w, acc[i][1]))));
                acc[i][2] = fmaf(ai.x, b2.x, fmaf(ai.y, b2.y, fmaf(ai.z, b2.z, fmaf(ai.w, b2.w, acc[i][2]))));
                acc[i][3] = fmaf(ai.x, b3.x, fmaf(ai.y, b3.y, fmaf(ai.z, b3.z, fmaf(ai.w, b3.w, acc[i][3]))));
            }
        }
    }

    float* red = smem + w*2176;
    #pragma unroll
    for (int i = 0; i < 4; ++i)
        #pragma unroll
        for (int j = 0; j < 4; ++j)
            red[lane*17 + i*4 + j] = acc[i][j];
    __syncthreads();
    int e0 = tid * 4;
    int r = e0 >> 5, c = e0 & 31;
    int tl = (r >> 2)*8 + (c >> 2);
    int sb = (r & 3)*4;
    float o0 = 0.f, o1 = 0.f, o2 = 0.f, o3 = 0.f;
    #pragma unroll
    for (int ww = 0; ww < 4; ++ww) {
        const float* rp = smem + ww*2176 + tl*17 + sb;
        o0 += rp[0]; o1 += rp[1]; o2 += rp[2]; o3 += rp[3];
    }
    float* Sb2 = S + (size_t)bm*1024;
    *(float4*)&Sb2[e0] = make_float4(o0, o1, o2, o3);
}

// ================= K6 v3: 256 thr/matrix, b64 V, f2 cs; A stride 35 ======
__device__ __forceinline__ void pair_of(int r, int k, int& p, int& q) {
    if (k == 0) { p = r; q = 31; }
    else {
        int a = (r + k) % 31;
        int b2 = (r - k + 31) % 31;
        p = min(a, b2); q = max(a, b2);
    }
}

__global__ __launch_bounds__(256) void k6_eig(const float* __restrict__ S,
        const float* __restrict__ wq, const float* __restrict__ wk, const float* __restrict__ wv,
        float* __restrict__ QQt, float* __restrict__ KKt, float* __restrict__ Vp) {
    __shared__ float A[32][35];             // stride 35: bank=(3p+rr)%32, scrambles
    __shared__ float Vt[32][34];            // V transposed: Vt[col][row], even stride
    __shared__ float2 cs2[16];
    __shared__ float sW[3][512];
    __shared__ unsigned int ptab[31*16];
    __shared__ float Up[32][9];
    __shared__ float Aw[16][9];
    __shared__ float G[8][9];
    __shared__ float Lm[8][9];
    __shared__ float Mm[16][9];
    __shared__ float lam[32];
    int bm = blockIdx.x, b = bm / 3, m = bm % 3;
    int tid = threadIdx.x;
    const float* Sb = S + (size_t)bm*1024;
    for (int i = tid; i < 1024; i += 256) {
        int r_ = i >> 5, c_ = i & 31;
        A[r_][c_] = Sb[i];
        Vt[r_][c_] = (r_ == c_) ? 1.f : 0.f;
    }
    for (int i = tid; i < 512; i += 256) {
        sW[0][i] = wq[i]; sW[1][i] = wk[i]; sW[2][i] = wv[i];
    }
    for (int i = tid; i < 31*16; i += 256) {
        int r_ = i >> 4, k_ = i & 15;
        int p, q; pair_of(r_, k_, p, q);
        ptab[i] = (unsigned)p | ((unsigned)q << 16);
    }
    __syncthreads();

    int kk_ = tid >> 4, ll_ = tid & 15;
    int i0 = kk_ * 2;
    for (int sweep = 0; sweep < NSWEEP; ++sweep) {
        for (int r = 0; r < 31; ++r) {
            if (tid < 16) {
                unsigned pq = ptab[(r << 4) + tid];
                int p = pq & 0xffff, q = pq >> 16;
                float app = A[p][p], aqq = A[q][q], apq = A[p][q];
                float c = 1.f, s = 0.f;
                if (apq != 0.f) {
                    float tau = (aqq - app) / (2.f * apq);
                    float tt = (tau >= 0.f ? 1.f : -1.f) / (fabsf(tau) + sqrtf(1.f + tau*tau));
                    c = 1.f / sqrtf(1.f + tt*tt);
                    s = tt * c;
                    if (!(c == c) || !(s == s)) { c = 1.f; s = 0.f; }
                }
                cs2[tid] = make_float2(c, s);
            }
            __syncthreads();
            {
                unsigned pqk = ptab[(r << 4) + kk_];
                unsigned pql = ptab[(r << 4) + ll_];
                int p = pqk & 0xffff, q = pqk >> 16;
                int rr = pql & 0xffff, ss = pql >> 16;
                float2 ck2 = cs2[kk_], cl2 = cs2[ll_];
                float ck = ck2.x, sk = ck2.y, cl = cl2.x, sl = cl2.y;
                float apr = A[p][rr], aps = A[p][ss], aqr = A[q][rr], aqs = A[q][ss];
                float tpr = ck*apr - sk*aqr;
                float tqr = sk*apr + ck*aqr;
                float tps = ck*aps - sk*aqs;
                float tqs = sk*aps + ck*aqs;
                A[p][rr] = cl*tpr - sl*tps;
                A[p][ss] = sl*tpr + cl*tps;
                A[q][rr] = cl*tqr - sl*tqs;
                A[q][ss] = sl*tqr + cl*tqs;
                float2 vr = *(const float2*)&Vt[rr][i0];
                float2 vs = *(const float2*)&Vt[ss][i0];
                float2 nvr, nvs;
                nvr.x = cl*vr.x - sl*vs.x;
                nvr.y = cl*vr.y - sl*vs.y;
                nvs.x = sl*vr.x + cl*vs.x;
                nvs.y = sl*vr.y + cl*vs.y;
                *(float2*)&Vt[rr][i0] = nvr;
                *(float2*)&Vt[ss][i0] = nvs;
            }
            __syncthreads();
        }
    }

    // top-8 eigenvalue selection (descending) -> Up (Up[row][rank] = Vt[col][row])
    if (tid < 32) lam[tid] = A[tid][tid];
    __syncthreads();
    if (tid < 32) {
        float lj = lam[tid];
        int rank = 0;
        #pragma unroll
        for (int i = 0; i < 32; ++i) {
            float li = lam[i];
            rank += (li > lj) || (li == lj && i < tid);
        }
        if (rank < PDIM) {
            #pragma unroll
            for (int i = 0; i < 32; ++i) Up[i][rank] = Vt[tid][i];
        }
    }
    __syncthreads();

    // projections: P = A (A^T A)^{-1} A^T for A = W * Up  (== qr(A).Q @ Q^T)
    for (int widx = 0; widx < 3; ++widx) {
        if (widx == 2 && m != 2) break;   // V-projection only needed for m==2
        const float* W = sW[widx];
        if (tid < 128) {
            int o = tid >> 3, pp = tid & 7;
            float s = 0.f;
            #pragma unroll
            for (int i = 0; i < 32; ++i) s = fmaf(W[o*32 + i], Up[i][pp], s);
            Aw[o][pp] = s;
        }
        __syncthreads();
        if (tid < 64) {
            int xx = tid >> 3, yy = tid & 7;
            float s = 0.f;
            #pragma unroll
            for (int o = 0; o < 16; ++o) s = fmaf(Aw[o][xx], Aw[o][yy], s);
            G[xx][yy] = s;
        }
        __syncthreads();
        if (tid == 0) {
            float Lr[8][8];
            #pragma unroll
            for (int jj = 0; jj < 8; ++jj) {
                float d = G[jj][jj];
                #pragma unroll
                for (int kk = 0; kk < 8; ++kk) if (kk < jj) d -= Lr[jj][kk]*Lr[jj][kk];
                d = sqrtf(fmaxf(d, 1e-30f));
                float inv = 1.f / d;
                Lr[jj][jj] = d;
                Lm[jj][jj] = inv;     // store INVERSE of diagonal
                #pragma unroll
                for (int ii = 0; ii < 8; ++ii) if (ii > jj) {
                    float v = G[ii][jj];
                    #pragma unroll
                    for (int kk = 0; kk < 8; ++kk) if (kk < jj) v -= Lr[ii][kk]*Lr[jj][kk];
                    v *= inv;
                    Lr[ii][jj] = v;
                    Lm[ii][jj] = v;
                }
            }
        }
        __syncthreads();
        if (tid < 16) {
            int o = tid;
            float a[8], mv[8];
            #pragma unroll
            for (int pp = 0; pp < 8; ++pp) a[pp] = Aw[o][pp];
            #pragma unroll
            for (int jj = 0; jj < 8; ++jj) {
                float v = a[jj];
                #pragma unroll
                for (int kk = 0; kk < 8; ++kk) if (kk < jj) v -= Lm[jj][kk]*mv[kk];
                mv[jj] = v * Lm[jj][jj];
            }
            #pragma unroll
            for (int pp = 0; pp < 8; ++pp) Mm[o][pp] = mv[pp];
        }
        __syncthreads();
        {
            int d = tid >> 4, e = tid & 15;
            float s = 0.f;
            #pragma unroll
            for (int pp = 0; pp < 8; ++pp) s = fmaf(Mm[d][pp], Mm[e][pp], s);
            float* dst = (widx == 0) ? (QQt + (size_t)bm*256)
                       : (widx == 1) ? (KKt + (size_t)bm*256)
                       : (Vp + (size_t)b*256);
            dst[d*16 + e] = s;
        }
        __syncthreads();
    }
}

// ================= K7: attention scores + softmax(i=2) + output linear ==========
__global__ __launch_bounds__(64) void k7_out(const float* __restrict__ QQt,
        const float* __restrict__ KKt, const float* __restrict__ Vp,
        const float* __restrict__ lw, const float* __restrict__ lb,
        float* __restrict__ out) {
    __shared__ float sQ[3][256], sK[3][256], sVp[256], ssc[9], wj[3];
    int b = blockIdx.x, tid = threadIdx.x;
    for (int i = tid; i < 768; i += 64) {
        sQ[i >> 8][i & 255] = QQt[(size_t)b*768 + i];
        sK[i >> 8][i & 255] = KKt[(size_t)b*768 + i];
    }
    for (int i = tid; i < 256; i += 64) sVp[i] = Vp[(size_t)b*256 + i];
    __syncthreads();
    for (int pair = 0; pair < 9; ++pair) {
        int i = pair / 3, j = pair % 3;
        const float* Qj = sQ[j];
        const float* Ki = sK[i];
        float accp = 0.f;
        #pragma unroll
        for (int it = 0; it < 4; ++it) {
            int e = tid + 64*it;
            int d = e >> 4, ee = e & 15;
            float y = 0.f;
            #pragma unroll
            for (int f = 0; f < 16; ++f) {
                float dv = Qj[d*16 + f] - Ki[d*16 + f];
                float ev = Qj[ee*16 + f] - Ki[ee*16 + f];
                y = fmaf(dv, ev, y);
            }
            accp += y*y;
        }
        for (int off = 32; off > 0; off >>= 1) accp += __shfl_down(accp, off, 64);
        if (tid == 0) {
            float E = sqrtf(accp);
            ssc[pair] = 1.f / (1.f + log1pf(E));
        }
        __syncthreads();
    }
    if (tid < 3) {
        int j = tid;
        float e0 = expf(ssc[0*3 + j]), e1 = expf(ssc[1*3 + j]), e2 = expf(ssc[2*3 + j]);
        wj[j] = e2 / (e0 + e1 + e2);
    }
    __syncthreads();
    int o = tid >> 4, g = tid & 15;
    float part = 0.f;
    #pragma unroll
    for (int t = 0; t < 16; ++t) {
        int de = g*16 + t;
        float vv = sVp[de];
        float l0 = lw[o*768 + de];
        float l1 = lw[o*768 + 256 + de];
        float l2 = lw[o*768 + 512 + de];
        part = fmaf(vv, fmaf(wj[0], l0, fmaf(wj[1], l1, wj[2]*l2)), part);
    }
    for (int off = 8; off > 0; off >>= 1) part += __shfl_down(part, off, 16);
    if (g == 0) out[b*4 + o] = part + lb[o];
}

// ================= launch ==========
extern "C" void kernel_launch(void* const* d_in, const int* in_sizes, int n_in,
                              void* d_out, int out_size, void* d_ws, size_t ws_size,
                              hipStream_t stream) {
    const float* x  = (const float*)d_in[0];
    const float* w1 = (const float*)d_in[1];
    // d_in[2] conv1_b: cancels exactly in batch-norm (mean subtraction) -> unused
    const float* g1 = (const float*)d_in[3];
    const float* b1 = (const float*)d_in[4];
    const float* w2 = (const float*)d_in[5];
    // d_in[6] conv2_b: cancels exactly in batch-norm -> unused
    const float* g2 = (const float*)d_in[7];
    const float* b2 = (const float*)d_in[8];
    const float* wq = (const float*)d_in[9];
    const float* wk = (const float*)d_in[10];
    const float* wv = (const float*)d_in[11];
    const float* lw = (const float*)d_in[12];
    const float* lb = (const float*)d_in[13];

    float* ws   = (float*)d_ws;
    float* h1   = ws + OFF_H1;
    float* h2   = ws + OFF_H2;
    float* Sm   = ws + OFF_S;
    unsigned short* WhiG = (unsigned short*)(ws + OFF_WH);
    unsigned short* WloG = (unsigned short*)(ws + OFF_WL);
    float* qqt  = ws + OFF_QQT;
    float* kkt  = ws + OFF_KKT;
    float* vpm  = ws + OFF_VP;
    float* p1a  = ws + OFF_P1;
    float* p2a  = ws + OFF_P2;
    float* bn1p = ws + OFF_BN1;
    float* bn2p = ws + OFF_BN2;

    k0_wsplit<<<(96*288 + 255)/256, 256, 0, stream>>>(w2, WhiG, WloG);
    k1_conv1<<<BSZ, 256, 0, stream>>>(x, w1, h1, p1a);
    k2_bn1<<<CEEG, 64, 0, stream>>>(p1a, g1, b1, bn1p);
    dim3 g3(BSZ, NT8);
    k3_conv2<<<g3, 256, 0, stream>>>(h1, WhiG, WloG, bn1p, h2, p2a);
    k4_bn2<<<C2, 256, 0, stream>>>(p2a, g2, b2, bn2p);
    k5_gram<<<BSZ*3, 256, 0, stream>>>(h2, bn2p, Sm);
    k6_eig<<<BSZ*3, 256, 0, stream>>>(Sm, wq, wk, wv, qqt, kkt, vpm);
    k7_out<<<BSZ, 64, 0, stream>>>(qqt, kkt, vpm, lw, lb, (float*)d_out);
}